// Round 2
// baseline (577.433 us; speedup 1.0000x reference)
//
#include <hip/hip_runtime.h>
#include <hip/hip_bf16.h>
#include <hip/hip_cooperative_groups.h>
#include <math.h>

namespace cg = cooperative_groups;

#define N_NODES 50000
#define E_MSG   800000
#define E_FULL  1000000
#define IN_C    128
#define H_C     64
#define T_STEPS 128

// ---- workspace layout (in floats) ----
#define OFF_Win   0
#define OFF_bin   8192
#define OFF_Wt1   8256
#define OFF_bt1   24640
#define OFF_Wt2   24896
#define OFF_bt2   41280
#define OFF_Wc0   41344
#define OFF_bc0   45440
#define OFF_Wc1   45504
#define OFF_bc1   49600
#define OFF_Wd1   49664
#define OFF_bd1   57856
#define OFF_Wd2   57920
#define OFF_bd2   57984
#define W_TOTAL   57985
#define OFF_BSUM  58016                 // 256 ints (bucket exclusive prefixes)
#define OFF_BCUR  58272                 // 256 ints (bucket fill cursors)
#define OFF_FWD1  58624                 // 8192 fp8 bytes (16*Wd1 frag table)
#define OFF_FWIN  60672                 // 8192 bf16 (W_in frag table)
#define OFF_FWC0  64768                 // 4096 bf16 (Wc0 frag table)
#define OFF_TEMB  66816                 // 128*64 floats
#define OFF_DINV  75008                 // 50000 floats
#define OFF_CNT   125008                // 50000 ints
#define OFF_PTR   175008                // 50001 ints
#define OFF_ELIST 225010                // 800000 ints
#define OFF_TMP   1025010               // pad
#define OFF_TMP2  1025012               // 1.6M ints (800000 uint2), 8B aligned
#define OFF_ZBF   2625012               // 3.2M bf16 (z0)
#define OFF_ZBF2  4225012               // 3.2M bf16 (z1)
#define OFF_HENC8 5825012               // 3.2M fp8 bytes
// total 6,625,012 floats = 26.5 MB

// Wc1 MFMA frag table (4096 bf16 = 2048 floats) lives in the dead tmp region:
// tmp is consumed by k_csr (runs BEFORE k_wprep on the same stream).
#define OFF_FWC1  OFF_TMP2

#define SCAN_NB   ((N_NODES + 255) / 256)   // 196 buckets
#define BF_CH     ((E_MSG + SCAN_NB - 1) / SCAN_NB)   // 4082 edges/block

typedef __attribute__((ext_vector_type(8))) short bf16x8;
typedef __attribute__((ext_vector_type(4))) float f32x4;

static __device__ __forceinline__ float bf2f(unsigned short u) {
    return __uint_as_float(((unsigned)u) << 16);
}
static __device__ __forceinline__ unsigned short f2bf(float f) {
    unsigned u = __float_as_uint(f);
    unsigned r = (u + 0x7fffu + ((u >> 16) & 1u)) >> 16;
    return (unsigned short)r;
}
// fp32 -> fp8 e4m3fn, RNE, clamp to +-448
static __device__ __forceinline__ unsigned char f2fp8(float f) {
    unsigned u = __float_as_uint(f);
    unsigned s = (u >> 24) & 0x80;
    float a = fminf(__uint_as_float(u & 0x7FFFFFFF), 448.0f);
    if (a < 0.015625f) {
        int qi = (int)rintf(a * 512.0f);
        return (unsigned char)(s | qi);
    }
    unsigned ua = __float_as_uint(a);
    int e = (int)((ua >> 23) & 0xFF) - 127;
    unsigned man = (ua & 0x7FFFFF) | 0x800000;
    unsigned r = man >> 20;
    unsigned rem = man & 0xFFFFF;
    if (rem > 0x80000u || (rem == 0x80000u && (r & 1))) r++;
    if (r == 16) { r = 8; e++; }
    if (e > 8) return (unsigned char)(s | 0x7E);
    return (unsigned char)(s | ((unsigned)(e + 7) << 3) | (r & 7));
}
static __device__ __forceinline__ bool detect_f32(const unsigned short* w, int* scnt) {
    if (threadIdx.x == 0) *scnt = 0;
    __syncthreads();
    int big = 0;
    for (int i = threadIdx.x; i < 2048; i += blockDim.x)
        if (fabsf(bf2f(w[2 * i])) > 0.5f) big++;
    atomicAdd(scnt, big);
    __syncthreads();
    return *scnt > 64;
}
// raw-weight load with dtype dispatch
static __device__ __forceinline__ float ldw(const void* p, int idx, bool f32) {
    return f32 ? ((const float*)p)[idx] : bf2f(((const unsigned short*)p)[idx]);
}

// ---------------- fused CSR build (cooperative, 196 blocks) ----------------
// phases: zero cnt -> count -> block sums -> bucket exclusive prefix ->
//         ptr/dinv -> bucketed scatter (bfill) -> per-bucket counting sort
__global__ void __launch_bounds__(256) k_csr(const int* __restrict__ row,
                                             const int* __restrict__ col,
                                             int* cnt, int* bsum, int* bcur,
                                             int* ptr, float* dinv,
                                             uint2* tmp, int* elist) {
    cg::grid_group grid = cg::this_grid();
    __shared__ int sh[256];
    __shared__ int hist[SCAN_NB];
    __shared__ int basew[SCAN_NB];
    int b = blockIdx.x, t = threadIdx.x;

    // phase 0: zero counters
    for (int n = b * 256 + t; n < N_NODES; n += SCAN_NB * 256) cnt[n] = 0;
    __threadfence();
    grid.sync();

    // phase 1: degree count (by dst)
    for (int e = b * 256 + t; e < E_MSG; e += SCAN_NB * 256)
        atomicAdd(&cnt[col[e]], 1);
    grid.sync();

    // phase 2: per-block (bucket) sums
    int n = b * 256 + t;
    int v = (n < N_NODES) ? cnt[n] : 0;
    sh[t] = v;
    __syncthreads();
    for (int off = 128; off > 0; off >>= 1) {
        if (t < off) sh[t] += sh[t + off];
        __syncthreads();
    }
    if (t == 0) bsum[b] = sh[0];
    __threadfence();
    grid.sync();

    // phase 3: exclusive prefix over buckets (block 0 only)
    if (b == 0) {
        int vv = (t < SCAN_NB) ? bsum[t] : 0;
        sh[t] = vv;
        __syncthreads();
        for (int off = 1; off < 256; off <<= 1) {
            int u = (t >= off) ? sh[t - off] : 0;
            __syncthreads();
            sh[t] += u;
            __syncthreads();
        }
        if (t < SCAN_NB) { bsum[t] = sh[t] - vv; bcur[t] = sh[t] - vv; }
        if (t == 0) ptr[N_NODES] = E_MSG;
        __threadfence();
    }
    grid.sync();

    // phase 4: per-node CSR pointers + dinv
    sh[t] = v;
    __syncthreads();
    for (int off = 1; off < 256; off <<= 1) {
        int u = (t >= off) ? sh[t - off] : 0;
        __syncthreads();
        sh[t] += u;
        __syncthreads();
    }
    if (n < N_NODES) {
        ptr[n] = bsum[b] + sh[t] - v;
        dinv[n] = rsqrtf((float)v + 1.0f);
    }
    __threadfence();
    grid.sync();

    // phase 5: bucketed scatter (chunk b of the edge list)
    int lo = b * BF_CH;
    int hi = lo + BF_CH; if (hi > E_MSG) hi = E_MSG;
    for (int i = t; i < SCAN_NB; i += 256) hist[i] = 0;
    __syncthreads();
    for (int e = lo + t; e < hi; e += 256)
        atomicAdd(&hist[col[e] >> 8], 1);
    __syncthreads();
    for (int i = t; i < SCAN_NB; i += 256) {
        int c = hist[i];
        basew[i] = (c > 0) ? atomicAdd(&bcur[i], c) : 0;
    }
    __syncthreads();
    for (int i = t; i < SCAN_NB; i += 256) hist[i] = 0;  // reuse as cursor
    __syncthreads();
    for (int e = lo + t; e < hi; e += 256) {
        int src = row[e], c = col[e];
        int bk = c >> 8;
        int off = atomicAdd(&hist[bk], 1);
        tmp[basew[bk] + off] = uint2{(unsigned)src, (unsigned)c};
    }
    __threadfence();
    grid.sync();

    // phase 6: per-bucket counting sort into elist
    int nn = (b << 8) + t;
    sh[t] = (nn < N_NODES) ? ptr[nn] : 0;
    __syncthreads();
    int start = bsum[b];
    int end = (b == SCAN_NB - 1) ? E_MSG : bsum[b + 1];
    for (int e = start + t; e < end; e += 256) {
        uint2 p = tmp[e];
        int pos = atomicAdd(&sh[p.y & 255], 1);
        elist[pos] = (int)p.x;
    }
}

// ---------------- fused weight prep: cvt + frag tables + temb ----------------
// blocks [0,227): cvt -> ws fp32
// blocks [227,323): MFMA B-frag tables (read RAW weights, convert inline)
// blocks [323,355): t_emb table, 4 timesteps per block (read RAW Wt1/Wt2)
#define WP_CVT_NB  227
#define WP_PREP_NB 96
#define WP_TEMB_NB 32

struct CvtArgs { const void* src[14]; };

__global__ void __launch_bounds__(256) k_wprep(CvtArgs a, float* ws) {
    __shared__ int scnt;
    bool f32 = detect_f32((const unsigned short*)a.src[0], &scnt);
    int bid = blockIdx.x;
    int tid = threadIdx.x;

    if (bid < WP_CVT_NB) {
        int t = bid * 256 + tid;
        if (t >= W_TOTAL) return;
        const int starts[14] = {OFF_Win, OFF_bin, OFF_Wt1, OFF_bt1, OFF_Wt2, OFF_bt2,
                                OFF_Wc0, OFF_bc0, OFF_Wc1, OFF_bc1, OFF_Wd1, OFF_bd1,
                                OFF_Wd2, OFF_bd2};
        int seg = 0;
#pragma unroll
        for (int i = 1; i < 14; i++)
            if (t >= starts[i]) seg = i;
        ws[t] = ldw(a.src[seg], t - starts[seg], f32);
    } else if (bid < WP_CVT_NB + WP_PREP_NB) {
        int idx = (bid - WP_CVT_NB) * 256 + tid;       // 0..24575
        int local, j, lane, ct, c, t, m, q;
        if (idx < 8192) {
            local = idx;
            j = local & 7; lane = (local >> 3) & 63; ct = local >> 9;
            c = ct >> 2; t = ct & 3; m = lane & 15; q = lane >> 4;
            ((unsigned char*)(ws + OFF_FWD1))[local] =
                f2fp8(16.0f * ldw(a.src[10], (32 * c + 8 * q + j) * 64 + 16 * t + m, f32));
        } else if (idx < 16384) {
            local = idx - 8192;
            j = local & 7; lane = (local >> 3) & 63; ct = local >> 9;
            c = ct >> 2; t = ct & 3; m = lane & 15; q = lane >> 4;
            ((unsigned short*)(ws + OFF_FWIN))[local] =
                f2bf(ldw(a.src[0], (32 * c + 8 * q + j) * 64 + 16 * t + m, f32));
        } else if (idx < 20480) {
            local = idx - 16384;
            j = local & 7; lane = (local >> 3) & 63; ct = local >> 9;
            c = ct >> 2; t = ct & 3; m = lane & 15; q = lane >> 4;
            ((unsigned short*)(ws + OFF_FWC0))[local] =
                f2bf(ldw(a.src[6], (32 * c + 8 * q + j) * 64 + 16 * t + m, f32));
        } else {
            local = idx - 20480;
            j = local & 7; lane = (local >> 3) & 63; ct = local >> 9;
            c = ct >> 2; t = ct & 3; m = lane & 15; q = lane >> 4;
            ((unsigned short*)(ws + OFF_FWC1))[local] =
                f2bf(ldw(a.src[8], (32 * c + 8 * q + j) * 64 + 16 * t + m, f32));
        }
    } else {
        // t_emb: 4 timesteps per block, 64 threads each
        __shared__ float pe[4][64];
        __shared__ float us[4][256];
        int g = tid >> 6;
        int j = tid & 63;
        int t = (bid - WP_CVT_NB - WP_PREP_NB) * 4 + g;

        float xt = (float)t * (4000.0f / 128.0f);
        float sc = -logf(10000.0f) / 31.0f;
        int idx = j & 31;
        float fr = __expf((float)idx * sc);
        float ang = xt * fr;
        pe[g][j] = (j < 32) ? sinf(ang) : cosf(ang);
        __syncthreads();

        float u[4];
#pragma unroll
        for (int q = 0; q < 4; q++) u[q] = ldw(a.src[3], q * 64 + j, f32);
        for (int k = 0; k < 64; k++) {
            float p = pe[g][k];
#pragma unroll
            for (int q = 0; q < 4; q++)
                u[q] = fmaf(p, ldw(a.src[2], k * 256 + q * 64 + j, f32), u[q]);
        }
#pragma unroll
        for (int q = 0; q < 4; q++) {
            float uu = u[q];
            us[g][q * 64 + j] = uu * __builtin_amdgcn_rcpf(1.0f + __expf(-uu));
        }
        __syncthreads();

        float acc = ldw(a.src[5], j, f32);
        for (int k = 0; k < 256; k++)
            acc = fmaf(us[g][k], ldw(a.src[4], k * 64 + j, f32), acc);
        (ws + OFF_TEMB)[t * 64 + j] = acc;
    }
}

// ---------------- embedder + fused GCN-linear-0 (MFMA x2) ----------------
__global__ void __launch_bounds__(256) k_embed(const void* __restrict__ xraw,
                                               const unsigned short* __restrict__ wdet,
                                               const int* __restrict__ tsteps,
                                               float* __restrict__ ws,
                                               float* __restrict__ out_hembed,
                                               unsigned short* __restrict__ zbf) {
    __shared__ int scnt;
    __shared__ unsigned short tl[4][16 * 64];
    bool f32 = detect_f32(wdet, &scnt);

    int lane = threadIdx.x & 63;
    int wv = threadIdx.x >> 6;
    int m = lane & 15, quad = lane >> 4;
    int wid = blockIdx.x * 4 + wv;
    if (wid > N_NODES / 16 - 1) wid = N_NODES / 16 - 1;   // clamp (dup work benign)
    int n0 = wid * 16;

    const unsigned short* fwin = (const unsigned short*)(ws + OFF_FWIN);
    const unsigned short* fwc0 = (const unsigned short*)(ws + OFF_FWC0);

    bf16x8 bI[4][4];
#pragma unroll
    for (int c = 0; c < 4; c++)
#pragma unroll
        for (int t = 0; t < 4; t++)
            bI[c][t] = *reinterpret_cast<const bf16x8*>(fwin + (c * 4 + t) * 512 + lane * 8);

    f32x4 acc[4] = {f32x4{0,0,0,0}, f32x4{0,0,0,0}, f32x4{0,0,0,0}, f32x4{0,0,0,0}};
#pragma unroll
    for (int c = 0; c < 4; c++) {
        bf16x8 a;
        if (f32) {
            const float* xp = (const float*)xraw + (size_t)(n0 + m) * 128 + 32 * c + 8 * quad;
            float4 v0 = *reinterpret_cast<const float4*>(xp);
            float4 v1 = *reinterpret_cast<const float4*>(xp + 4);
            a[0] = (short)f2bf(v0.x); a[1] = (short)f2bf(v0.y);
            a[2] = (short)f2bf(v0.z); a[3] = (short)f2bf(v0.w);
            a[4] = (short)f2bf(v1.x); a[5] = (short)f2bf(v1.y);
            a[6] = (short)f2bf(v1.z); a[7] = (short)f2bf(v1.w);
        } else {
            a = *reinterpret_cast<const bf16x8*>(
                (const unsigned short*)xraw + (size_t)(n0 + m) * 128 + 32 * c + 8 * quad);
        }
#pragma unroll
        for (int t = 0; t < 4; t++)
            acc[t] = __builtin_amdgcn_mfma_f32_16x16x32_bf16(a, bI[c][t], acc[t], 0, 0, 0);
    }

    int tn[4];
#pragma unroll
    for (int r = 0; r < 4; r++) tn[r] = tsteps[n0 + 4 * quad + r];
    const float* temb = ws + OFF_TEMB;
#pragma unroll
    for (int t = 0; t < 4; t++) {
        int ch = 16 * t + m;
        float bj = ws[OFF_bin + ch];
#pragma unroll
        for (int r = 0; r < 4; r++) {
            int node = n0 + 4 * quad + r;
            float v = acc[t][r] + bj + temb[tn[r] * 64 + ch];
            out_hembed[(size_t)node * 64 + ch] = v;
            tl[wv][(4 * quad + r) * 64 + ch] = f2bf(v);
        }
    }
    __syncthreads();

    bf16x8 bC[2][4];
#pragma unroll
    for (int c = 0; c < 2; c++)
#pragma unroll
        for (int t = 0; t < 4; t++)
            bC[c][t] = *reinterpret_cast<const bf16x8*>(fwc0 + (c * 4 + t) * 512 + lane * 8);

    f32x4 az[4] = {f32x4{0,0,0,0}, f32x4{0,0,0,0}, f32x4{0,0,0,0}, f32x4{0,0,0,0}};
#pragma unroll
    for (int c = 0; c < 2; c++) {
        bf16x8 a2 = *reinterpret_cast<const bf16x8*>(&tl[wv][m * 64 + 32 * c + 8 * quad]);
#pragma unroll
        for (int t = 0; t < 4; t++)
            az[t] = __builtin_amdgcn_mfma_f32_16x16x32_bf16(a2, bC[c][t], az[t], 0, 0, 0);
    }
    const float* dinv = ws + OFF_DINV;
    float dv[4];
#pragma unroll
    for (int r = 0; r < 4; r++) dv[r] = dinv[n0 + 4 * quad + r];
#pragma unroll
    for (int t = 0; t < 4; t++) {
        int ch = 16 * t + m;
#pragma unroll
        for (int r = 0; r < 4; r++)
            zbf[(size_t)(n0 + 4 * quad + r) * 64 + ch] = f2bf(az[t][r] * dv[r]);
    }
}

// ---------------- gather-0 + relu + fused GCN-linear-1 (MFMA) ----------------
__global__ void __launch_bounds__(256) k_gather0(const unsigned short* __restrict__ zbf,
                                                 const int* __restrict__ ptr,
                                                 const int* __restrict__ elist,
                                                 const float* __restrict__ ws,
                                                 unsigned short* __restrict__ zout) {
    __shared__ unsigned short tile[16 * 64];     // 2KB, swizzled bf16 [16][64]
    const float* dinv = ws + OFF_DINV;
    const float* bias = ws + OFF_bc0;
    const unsigned short* fwc1 = (const unsigned short*)(ws + OFF_FWC1);

    int lane = threadIdx.x & 63;
    int wv = threadIdx.x >> 6;
    int g = lane >> 4;              // neighbor sub-group 0..3
    int cl = lane & 15;             // channel quad: channels 4cl..4cl+3
    int n0 = blockIdx.x * 16;

    float4 b4 = *reinterpret_cast<const float4*>(bias + 4 * cl);

#pragma unroll
    for (int snode = 0; snode < 4; snode++) {
        int li = wv * 4 + snode;    // local tile row
        int n = n0 + li;
        int base = ptr[n], end = ptr[n + 1];

        float ws0 = (g == 0) ? 1.0f : 0.0f;
        ushort4 sv = *reinterpret_cast<const ushort4*>(zbf + (size_t)n * 64 + cl * 4);
        float s0 = ws0 * bf2f(sv.x), s1 = ws0 * bf2f(sv.y);
        float s2 = ws0 * bf2f(sv.z), s3 = ws0 * bf2f(sv.w);

        for (int k = base; k < end; k += 8) {
            int e0 = k + g, e1 = k + 4 + g;
            int r0 = elist[min(e0, end - 1)];
            int r1 = elist[min(e1, end - 1)];
            ushort4 v0 = *reinterpret_cast<const ushort4*>(zbf + (size_t)r0 * 64 + cl * 4);
            ushort4 v1 = *reinterpret_cast<const ushort4*>(zbf + (size_t)r1 * 64 + cl * 4);
            float w0 = (e0 < end) ? 1.0f : 0.0f;
            float w1 = (e1 < end) ? 1.0f : 0.0f;
            s0 = fmaf(w0, bf2f(v0.x), s0); s1 = fmaf(w0, bf2f(v0.y), s1);
            s2 = fmaf(w0, bf2f(v0.z), s2); s3 = fmaf(w0, bf2f(v0.w), s3);
            s0 = fmaf(w1, bf2f(v1.x), s0); s1 = fmaf(w1, bf2f(v1.y), s1);
            s2 = fmaf(w1, bf2f(v1.z), s2); s3 = fmaf(w1, bf2f(v1.w), s3);
        }
        s0 += __shfl_xor(s0, 16, 64); s0 += __shfl_xor(s0, 32, 64);
        s1 += __shfl_xor(s1, 16, 64); s1 += __shfl_xor(s1, 32, 64);
        s2 += __shfl_xor(s2, 16, 64); s2 += __shfl_xor(s2, 32, 64);
        s3 += __shfl_xor(s3, 16, 64); s3 += __shfl_xor(s3, 32, 64);

        if (g == 0) {
            float dv = dinv[n];
            float h0 = fmaxf(fmaf(dv, s0, b4.x), 0.0f);
            float h1 = fmaxf(fmaf(dv, s1, b4.y), 0.0f);
            float h2 = fmaxf(fmaf(dv, s2, b4.z), 0.0f);
            float h3 = fmaxf(fmaf(dv, s3, b4.w), 0.0f);
            ushort4 hv;
            hv.x = f2bf(h0); hv.y = f2bf(h1); hv.z = f2bf(h2); hv.w = f2bf(h3);
            int bo = li * 128 + ((cl * 8) ^ ((li & 7) << 4));   // XOR-swizzle (G4)
            *reinterpret_cast<ushort4*>((char*)tile + bo) = hv;
        }
    }
    __syncthreads();

    // phase 2: wave wv computes output channels 16*wv..16*wv+15 for all 16 nodes
    int m = lane & 15, q = lane >> 4;
    bf16x8 bB0 = *reinterpret_cast<const bf16x8*>(fwc1 + (0 * 4 + wv) * 512 + lane * 8);
    bf16x8 bB1 = *reinterpret_cast<const bf16x8*>(fwc1 + (1 * 4 + wv) * 512 + lane * 8);

    f32x4 az = f32x4{0, 0, 0, 0};
    {
        int bo0 = m * 128 + ((0 * 64 + q * 16) ^ ((m & 7) << 4));
        bf16x8 a0 = *reinterpret_cast<const bf16x8*>((const char*)tile + bo0);
        az = __builtin_amdgcn_mfma_f32_16x16x32_bf16(a0, bB0, az, 0, 0, 0);
        int bo1 = m * 128 + ((1 * 64 + q * 16) ^ ((m & 7) << 4));
        bf16x8 a1 = *reinterpret_cast<const bf16x8*>((const char*)tile + bo1);
        az = __builtin_amdgcn_mfma_f32_16x16x32_bf16(a1, bB1, az, 0, 0, 0);
    }
    float dv4[4];
#pragma unroll
    for (int r = 0; r < 4; r++) dv4[r] = dinv[n0 + 4 * q + r];
#pragma unroll
    for (int r = 0; r < 4; r++) {
        int node = n0 + 4 * q + r;
        zout[(size_t)node * 64 + 16 * wv + m] = f2bf(az[r] * dv4[r]);
    }
}

// ---------------- gather-1 -> h_enc (fp32 out + fp8x16 table) ----------------
__global__ void __launch_bounds__(256) k_gather1(const unsigned short* __restrict__ zbf,
                                                 const int* __restrict__ ptr,
                                                 const int* __restrict__ elist,
                                                 const float* __restrict__ dinv,
                                                 const float* __restrict__ bias,
                                                 unsigned char* __restrict__ henc8,
                                                 float* __restrict__ ofp) {
    int lane = threadIdx.x & 63;
    int n = blockIdx.x * 4 + (threadIdx.x >> 6);
    int g = lane >> 4;
    int cl = lane & 15;
    int base = ptr[n], end = ptr[n + 1];

    float4 b4 = *reinterpret_cast<const float4*>(bias + 4 * cl);

    float ws0 = (g == 0) ? 1.0f : 0.0f;
    ushort4 sv = *reinterpret_cast<const ushort4*>(zbf + (size_t)n * 64 + cl * 4);
    float s0 = ws0 * bf2f(sv.x), s1 = ws0 * bf2f(sv.y);
    float s2 = ws0 * bf2f(sv.z), s3 = ws0 * bf2f(sv.w);

    for (int k = base; k < end; k += 8) {
        int e0 = k + g, e1 = k + 4 + g;
        int r0 = elist[min(e0, end - 1)];
        int r1 = elist[min(e1, end - 1)];
        ushort4 v0 = *reinterpret_cast<const ushort4*>(zbf + (size_t)r0 * 64 + cl * 4);
        ushort4 v1 = *reinterpret_cast<const ushort4*>(zbf + (size_t)r1 * 64 + cl * 4);
        float w0 = (e0 < end) ? 1.0f : 0.0f;
        float w1 = (e1 < end) ? 1.0f : 0.0f;
        s0 = fmaf(w0, bf2f(v0.x), s0); s1 = fmaf(w0, bf2f(v0.y), s1);
        s2 = fmaf(w0, bf2f(v0.z), s2); s3 = fmaf(w0, bf2f(v0.w), s3);
        s0 = fmaf(w1, bf2f(v1.x), s0); s1 = fmaf(w1, bf2f(v1.y), s1);
        s2 = fmaf(w1, bf2f(v1.z), s2); s3 = fmaf(w1, bf2f(v1.w), s3);
    }
    s0 += __shfl_xor(s0, 16, 64); s0 += __shfl_xor(s0, 32, 64);
    s1 += __shfl_xor(s1, 16, 64); s1 += __shfl_xor(s1, 32, 64);
    s2 += __shfl_xor(s2, 16, 64); s2 += __shfl_xor(s2, 32, 64);
    s3 += __shfl_xor(s3, 16, 64); s3 += __shfl_xor(s3, 32, 64);

    float dv = dinv[n];
    float o0 = fmaf(dv, s0, b4.x);
    float o1 = fmaf(dv, s1, b4.y);
    float o2 = fmaf(dv, s2, b4.z);
    float o3 = fmaf(dv, s3, b4.w);

    if (g == 0) {
        float4 ov; ov.x = o0; ov.y = o1; ov.z = o2; ov.w = o3;
        *reinterpret_cast<float4*>(ofp + (size_t)n * 64 + cl * 4) = ov;
    }
    // redistribute: lane converts channel `lane`
    int jc = lane >> 2;
    float a0 = __shfl(o0, jc, 64);
    float a1 = __shfl(o1, jc, 64);
    float a2 = __shfl(o2, jc, 64);
    float a3 = __shfl(o3, jc, 64);
    int sel = lane & 3;
    float mv = (sel == 0) ? a0 : (sel == 1) ? a1 : (sel == 2) ? a2 : a3;
    henc8[(size_t)n * 64 + lane] = f2fp8(16.0f * mv);
}

// ---------------- edge decoder (MFMA fp8, pipelined) ----------------
#define DEC_TPW 4
#define DEC_TILES (E_FULL / 16)

__global__ void __launch_bounds__(256) k_dec(const int* __restrict__ src,
                                             const int* __restrict__ dst,
                                             const unsigned char* __restrict__ h8,
                                             const float* __restrict__ ws,
                                             float* __restrict__ out) {
    int lane = threadIdx.x & 63;
    int wv = threadIdx.x >> 6;
    int m = lane & 15;
    int quad = lane >> 4;

    const unsigned char* fw = (const unsigned char*)(ws + OFF_FWD1);
    long bfr[4][4];
#pragma unroll
    for (int c = 0; c < 4; c++)
#pragma unroll
        for (int t = 0; t < 4; t++)
            bfr[c][t] = *reinterpret_cast<const long*>(fw + ((c * 4 + t) * 512 + lane * 8));

    float w2[4], b1v[4];
#pragma unroll
    for (int t = 0; t < 4; t++) {
        w2[t]  = ws[OFF_Wd2 + 16 * t + m];
        b1v[t] = ws[OFF_bd1 + 16 * t + m];
    }
    float b2 = ws[OFF_bd2];

    int tile0 = (blockIdx.x * 4 + wv) * DEC_TPW;
    int tc = min(tile0, DEC_TILES - 1);
    int s0 = src[tc * 16 + m], d0 = dst[tc * 16 + m];
    tc = min(tile0 + 1, DEC_TILES - 1);
    int s1 = src[tc * 16 + m], d1 = dst[tc * 16 + m];
    long A0[4];
#pragma unroll
    for (int c = 0; c < 4; c++) {
        int row = (c < 2) ? s0 : d0;
        A0[c] = *reinterpret_cast<const long*>(
            h8 + (size_t)row * 64 + (c & 1) * 32 + 8 * quad);
    }

    for (int i = 0; i < DEC_TPW; i++) {
        int tile = tile0 + i;
        int t2 = min(tile0 + i + 2, DEC_TILES - 1);
        int s2 = src[t2 * 16 + m], d2 = dst[t2 * 16 + m];
        long A1[4];
#pragma unroll
        for (int c = 0; c < 4; c++) {
            int row = (c < 2) ? s1 : d1;
            A1[c] = *reinterpret_cast<const long*>(
                h8 + (size_t)row * 64 + (c & 1) * 32 + 8 * quad);
        }
        f32x4 acc[4] = {f32x4{0,0,0,0}, f32x4{0,0,0,0}, f32x4{0,0,0,0}, f32x4{0,0,0,0}};
#pragma unroll
        for (int c = 0; c < 4; c++)
#pragma unroll
            for (int t = 0; t < 4; t++)
                acc[t] = __builtin_amdgcn_mfma_f32_16x16x32_fp8_fp8(A0[c], bfr[c][t], acc[t], 0, 0, 0);
        float sums[4];
#pragma unroll
        for (int r = 0; r < 4; r++) {
            float sv = 0.0f;
#pragma unroll
            for (int t = 0; t < 4; t++) {
                float v = fmaf(acc[t][r], 0.00390625f, b1v[t]);   // /256 un-scale
                float h = v * __builtin_amdgcn_rcpf(1.0f + __expf(-v));
                sv = fmaf(h, w2[t], sv);
            }
#pragma unroll
            for (int msk = 8; msk >= 1; msk >>= 1)
                sv += __shfl_xor(sv, msk, 64);
            sums[r] = sv;
        }
        if (m == 0 && tile < DEC_TILES) {
            float4 o;
            o.x = sums[0] + b2; o.y = sums[1] + b2;
            o.z = sums[2] + b2; o.w = sums[3] + b2;
            *reinterpret_cast<float4*>(out + tile * 16 + 4 * quad) = o;
        }
#pragma unroll
        for (int c = 0; c < 4; c++) A0[c] = A1[c];
        s1 = s2; d1 = d2;
    }
}

extern "C" void kernel_launch(void* const* d_in, const int* in_sizes, int n_in,
                              void* d_out, int out_size, void* d_ws, size_t ws_size,
                              hipStream_t stream) {
    if (n_in < 18) return;
    const void* x              = d_in[0];
    const int* edge_index      = (const int*)d_in[1];
    const int* full_edge_index = (const int*)d_in[2];
    const int* tsteps          = (const int*)d_in[3];
    float* ws = (float*)d_ws;
    float* out = (float*)d_out;

    int*   iws   = (int*)d_ws;
    int*   bsum  = iws + OFF_BSUM;
    int*   bcur  = iws + OFF_BCUR;
    int*   cnt   = iws + OFF_CNT;
    int*   ptr   = iws + OFF_PTR;
    int*   elist = iws + OFF_ELIST;
    uint2* tmp   = (uint2*)(iws + OFF_TMP2);
    unsigned short* zbf  = (unsigned short*)(ws + OFF_ZBF);
    unsigned short* zbf2 = (unsigned short*)(ws + OFF_ZBF2);
    unsigned char*  h8   = (unsigned char*)(ws + OFF_HENC8);

    CvtArgs ca;
    for (int i = 0; i < 14; i++) ca.src[i] = d_in[4 + i];

    // 1) fused CSR build (cooperative): count + scans + bucket sort
    {
        const int* row_p = edge_index;
        const int* col_p = edge_index + E_MSG;
        float* dinv_p = ws + OFF_DINV;
        void* args[] = {(void*)&row_p, (void*)&col_p, (void*)&cnt, (void*)&bsum,
                        (void*)&bcur, (void*)&ptr, (void*)&dinv_p, (void*)&tmp,
                        (void*)&elist};
        hipLaunchCooperativeKernel((const void*)k_csr, dim3(SCAN_NB), dim3(256),
                                   args, 0, stream);
    }

    // 2) fused weight prep: cvt + frag tables (incl. Wc1 over dead tmp) + t_emb
    k_wprep<<<WP_CVT_NB + WP_PREP_NB + WP_TEMB_NB, 256, 0, stream>>>(ca, ws);

    // 3) embedder + fused lin0 (h_embed -> d_out fp32; z0 -> zbf)
    k_embed<<<(N_NODES / 16 + 3) / 4, 256, 0, stream>>>(
        x, (const unsigned short*)d_in[4], tsteps, ws, out + E_FULL, zbf);

    // 4) gather0 + relu + fused lin1 (MFMA): zbf -> zbf2
    k_gather0<<<N_NODES / 16, 256, 0, stream>>>(zbf, ptr, elist, ws, zbf2);

    // 5) gather1: zbf2 -> {out fp32, h8 fp8x16}
    k_gather1<<<N_NODES / 4, 256, 0, stream>>>(
        zbf2, ptr, elist, ws + OFF_DINV, ws + OFF_bc1, h8,
        out + E_FULL + (size_t)N_NODES * 64);

    // 6) decoder (fp8 MFMA)
    int dec_blocks = (DEC_TILES + 4 * DEC_TPW - 1) / (4 * DEC_TPW);
    k_dec<<<dec_blocks, 256, 0, stream>>>(full_edge_index, full_edge_index + E_FULL,
                                          h8, ws, out);
}

// Round 3
// 350.129 us; speedup vs baseline: 1.6492x; 1.6492x over previous
//
#include <hip/hip_runtime.h>
#include <hip/hip_bf16.h>
#include <math.h>

#define N_NODES 50000
#define E_MSG   800000
#define E_FULL  1000000
#define IN_C    128
#define H_C     64
#define T_STEPS 128

// ---- workspace layout (in floats) ----
#define OFF_Win   0
#define OFF_bin   8192
#define OFF_Wt1   8256
#define OFF_bt1   24640
#define OFF_Wt2   24896
#define OFF_bt2   41280
#define OFF_Wc0   41344
#define OFF_bc0   45440
#define OFF_Wc1   45504
#define OFF_bc1   49600
#define OFF_Wd1   49664
#define OFF_bd1   57856
#define OFF_Wd2   57920
#define OFF_bd2   57984
#define W_TOTAL   57985
#define OFF_BSUM  58016                 // 256 ints (bucket sums / prefixes)
#define OFF_FWD1  58624                 // 8192 fp8 bytes (16*Wd1 frag table)
#define OFF_FWIN  60672                 // 8192 bf16 (W_in frag table)
#define OFF_FWC0  64768                 // 4096 bf16 (Wc0 frag table)
#define OFF_TEMB  66816                 // 128*64 floats
#define OFF_DINV  75008                 // 50000 floats
#define OFF_CNT   125008                // 50000 ints (degree, then fill cursor)
#define OFF_PTR   175008                // 50001 ints
#define OFF_ELIST 225010                // 800000 ints
#define OFF_TMP2  1025012               // dead region; hosts FWC1
#define OFF_ZBF   2625012               // 3.2M bf16 (z0)
#define OFF_ZBF2  4225012               // 3.2M bf16 (z1)
#define OFF_HENC8 5825012               // 3.2M fp8 bytes
// total 6,625,012 floats = 26.5 MB

// Wc1 MFMA frag table (4096 bf16 = 2048 floats) in the dead tmp region.
#define OFF_FWC1  OFF_TMP2

#define SCAN_NB   ((N_NODES + 255) / 256)   // 196 buckets

typedef __attribute__((ext_vector_type(8))) short bf16x8;
typedef __attribute__((ext_vector_type(4))) float f32x4;

static __device__ __forceinline__ float bf2f(unsigned short u) {
    return __uint_as_float(((unsigned)u) << 16);
}
static __device__ __forceinline__ unsigned short f2bf(float f) {
    unsigned u = __float_as_uint(f);
    unsigned r = (u + 0x7fffu + ((u >> 16) & 1u)) >> 16;
    return (unsigned short)r;
}
// fp32 -> fp8 e4m3fn, RNE, clamp to +-448
static __device__ __forceinline__ unsigned char f2fp8(float f) {
    unsigned u = __float_as_uint(f);
    unsigned s = (u >> 24) & 0x80;
    float a = fminf(__uint_as_float(u & 0x7FFFFFFF), 448.0f);
    if (a < 0.015625f) {
        int qi = (int)rintf(a * 512.0f);
        return (unsigned char)(s | qi);
    }
    unsigned ua = __float_as_uint(a);
    int e = (int)((ua >> 23) & 0xFF) - 127;
    unsigned man = (ua & 0x7FFFFF) | 0x800000;
    unsigned r = man >> 20;
    unsigned rem = man & 0xFFFFF;
    if (rem > 0x80000u || (rem == 0x80000u && (r & 1))) r++;
    if (r == 16) { r = 8; e++; }
    if (e > 8) return (unsigned char)(s | 0x7E);
    return (unsigned char)(s | ((unsigned)(e + 7) << 3) | (r & 7));
}
static __device__ __forceinline__ bool detect_f32(const unsigned short* w, int* scnt) {
    if (threadIdx.x == 0) *scnt = 0;
    __syncthreads();
    int big = 0;
    for (int i = threadIdx.x; i < 2048; i += blockDim.x)
        if (fabsf(bf2f(w[2 * i])) > 0.5f) big++;
    atomicAdd(scnt, big);
    __syncthreads();
    return *scnt > 64;
}
// raw-weight load with dtype dispatch
static __device__ __forceinline__ float ldw(const void* p, int idx, bool f32) {
    return f32 ? ((const float*)p)[idx] : bf2f(((const unsigned short*)p)[idx]);
}

// ---------------- CSR build (split kernels, no grid sync) ----------------
__global__ void k_count(const int* __restrict__ col, int* __restrict__ cnt) {
    int t = blockIdx.x * 256 + threadIdx.x;
    if (t < E_MSG) atomicAdd(&cnt[col[t]], 1);
}

__global__ void __launch_bounds__(256) k_scan1(const int* __restrict__ cnt,
                                               int* __restrict__ bsum) {
    __shared__ int s[256];
    int n = blockIdx.x * 256 + threadIdx.x;
    s[threadIdx.x] = (n < N_NODES) ? cnt[n] : 0;
    __syncthreads();
    for (int off = 128; off > 0; off >>= 1) {
        if (threadIdx.x < off) s[threadIdx.x] += s[threadIdx.x + off];
        __syncthreads();
    }
    if (threadIdx.x == 0) bsum[blockIdx.x] = s[0];
}

__global__ void __launch_bounds__(256) k_scan2(int* __restrict__ bsum,
                                               int* __restrict__ ptr) {
    __shared__ int s[256];
    int t = threadIdx.x;
    int v = (t < SCAN_NB) ? bsum[t] : 0;
    s[t] = v;
    __syncthreads();
    for (int off = 1; off < 256; off <<= 1) {
        int u = (t >= off) ? s[t - off] : 0;
        __syncthreads();
        s[t] += u;
        __syncthreads();
    }
    if (t < SCAN_NB) bsum[t] = s[t] - v;       // exclusive bucket prefix
    if (t == 0) ptr[N_NODES] = E_MSG;
}

// ptr + dinv; also rewrites cnt[n] = ptr[n] as the fill cursor
__global__ void __launch_bounds__(256) k_scan3(int* __restrict__ cnt,
                                               const int* __restrict__ bsum,
                                               int* __restrict__ ptr,
                                               float* __restrict__ dinv) {
    __shared__ int s[256];
    int t = threadIdx.x;
    int n = blockIdx.x * 256 + t;
    int v = (n < N_NODES) ? cnt[n] : 0;
    s[t] = v;
    __syncthreads();
    for (int off = 1; off < 256; off <<= 1) {
        int u = (t >= off) ? s[t - off] : 0;
        __syncthreads();
        s[t] += u;
        __syncthreads();
    }
    if (n < N_NODES) {
        int p = bsum[blockIdx.x] + s[t] - v;
        ptr[n] = p;
        cnt[n] = p;                          // fill cursor
        dinv[n] = rsqrtf((float)v + 1.0f);
    }
}

// direct scatter: per-node atomic cursor (order within a node is arbitrary;
// gather sums are order-independent up to fp32 rounding)
__global__ void k_fill(const int* __restrict__ row, const int* __restrict__ col,
                       int* __restrict__ cur, int* __restrict__ elist) {
    int e = blockIdx.x * 256 + threadIdx.x;
    if (e < E_MSG) {
        int pos = atomicAdd(&cur[col[e]], 1);
        elist[pos] = row[e];
    }
}

// ---------------- fused weight prep: cvt + frag tables + temb ----------------
// blocks [0,227): cvt -> ws fp32
// blocks [227,323): MFMA B-frag tables (read RAW weights, convert inline)
// blocks [323,355): t_emb table, 4 timesteps per block (read RAW Wt1/Wt2)
#define WP_CVT_NB  227
#define WP_PREP_NB 96
#define WP_TEMB_NB 32

struct CvtArgs { const void* src[14]; };

__global__ void __launch_bounds__(256) k_wprep(CvtArgs a, float* ws) {
    __shared__ int scnt;
    bool f32 = detect_f32((const unsigned short*)a.src[0], &scnt);
    int bid = blockIdx.x;
    int tid = threadIdx.x;

    if (bid < WP_CVT_NB) {
        int t = bid * 256 + tid;
        if (t >= W_TOTAL) return;
        const int starts[14] = {OFF_Win, OFF_bin, OFF_Wt1, OFF_bt1, OFF_Wt2, OFF_bt2,
                                OFF_Wc0, OFF_bc0, OFF_Wc1, OFF_bc1, OFF_Wd1, OFF_bd1,
                                OFF_Wd2, OFF_bd2};
        int seg = 0;
#pragma unroll
        for (int i = 1; i < 14; i++)
            if (t >= starts[i]) seg = i;
        ws[t] = ldw(a.src[seg], t - starts[seg], f32);
    } else if (bid < WP_CVT_NB + WP_PREP_NB) {
        int idx = (bid - WP_CVT_NB) * 256 + tid;       // 0..24575
        int local, j, lane, ct, c, t, m, q;
        if (idx < 8192) {
            local = idx;
            j = local & 7; lane = (local >> 3) & 63; ct = local >> 9;
            c = ct >> 2; t = ct & 3; m = lane & 15; q = lane >> 4;
            ((unsigned char*)(ws + OFF_FWD1))[local] =
                f2fp8(16.0f * ldw(a.src[10], (32 * c + 8 * q + j) * 64 + 16 * t + m, f32));
        } else if (idx < 16384) {
            local = idx - 8192;
            j = local & 7; lane = (local >> 3) & 63; ct = local >> 9;
            c = ct >> 2; t = ct & 3; m = lane & 15; q = lane >> 4;
            ((unsigned short*)(ws + OFF_FWIN))[local] =
                f2bf(ldw(a.src[0], (32 * c + 8 * q + j) * 64 + 16 * t + m, f32));
        } else if (idx < 20480) {
            local = idx - 16384;
            j = local & 7; lane = (local >> 3) & 63; ct = local >> 9;
            c = ct >> 2; t = ct & 3; m = lane & 15; q = lane >> 4;
            ((unsigned short*)(ws + OFF_FWC0))[local] =
                f2bf(ldw(a.src[6], (32 * c + 8 * q + j) * 64 + 16 * t + m, f32));
        } else {
            local = idx - 20480;
            j = local & 7; lane = (local >> 3) & 63; ct = local >> 9;
            c = ct >> 2; t = ct & 3; m = lane & 15; q = lane >> 4;
            ((unsigned short*)(ws + OFF_FWC1))[local] =
                f2bf(ldw(a.src[8], (32 * c + 8 * q + j) * 64 + 16 * t + m, f32));
        }
    } else {
        // t_emb: 4 timesteps per block, 64 threads each
        __shared__ float pe[4][64];
        __shared__ float us[4][256];
        int g = tid >> 6;
        int j = tid & 63;
        int t = (bid - WP_CVT_NB - WP_PREP_NB) * 4 + g;

        float xt = (float)t * (4000.0f / 128.0f);
        float sc = -logf(10000.0f) / 31.0f;
        int idx = j & 31;
        float fr = __expf((float)idx * sc);
        float ang = xt * fr;
        pe[g][j] = (j < 32) ? sinf(ang) : cosf(ang);
        __syncthreads();

        float u[4];
#pragma unroll
        for (int q = 0; q < 4; q++) u[q] = ldw(a.src[3], q * 64 + j, f32);
        for (int k = 0; k < 64; k++) {
            float p = pe[g][k];
#pragma unroll
            for (int q = 0; q < 4; q++)
                u[q] = fmaf(p, ldw(a.src[2], k * 256 + q * 64 + j, f32), u[q]);
        }
#pragma unroll
        for (int q = 0; q < 4; q++) {
            float uu = u[q];
            us[g][q * 64 + j] = uu * __builtin_amdgcn_rcpf(1.0f + __expf(-uu));
        }
        __syncthreads();

        float acc = ldw(a.src[5], j, f32);
        for (int k = 0; k < 256; k++)
            acc = fmaf(us[g][k], ldw(a.src[4], k * 64 + j, f32), acc);
        (ws + OFF_TEMB)[t * 64 + j] = acc;
    }
}

// ---------------- embedder + fused GCN-linear-0 (MFMA x2) ----------------
__global__ void __launch_bounds__(256) k_embed(const void* __restrict__ xraw,
                                               const unsigned short* __restrict__ wdet,
                                               const int* __restrict__ tsteps,
                                               float* __restrict__ ws,
                                               float* __restrict__ out_hembed,
                                               unsigned short* __restrict__ zbf) {
    __shared__ int scnt;
    __shared__ unsigned short tl[4][16 * 64];
    bool f32 = detect_f32(wdet, &scnt);

    int lane = threadIdx.x & 63;
    int wv = threadIdx.x >> 6;
    int m = lane & 15, quad = lane >> 4;
    int wid = blockIdx.x * 4 + wv;
    if (wid > N_NODES / 16 - 1) wid = N_NODES / 16 - 1;   // clamp (dup work benign)
    int n0 = wid * 16;

    const unsigned short* fwin = (const unsigned short*)(ws + OFF_FWIN);
    const unsigned short* fwc0 = (const unsigned short*)(ws + OFF_FWC0);

    bf16x8 bI[4][4];
#pragma unroll
    for (int c = 0; c < 4; c++)
#pragma unroll
        for (int t = 0; t < 4; t++)
            bI[c][t] = *reinterpret_cast<const bf16x8*>(fwin + (c * 4 + t) * 512 + lane * 8);

    f32x4 acc[4] = {f32x4{0,0,0,0}, f32x4{0,0,0,0}, f32x4{0,0,0,0}, f32x4{0,0,0,0}};
#pragma unroll
    for (int c = 0; c < 4; c++) {
        bf16x8 a;
        if (f32) {
            const float* xp = (const float*)xraw + (size_t)(n0 + m) * 128 + 32 * c + 8 * quad;
            float4 v0 = *reinterpret_cast<const float4*>(xp);
            float4 v1 = *reinterpret_cast<const float4*>(xp + 4);
            a[0] = (short)f2bf(v0.x); a[1] = (short)f2bf(v0.y);
            a[2] = (short)f2bf(v0.z); a[3] = (short)f2bf(v0.w);
            a[4] = (short)f2bf(v1.x); a[5] = (short)f2bf(v1.y);
            a[6] = (short)f2bf(v1.z); a[7] = (short)f2bf(v1.w);
        } else {
            a = *reinterpret_cast<const bf16x8*>(
                (const unsigned short*)xraw + (size_t)(n0 + m) * 128 + 32 * c + 8 * quad);
        }
#pragma unroll
        for (int t = 0; t < 4; t++)
            acc[t] = __builtin_amdgcn_mfma_f32_16x16x32_bf16(a, bI[c][t], acc[t], 0, 0, 0);
    }

    int tn[4];
#pragma unroll
    for (int r = 0; r < 4; r++) tn[r] = tsteps[n0 + 4 * quad + r];
    const float* temb = ws + OFF_TEMB;
#pragma unroll
    for (int t = 0; t < 4; t++) {
        int ch = 16 * t + m;
        float bj = ws[OFF_bin + ch];
#pragma unroll
        for (int r = 0; r < 4; r++) {
            int node = n0 + 4 * quad + r;
            float v = acc[t][r] + bj + temb[tn[r] * 64 + ch];
            out_hembed[(size_t)node * 64 + ch] = v;
            tl[wv][(4 * quad + r) * 64 + ch] = f2bf(v);
        }
    }
    __syncthreads();

    bf16x8 bC[2][4];
#pragma unroll
    for (int c = 0; c < 2; c++)
#pragma unroll
        for (int t = 0; t < 4; t++)
            bC[c][t] = *reinterpret_cast<const bf16x8*>(fwc0 + (c * 4 + t) * 512 + lane * 8);

    f32x4 az[4] = {f32x4{0,0,0,0}, f32x4{0,0,0,0}, f32x4{0,0,0,0}, f32x4{0,0,0,0}};
#pragma unroll
    for (int c = 0; c < 2; c++) {
        bf16x8 a2 = *reinterpret_cast<const bf16x8*>(&tl[wv][m * 64 + 32 * c + 8 * quad]);
#pragma unroll
        for (int t = 0; t < 4; t++)
            az[t] = __builtin_amdgcn_mfma_f32_16x16x32_bf16(a2, bC[c][t], az[t], 0, 0, 0);
    }
    const float* dinv = ws + OFF_DINV;
    float dv[4];
#pragma unroll
    for (int r = 0; r < 4; r++) dv[r] = dinv[n0 + 4 * quad + r];
#pragma unroll
    for (int t = 0; t < 4; t++) {
        int ch = 16 * t + m;
#pragma unroll
        for (int r = 0; r < 4; r++)
            zbf[(size_t)(n0 + 4 * quad + r) * 64 + ch] = f2bf(az[t][r] * dv[r]);
    }
}

// ---------------- gather-0 + relu + fused GCN-linear-1 (MFMA) ----------------
__global__ void __launch_bounds__(256) k_gather0(const unsigned short* __restrict__ zbf,
                                                 const int* __restrict__ ptr,
                                                 const int* __restrict__ elist,
                                                 const float* __restrict__ ws,
                                                 unsigned short* __restrict__ zout) {
    __shared__ unsigned short tile[16 * 64];     // 2KB, swizzled bf16 [16][64]
    const float* dinv = ws + OFF_DINV;
    const float* bias = ws + OFF_bc0;
    const unsigned short* fwc1 = (const unsigned short*)(ws + OFF_FWC1);

    int lane = threadIdx.x & 63;
    int wv = threadIdx.x >> 6;
    int g = lane >> 4;              // neighbor sub-group 0..3
    int cl = lane & 15;             // channel quad: channels 4cl..4cl+3
    int n0 = blockIdx.x * 16;

    float4 b4 = *reinterpret_cast<const float4*>(bias + 4 * cl);

#pragma unroll
    for (int snode = 0; snode < 4; snode++) {
        int li = wv * 4 + snode;    // local tile row
        int n = n0 + li;
        int base = ptr[n], end = ptr[n + 1];

        float ws0 = (g == 0) ? 1.0f : 0.0f;
        ushort4 sv = *reinterpret_cast<const ushort4*>(zbf + (size_t)n * 64 + cl * 4);
        float s0 = ws0 * bf2f(sv.x), s1 = ws0 * bf2f(sv.y);
        float s2 = ws0 * bf2f(sv.z), s3 = ws0 * bf2f(sv.w);

        for (int k = base; k < end; k += 8) {
            int e0 = k + g, e1 = k + 4 + g;
            int r0 = elist[min(e0, end - 1)];
            int r1 = elist[min(e1, end - 1)];
            ushort4 v0 = *reinterpret_cast<const ushort4*>(zbf + (size_t)r0 * 64 + cl * 4);
            ushort4 v1 = *reinterpret_cast<const ushort4*>(zbf + (size_t)r1 * 64 + cl * 4);
            float w0 = (e0 < end) ? 1.0f : 0.0f;
            float w1 = (e1 < end) ? 1.0f : 0.0f;
            s0 = fmaf(w0, bf2f(v0.x), s0); s1 = fmaf(w0, bf2f(v0.y), s1);
            s2 = fmaf(w0, bf2f(v0.z), s2); s3 = fmaf(w0, bf2f(v0.w), s3);
            s0 = fmaf(w1, bf2f(v1.x), s0); s1 = fmaf(w1, bf2f(v1.y), s1);
            s2 = fmaf(w1, bf2f(v1.z), s2); s3 = fmaf(w1, bf2f(v1.w), s3);
        }
        s0 += __shfl_xor(s0, 16, 64); s0 += __shfl_xor(s0, 32, 64);
        s1 += __shfl_xor(s1, 16, 64); s1 += __shfl_xor(s1, 32, 64);
        s2 += __shfl_xor(s2, 16, 64); s2 += __shfl_xor(s2, 32, 64);
        s3 += __shfl_xor(s3, 16, 64); s3 += __shfl_xor(s3, 32, 64);

        if (g == 0) {
            float dv = dinv[n];
            float h0 = fmaxf(fmaf(dv, s0, b4.x), 0.0f);
            float h1 = fmaxf(fmaf(dv, s1, b4.y), 0.0f);
            float h2 = fmaxf(fmaf(dv, s2, b4.z), 0.0f);
            float h3 = fmaxf(fmaf(dv, s3, b4.w), 0.0f);
            ushort4 hv;
            hv.x = f2bf(h0); hv.y = f2bf(h1); hv.z = f2bf(h2); hv.w = f2bf(h3);
            int bo = li * 128 + ((cl * 8) ^ ((li & 7) << 4));   // XOR-swizzle (G4)
            *reinterpret_cast<ushort4*>((char*)tile + bo) = hv;
        }
    }
    __syncthreads();

    // phase 2: wave wv computes output channels 16*wv..16*wv+15 for all 16 nodes
    int m = lane & 15, q = lane >> 4;
    bf16x8 bB0 = *reinterpret_cast<const bf16x8*>(fwc1 + (0 * 4 + wv) * 512 + lane * 8);
    bf16x8 bB1 = *reinterpret_cast<const bf16x8*>(fwc1 + (1 * 4 + wv) * 512 + lane * 8);

    f32x4 az = f32x4{0, 0, 0, 0};
    {
        int bo0 = m * 128 + ((0 * 64 + q * 16) ^ ((m & 7) << 4));
        bf16x8 a0 = *reinterpret_cast<const bf16x8*>((const char*)tile + bo0);
        az = __builtin_amdgcn_mfma_f32_16x16x32_bf16(a0, bB0, az, 0, 0, 0);
        int bo1 = m * 128 + ((1 * 64 + q * 16) ^ ((m & 7) << 4));
        bf16x8 a1 = *reinterpret_cast<const bf16x8*>((const char*)tile + bo1);
        az = __builtin_amdgcn_mfma_f32_16x16x32_bf16(a1, bB1, az, 0, 0, 0);
    }
    float dv4[4];
#pragma unroll
    for (int r = 0; r < 4; r++) dv4[r] = dinv[n0 + 4 * q + r];
#pragma unroll
    for (int r = 0; r < 4; r++) {
        int node = n0 + 4 * q + r;
        zout[(size_t)node * 64 + 16 * wv + m] = f2bf(az[r] * dv4[r]);
    }
}

// ---------------- gather-1 -> h_enc (fp32 out + fp8x16 table) ----------------
__global__ void __launch_bounds__(256) k_gather1(const unsigned short* __restrict__ zbf,
                                                 const int* __restrict__ ptr,
                                                 const int* __restrict__ elist,
                                                 const float* __restrict__ dinv,
                                                 const float* __restrict__ bias,
                                                 unsigned char* __restrict__ henc8,
                                                 float* __restrict__ ofp) {
    int lane = threadIdx.x & 63;
    int n = blockIdx.x * 4 + (threadIdx.x >> 6);
    int g = lane >> 4;
    int cl = lane & 15;
    int base = ptr[n], end = ptr[n + 1];

    float4 b4 = *reinterpret_cast<const float4*>(bias + 4 * cl);

    float ws0 = (g == 0) ? 1.0f : 0.0f;
    ushort4 sv = *reinterpret_cast<const ushort4*>(zbf + (size_t)n * 64 + cl * 4);
    float s0 = ws0 * bf2f(sv.x), s1 = ws0 * bf2f(sv.y);
    float s2 = ws0 * bf2f(sv.z), s3 = ws0 * bf2f(sv.w);

    for (int k = base; k < end; k += 8) {
        int e0 = k + g, e1 = k + 4 + g;
        int r0 = elist[min(e0, end - 1)];
        int r1 = elist[min(e1, end - 1)];
        ushort4 v0 = *reinterpret_cast<const ushort4*>(zbf + (size_t)r0 * 64 + cl * 4);
        ushort4 v1 = *reinterpret_cast<const ushort4*>(zbf + (size_t)r1 * 64 + cl * 4);
        float w0 = (e0 < end) ? 1.0f : 0.0f;
        float w1 = (e1 < end) ? 1.0f : 0.0f;
        s0 = fmaf(w0, bf2f(v0.x), s0); s1 = fmaf(w0, bf2f(v0.y), s1);
        s2 = fmaf(w0, bf2f(v0.z), s2); s3 = fmaf(w0, bf2f(v0.w), s3);
        s0 = fmaf(w1, bf2f(v1.x), s0); s1 = fmaf(w1, bf2f(v1.y), s1);
        s2 = fmaf(w1, bf2f(v1.z), s2); s3 = fmaf(w1, bf2f(v1.w), s3);
    }
    s0 += __shfl_xor(s0, 16, 64); s0 += __shfl_xor(s0, 32, 64);
    s1 += __shfl_xor(s1, 16, 64); s1 += __shfl_xor(s1, 32, 64);
    s2 += __shfl_xor(s2, 16, 64); s2 += __shfl_xor(s2, 32, 64);
    s3 += __shfl_xor(s3, 16, 64); s3 += __shfl_xor(s3, 32, 64);

    float dv = dinv[n];
    float o0 = fmaf(dv, s0, b4.x);
    float o1 = fmaf(dv, s1, b4.y);
    float o2 = fmaf(dv, s2, b4.z);
    float o3 = fmaf(dv, s3, b4.w);

    if (g == 0) {
        float4 ov; ov.x = o0; ov.y = o1; ov.z = o2; ov.w = o3;
        *reinterpret_cast<float4*>(ofp + (size_t)n * 64 + cl * 4) = ov;
    }
    // redistribute: lane converts channel `lane`
    int jc = lane >> 2;
    float a0 = __shfl(o0, jc, 64);
    float a1 = __shfl(o1, jc, 64);
    float a2 = __shfl(o2, jc, 64);
    float a3 = __shfl(o3, jc, 64);
    int sel = lane & 3;
    float mv = (sel == 0) ? a0 : (sel == 1) ? a1 : (sel == 2) ? a2 : a3;
    henc8[(size_t)n * 64 + lane] = f2fp8(16.0f * mv);
}

// ---------------- edge decoder (MFMA fp8, pipelined) ----------------
#define DEC_TPW 4
#define DEC_TILES (E_FULL / 16)

__global__ void __launch_bounds__(256) k_dec(const int* __restrict__ src,
                                             const int* __restrict__ dst,
                                             const unsigned char* __restrict__ h8,
                                             const float* __restrict__ ws,
                                             float* __restrict__ out) {
    int lane = threadIdx.x & 63;
    int wv = threadIdx.x >> 6;
    int m = lane & 15;
    int quad = lane >> 4;

    const unsigned char* fw = (const unsigned char*)(ws + OFF_FWD1);
    long bfr[4][4];
#pragma unroll
    for (int c = 0; c < 4; c++)
#pragma unroll
        for (int t = 0; t < 4; t++)
            bfr[c][t] = *reinterpret_cast<const long*>(fw + ((c * 4 + t) * 512 + lane * 8));

    float w2[4], b1v[4];
#pragma unroll
    for (int t = 0; t < 4; t++) {
        w2[t]  = ws[OFF_Wd2 + 16 * t + m];
        b1v[t] = ws[OFF_bd1 + 16 * t + m];
    }
    float b2 = ws[OFF_bd2];

    int tile0 = (blockIdx.x * 4 + wv) * DEC_TPW;
    int tc = min(tile0, DEC_TILES - 1);
    int s0 = src[tc * 16 + m], d0 = dst[tc * 16 + m];
    tc = min(tile0 + 1, DEC_TILES - 1);
    int s1 = src[tc * 16 + m], d1 = dst[tc * 16 + m];
    long A0[4];
#pragma unroll
    for (int c = 0; c < 4; c++) {
        int row = (c < 2) ? s0 : d0;
        A0[c] = *reinterpret_cast<const long*>(
            h8 + (size_t)row * 64 + (c & 1) * 32 + 8 * quad);
    }

    for (int i = 0; i < DEC_TPW; i++) {
        int tile = tile0 + i;
        int t2 = min(tile0 + i + 2, DEC_TILES - 1);
        int s2 = src[t2 * 16 + m], d2 = dst[t2 * 16 + m];
        long A1[4];
#pragma unroll
        for (int c = 0; c < 4; c++) {
            int row = (c < 2) ? s1 : d1;
            A1[c] = *reinterpret_cast<const long*>(
                h8 + (size_t)row * 64 + (c & 1) * 32 + 8 * quad);
        }
        f32x4 acc[4] = {f32x4{0,0,0,0}, f32x4{0,0,0,0}, f32x4{0,0,0,0}, f32x4{0,0,0,0}};
#pragma unroll
        for (int c = 0; c < 4; c++)
#pragma unroll
            for (int t = 0; t < 4; t++)
                acc[t] = __builtin_amdgcn_mfma_f32_16x16x32_fp8_fp8(A0[c], bfr[c][t], acc[t], 0, 0, 0);
        float sums[4];
#pragma unroll
        for (int r = 0; r < 4; r++) {
            float sv = 0.0f;
#pragma unroll
            for (int t = 0; t < 4; t++) {
                float v = fmaf(acc[t][r], 0.00390625f, b1v[t]);   // /256 un-scale
                float h = v * __builtin_amdgcn_rcpf(1.0f + __expf(-v));
                sv = fmaf(h, w2[t], sv);
            }
#pragma unroll
            for (int msk = 8; msk >= 1; msk >>= 1)
                sv += __shfl_xor(sv, msk, 64);
            sums[r] = sv;
        }
        if (m == 0 && tile < DEC_TILES) {
            float4 o;
            o.x = sums[0] + b2; o.y = sums[1] + b2;
            o.z = sums[2] + b2; o.w = sums[3] + b2;
            *reinterpret_cast<float4*>(out + tile * 16 + 4 * quad) = o;
        }
#pragma unroll
        for (int c = 0; c < 4; c++) A0[c] = A1[c];
        s1 = s2; d1 = d2;
    }
}

extern "C" void kernel_launch(void* const* d_in, const int* in_sizes, int n_in,
                              void* d_out, int out_size, void* d_ws, size_t ws_size,
                              hipStream_t stream) {
    if (n_in < 18) return;
    const void* x              = d_in[0];
    const int* edge_index      = (const int*)d_in[1];
    const int* full_edge_index = (const int*)d_in[2];
    const int* tsteps          = (const int*)d_in[3];
    float* ws = (float*)d_ws;
    float* out = (float*)d_out;

    int*   iws   = (int*)d_ws;
    int*   bsum  = iws + OFF_BSUM;
    int*   cnt   = iws + OFF_CNT;
    int*   ptr   = iws + OFF_PTR;
    int*   elist = iws + OFF_ELIST;
    unsigned short* zbf  = (unsigned short*)(ws + OFF_ZBF);
    unsigned short* zbf2 = (unsigned short*)(ws + OFF_ZBF2);
    unsigned char*  h8   = (unsigned char*)(ws + OFF_HENC8);

    CvtArgs ca;
    for (int i = 0; i < 14; i++) ca.src[i] = d_in[4 + i];

    // CSR build (by dst) + dinv — direct scatter with per-node cursors
    hipMemsetAsync(cnt, 0, (size_t)N_NODES * 4, stream);
    k_count<<<(E_MSG + 255) / 256, 256, 0, stream>>>(edge_index + E_MSG, cnt);
    k_scan1<<<SCAN_NB, 256, 0, stream>>>(cnt, bsum);
    k_scan2<<<1, 256, 0, stream>>>(bsum, ptr);
    k_scan3<<<SCAN_NB, 256, 0, stream>>>(cnt, bsum, ptr, ws + OFF_DINV);
    k_fill<<<(E_MSG + 255) / 256, 256, 0, stream>>>(edge_index, edge_index + E_MSG,
                                                    cnt, elist);

    // fused weight prep: cvt + frag tables (incl. Wc1 in dead tmp region) + t_emb
    k_wprep<<<WP_CVT_NB + WP_PREP_NB + WP_TEMB_NB, 256, 0, stream>>>(ca, ws);

    // embedder + fused lin0 (h_embed -> d_out fp32; z0 -> zbf)
    k_embed<<<(N_NODES / 16 + 3) / 4, 256, 0, stream>>>(
        x, (const unsigned short*)d_in[4], tsteps, ws, out + E_FULL, zbf);

    // gather0 + relu + fused lin1 (MFMA): zbf -> zbf2
    k_gather0<<<N_NODES / 16, 256, 0, stream>>>(zbf, ptr, elist, ws, zbf2);

    // gather1: zbf2 -> {out fp32, h8 fp8x16}
    k_gather1<<<N_NODES / 4, 256, 0, stream>>>(
        zbf2, ptr, elist, ws + OFF_DINV, ws + OFF_bc1, h8,
        out + E_FULL + (size_t)N_NODES * 64);

    // decoder (fp8 MFMA)
    int dec_blocks = (DEC_TILES + 4 * DEC_TPW - 1) / (4 * DEC_TPW);
    k_dec<<<dec_blocks, 256, 0, stream>>>(full_edge_index, full_edge_index + E_FULL,
                                          h8, ws, out);
}

// Round 4
// 263.258 us; speedup vs baseline: 2.1934x; 1.3300x over previous
//
#include <hip/hip_runtime.h>
#include <hip/hip_bf16.h>
#include <math.h>

#define N_NODES 50000
#define E_MSG   800000
#define E_FULL  1000000
#define IN_C    128
#define H_C     64
#define T_STEPS 128

// ---- workspace layout (in floats) ----
#define OFF_Win   0
#define OFF_bin   8192
#define OFF_Wt1   8256
#define OFF_bt1   24640
#define OFF_Wt2   24896
#define OFF_bt2   41280
#define OFF_Wc0   41344
#define OFF_bc0   45440
#define OFF_Wc1   45504
#define OFF_bc1   49600
#define OFF_Wd1   49664
#define OFF_bd1   57856
#define OFF_Wd2   57920
#define OFF_bd2   57984
#define W_TOTAL   57985
#define OFF_BSUM  58016                 // 256 ints (bucket totals -> excl prefix)
#define OFF_BCUR  58272                 // 256 ints (bucket fill cursors)
#define OFF_FWD1  58624                 // 8192 fp8 bytes (16*Wd1 frag table)
#define OFF_FWIN  60672                 // 8192 bf16 (W_in frag table)
#define OFF_FWC0  64768                 // 4096 bf16 (Wc0 frag table)
#define OFF_TEMB  66816                 // 128*64 floats
#define OFF_DINV  75008                 // 50000 floats
#define OFF_CNT   125008                // (unused now)
#define OFF_PTR   175008                // 50001 ints
#define OFF_ELIST 225010                // 800000 ints
#define OFF_TMP2  1025012               // 1.6M ints (800000 uint2), 8B aligned
#define OFF_ZBF   2625012               // 3.2M bf16 (z0)
#define OFF_ZBF2  4225012               // 3.2M bf16 (z1)
#define OFF_HENC8 5825012               // 3.2M fp8 bytes
// total 6,625,012 floats = 26.5 MB

// Wc1 MFMA frag table overlays tmp: bfill writes tmp -> csort2 reads tmp ->
// wprep writes FWC1 -> gather0 reads FWC1. Stream-serial => safe.
#define OFF_FWC1  OFF_TMP2

#define SCAN_NB   ((N_NODES + 255) / 256)   // 196 buckets
#define BF_CH     ((E_MSG + SCAN_NB - 1) / SCAN_NB)   // 4082 edges/block
#define BC_NB     392
#define BC_CH     ((E_MSG + BC_NB - 1) / BC_NB)       // 2041 edges/block

typedef __attribute__((ext_vector_type(8))) short bf16x8;
typedef __attribute__((ext_vector_type(4))) float f32x4;

static __device__ __forceinline__ float bf2f(unsigned short u) {
    return __uint_as_float(((unsigned)u) << 16);
}
static __device__ __forceinline__ unsigned short f2bf(float f) {
    unsigned u = __float_as_uint(f);
    unsigned r = (u + 0x7fffu + ((u >> 16) & 1u)) >> 16;
    return (unsigned short)r;
}
// fp32 -> fp8 e4m3fn, RNE, clamp to +-448
static __device__ __forceinline__ unsigned char f2fp8(float f) {
    unsigned u = __float_as_uint(f);
    unsigned s = (u >> 24) & 0x80;
    float a = fminf(__uint_as_float(u & 0x7FFFFFFF), 448.0f);
    if (a < 0.015625f) {
        int qi = (int)rintf(a * 512.0f);
        return (unsigned char)(s | qi);
    }
    unsigned ua = __float_as_uint(a);
    int e = (int)((ua >> 23) & 0xFF) - 127;
    unsigned man = (ua & 0x7FFFFF) | 0x800000;
    unsigned r = man >> 20;
    unsigned rem = man & 0xFFFFF;
    if (rem > 0x80000u || (rem == 0x80000u && (r & 1))) r++;
    if (r == 16) { r = 8; e++; }
    if (e > 8) return (unsigned char)(s | 0x7E);
    return (unsigned char)(s | ((unsigned)(e + 7) << 3) | (r & 7));
}
static __device__ __forceinline__ bool detect_f32(const unsigned short* w, int* scnt) {
    if (threadIdx.x == 0) *scnt = 0;
    __syncthreads();
    int big = 0;
    for (int i = threadIdx.x; i < 2048; i += blockDim.x)
        if (fabsf(bf2f(w[2 * i])) > 0.5f) big++;
    atomicAdd(scnt, big);
    __syncthreads();
    return *scnt > 64;
}
// raw-weight load with dtype dispatch
static __device__ __forceinline__ float ldw(const void* p, int idx, bool f32) {
    return f32 ? ((const float*)p)[idx] : bf2f(((const unsigned short*)p)[idx]);
}

// ---------------- CSR build ----------------
// bucket totals only: per-block LDS 196-bin histogram -> 196 global atomics/block
__global__ void __launch_bounds__(256) k_bcount(const int* __restrict__ col,
                                                int* __restrict__ bsum) {
    __shared__ int hist[SCAN_NB];
    int b = blockIdx.x, t = threadIdx.x;
    for (int i = t; i < SCAN_NB; i += 256) hist[i] = 0;
    __syncthreads();
    int lo = b * BC_CH;
    int hi = lo + BC_CH; if (hi > E_MSG) hi = E_MSG;
    for (int e = lo + t; e < hi; e += 256)
        atomicAdd(&hist[col[e] >> 8], 1);
    __syncthreads();
    for (int i = t; i < SCAN_NB; i += 256) {
        int c = hist[i];
        if (c > 0) atomicAdd(&bsum[i], c);
    }
}

// exclusive prefix over buckets; init bucket cursors
__global__ void __launch_bounds__(256) k_scan2(int* __restrict__ bsum,
                                               int* __restrict__ bcur,
                                               int* __restrict__ ptr) {
    __shared__ int s[256];
    int t = threadIdx.x;
    int v = (t < SCAN_NB) ? bsum[t] : 0;
    s[t] = v;
    __syncthreads();
    for (int off = 1; off < 256; off <<= 1) {
        int u = (t >= off) ? s[t - off] : 0;
        __syncthreads();
        s[t] += u;
        __syncthreads();
    }
    if (t < SCAN_NB) { bsum[t] = s[t] - v; bcur[t] = s[t] - v; }
    if (t == 0) ptr[N_NODES] = E_MSG;
}

// bucketed scatter: per-block LDS histogram + one reservation atomic per
// (block, bucket)
__global__ void __launch_bounds__(256) k_bfill(const int* __restrict__ row,
                                               const int* __restrict__ col,
                                               int* __restrict__ bcur,
                                               uint2* __restrict__ tmp) {
    __shared__ int hist[SCAN_NB];
    __shared__ int basew[SCAN_NB];
    int b = blockIdx.x;
    int lo = b * BF_CH;
    int hi = lo + BF_CH; if (hi > E_MSG) hi = E_MSG;
    for (int i = threadIdx.x; i < SCAN_NB; i += 256) hist[i] = 0;
    __syncthreads();
    for (int e = lo + threadIdx.x; e < hi; e += 256)
        atomicAdd(&hist[col[e] >> 8], 1);
    __syncthreads();
    for (int i = threadIdx.x; i < SCAN_NB; i += 256) {
        int c = hist[i];
        basew[i] = (c > 0) ? atomicAdd(&bcur[i], c) : 0;
    }
    __syncthreads();
    for (int i = threadIdx.x; i < SCAN_NB; i += 256) hist[i] = 0;  // reuse as cursor
    __syncthreads();
    for (int e = lo + threadIdx.x; e < hi; e += 256) {
        int src = row[e], c = col[e];
        int bk = c >> 8;
        int off = atomicAdd(&hist[bk], 1);
        tmp[basew[bk] + off] = uint2{(unsigned)src, (unsigned)c};
    }
}

// per bucket: LDS degree count + prefix -> ptr/dinv, then LDS-cursor scatter.
// No per-node GLOBAL atomics anywhere.
__global__ void __launch_bounds__(256) k_csort2(const uint2* __restrict__ tmp,
                                                const int* __restrict__ bsum,
                                                int* __restrict__ ptr,
                                                float* __restrict__ dinv,
                                                int* __restrict__ elist) {
    __shared__ int deg[256];
    __shared__ int pfx[256];
    int b = blockIdx.x, t = threadIdx.x;
    int start = bsum[b];
    int end = (b == SCAN_NB - 1) ? E_MSG : bsum[b + 1];

    deg[t] = 0;
    __syncthreads();
    for (int e = start + t; e < end; e += 256)
        atomicAdd(&deg[tmp[e].y & 255], 1);
    __syncthreads();

    int v = deg[t];
    pfx[t] = v;
    __syncthreads();
    for (int off = 1; off < 256; off <<= 1) {
        int u = (t >= off) ? pfx[t - off] : 0;
        __syncthreads();
        pfx[t] += u;
        __syncthreads();
    }
    int excl = pfx[t] - v;
    int n = (b << 8) + t;
    if (n < N_NODES) {
        ptr[n] = start + excl;
        dinv[n] = rsqrtf((float)v + 1.0f);
    }
    __syncthreads();
    deg[t] = excl;                       // reuse as local cursor
    __syncthreads();
    for (int e = start + t; e < end; e += 256) {
        uint2 p = tmp[e];
        int pos = atomicAdd(&deg[p.y & 255], 1);
        elist[start + pos] = (int)p.x;
    }
}

// ---------------- fused weight prep: cvt + frag tables + temb ----------------
// blocks [0,227): cvt -> ws fp32
// blocks [227,323): MFMA B-frag tables (read RAW weights, convert inline)
// blocks [323,451): t_emb, ONE timestep per block, 4-way k-split (latency fix)
#define WP_CVT_NB  227
#define WP_PREP_NB 96
#define WP_TEMB_NB 128

struct CvtArgs { const void* src[14]; };

__global__ void __launch_bounds__(256) k_wprep(CvtArgs a, float* ws) {
    __shared__ int scnt;
    bool f32 = detect_f32((const unsigned short*)a.src[0], &scnt);
    int bid = blockIdx.x;
    int tid = threadIdx.x;

    if (bid < WP_CVT_NB) {
        int t = bid * 256 + tid;
        if (t >= W_TOTAL) return;
        const int starts[14] = {OFF_Win, OFF_bin, OFF_Wt1, OFF_bt1, OFF_Wt2, OFF_bt2,
                                OFF_Wc0, OFF_bc0, OFF_Wc1, OFF_bc1, OFF_Wd1, OFF_bd1,
                                OFF_Wd2, OFF_bd2};
        int seg = 0;
#pragma unroll
        for (int i = 1; i < 14; i++)
            if (t >= starts[i]) seg = i;
        ws[t] = ldw(a.src[seg], t - starts[seg], f32);
    } else if (bid < WP_CVT_NB + WP_PREP_NB) {
        int idx = (bid - WP_CVT_NB) * 256 + tid;       // 0..24575
        int local, j, lane, ct, c, t, m, q;
        if (idx < 8192) {
            local = idx;
            j = local & 7; lane = (local >> 3) & 63; ct = local >> 9;
            c = ct >> 2; t = ct & 3; m = lane & 15; q = lane >> 4;
            ((unsigned char*)(ws + OFF_FWD1))[local] =
                f2fp8(16.0f * ldw(a.src[10], (32 * c + 8 * q + j) * 64 + 16 * t + m, f32));
        } else if (idx < 16384) {
            local = idx - 8192;
            j = local & 7; lane = (local >> 3) & 63; ct = local >> 9;
            c = ct >> 2; t = ct & 3; m = lane & 15; q = lane >> 4;
            ((unsigned short*)(ws + OFF_FWIN))[local] =
                f2bf(ldw(a.src[0], (32 * c + 8 * q + j) * 64 + 16 * t + m, f32));
        } else if (idx < 20480) {
            local = idx - 16384;
            j = local & 7; lane = (local >> 3) & 63; ct = local >> 9;
            c = ct >> 2; t = ct & 3; m = lane & 15; q = lane >> 4;
            ((unsigned short*)(ws + OFF_FWC0))[local] =
                f2bf(ldw(a.src[6], (32 * c + 8 * q + j) * 64 + 16 * t + m, f32));
        } else {
            local = idx - 20480;
            j = local & 7; lane = (local >> 3) & 63; ct = local >> 9;
            c = ct >> 2; t = ct & 3; m = lane & 15; q = lane >> 4;
            ((unsigned short*)(ws + OFF_FWC1))[local] =
                f2bf(ldw(a.src[8], (32 * c + 8 * q + j) * 64 + 16 * t + m, f32));
        }
    } else {
        // t_emb: one timestep per block; threads (j = tid&63, kg = tid>>6)
        __shared__ float pe[64];
        __shared__ float us4[4][256];
        __shared__ float us[256];
        __shared__ float pcs[4][64];
        int j = tid & 63;
        int kg = tid >> 6;
        int t = bid - WP_CVT_NB - WP_PREP_NB;

        if (tid < 64) {
            float xt = (float)t * (4000.0f / 128.0f);
            float sc = -logf(10000.0f) / 31.0f;
            float fr = __expf((float)(tid & 31) * sc);
            float ang = xt * fr;
            pe[tid] = (tid < 32) ? sinf(ang) : cosf(ang);
        }
        __syncthreads();

        // phase B: u[ch] partials over k in [16kg, 16kg+16)
        float pu[4] = {0.f, 0.f, 0.f, 0.f};
#pragma unroll
        for (int kk = 0; kk < 16; kk++) {
            int k = 16 * kg + kk;
            float p = pe[k];
#pragma unroll
            for (int q = 0; q < 4; q++)
                pu[q] = fmaf(p, ldw(a.src[2], k * 256 + q * 64 + j, f32), pu[q]);
        }
#pragma unroll
        for (int q = 0; q < 4; q++) us4[kg][q * 64 + j] = pu[q];
        __syncthreads();

        // reduce + silu: thread tid owns channel tid (0..255)
        {
            float uu = ldw(a.src[3], tid, f32) +
                       us4[0][tid] + us4[1][tid] + us4[2][tid] + us4[3][tid];
            us[tid] = uu * __builtin_amdgcn_rcpf(1.0f + __expf(-uu));
        }
        __syncthreads();

        // phase C: output j partials over k in [64kg, 64kg+64)
        float pc = 0.f;
#pragma unroll
        for (int kk = 0; kk < 64; kk++) {
            int k = 64 * kg + kk;
            pc = fmaf(us[k], ldw(a.src[4], k * 64 + j, f32), pc);
        }
        pcs[kg][j] = pc;
        __syncthreads();
        if (tid < 64) {
            float acc = ldw(a.src[5], j, f32) +
                        pcs[0][j] + pcs[1][j] + pcs[2][j] + pcs[3][j];
            (ws + OFF_TEMB)[t * 64 + j] = acc;
        }
    }
}

// ---------------- embedder + fused GCN-linear-0 (MFMA x2) ----------------
__global__ void __launch_bounds__(256) k_embed(const void* __restrict__ xraw,
                                               const unsigned short* __restrict__ wdet,
                                               const int* __restrict__ tsteps,
                                               float* __restrict__ ws,
                                               float* __restrict__ out_hembed,
                                               unsigned short* __restrict__ zbf) {
    __shared__ int scnt;
    __shared__ unsigned short tl[4][16 * 64];
    bool f32 = detect_f32(wdet, &scnt);

    int lane = threadIdx.x & 63;
    int wv = threadIdx.x >> 6;
    int m = lane & 15, quad = lane >> 4;
    int wid = blockIdx.x * 4 + wv;
    if (wid > N_NODES / 16 - 1) wid = N_NODES / 16 - 1;   // clamp (dup work benign)
    int n0 = wid * 16;

    const unsigned short* fwin = (const unsigned short*)(ws + OFF_FWIN);
    const unsigned short* fwc0 = (const unsigned short*)(ws + OFF_FWC0);

    bf16x8 bI[4][4];
#pragma unroll
    for (int c = 0; c < 4; c++)
#pragma unroll
        for (int t = 0; t < 4; t++)
            bI[c][t] = *reinterpret_cast<const bf16x8*>(fwin + (c * 4 + t) * 512 + lane * 8);

    f32x4 acc[4] = {f32x4{0,0,0,0}, f32x4{0,0,0,0}, f32x4{0,0,0,0}, f32x4{0,0,0,0}};
#pragma unroll
    for (int c = 0; c < 4; c++) {
        bf16x8 a;
        if (f32) {
            const float* xp = (const float*)xraw + (size_t)(n0 + m) * 128 + 32 * c + 8 * quad;
            float4 v0 = *reinterpret_cast<const float4*>(xp);
            float4 v1 = *reinterpret_cast<const float4*>(xp + 4);
            a[0] = (short)f2bf(v0.x); a[1] = (short)f2bf(v0.y);
            a[2] = (short)f2bf(v0.z); a[3] = (short)f2bf(v0.w);
            a[4] = (short)f2bf(v1.x); a[5] = (short)f2bf(v1.y);
            a[6] = (short)f2bf(v1.z); a[7] = (short)f2bf(v1.w);
        } else {
            a = *reinterpret_cast<const bf16x8*>(
                (const unsigned short*)xraw + (size_t)(n0 + m) * 128 + 32 * c + 8 * quad);
        }
#pragma unroll
        for (int t = 0; t < 4; t++)
            acc[t] = __builtin_amdgcn_mfma_f32_16x16x32_bf16(a, bI[c][t], acc[t], 0, 0, 0);
    }

    int tn[4];
#pragma unroll
    for (int r = 0; r < 4; r++) tn[r] = tsteps[n0 + 4 * quad + r];
    const float* temb = ws + OFF_TEMB;
#pragma unroll
    for (int t = 0; t < 4; t++) {
        int ch = 16 * t + m;
        float bj = ws[OFF_bin + ch];
#pragma unroll
        for (int r = 0; r < 4; r++) {
            int node = n0 + 4 * quad + r;
            float v = acc[t][r] + bj + temb[tn[r] * 64 + ch];
            out_hembed[(size_t)node * 64 + ch] = v;
            tl[wv][(4 * quad + r) * 64 + ch] = f2bf(v);
        }
    }
    __syncthreads();

    bf16x8 bC[2][4];
#pragma unroll
    for (int c = 0; c < 2; c++)
#pragma unroll
        for (int t = 0; t < 4; t++)
            bC[c][t] = *reinterpret_cast<const bf16x8*>(fwc0 + (c * 4 + t) * 512 + lane * 8);

    f32x4 az[4] = {f32x4{0,0,0,0}, f32x4{0,0,0,0}, f32x4{0,0,0,0}, f32x4{0,0,0,0}};
#pragma unroll
    for (int c = 0; c < 2; c++) {
        bf16x8 a2 = *reinterpret_cast<const bf16x8*>(&tl[wv][m * 64 + 32 * c + 8 * quad]);
#pragma unroll
        for (int t = 0; t < 4; t++)
            az[t] = __builtin_amdgcn_mfma_f32_16x16x32_bf16(a2, bC[c][t], az[t], 0, 0, 0);
    }
    const float* dinv = ws + OFF_DINV;
    float dv[4];
#pragma unroll
    for (int r = 0; r < 4; r++) dv[r] = dinv[n0 + 4 * quad + r];
#pragma unroll
    for (int t = 0; t < 4; t++) {
        int ch = 16 * t + m;
#pragma unroll
        for (int r = 0; r < 4; r++)
            zbf[(size_t)(n0 + 4 * quad + r) * 64 + ch] = f2bf(az[t][r] * dv[r]);
    }
}

// ---------------- gather-0 + relu + fused GCN-linear-1 (MFMA) ----------------
__global__ void __launch_bounds__(256) k_gather0(const unsigned short* __restrict__ zbf,
                                                 const int* __restrict__ ptr,
                                                 const int* __restrict__ elist,
                                                 const float* __restrict__ ws,
                                                 unsigned short* __restrict__ zout) {
    __shared__ unsigned short tile[16 * 64];     // 2KB, swizzled bf16 [16][64]
    const float* dinv = ws + OFF_DINV;
    const float* bias = ws + OFF_bc0;
    const unsigned short* fwc1 = (const unsigned short*)(ws + OFF_FWC1);

    int lane = threadIdx.x & 63;
    int wv = threadIdx.x >> 6;
    int g = lane >> 4;              // neighbor sub-group 0..3
    int cl = lane & 15;             // channel quad: channels 4cl..4cl+3
    int n0 = blockIdx.x * 16;

    float4 b4 = *reinterpret_cast<const float4*>(bias + 4 * cl);

#pragma unroll
    for (int snode = 0; snode < 4; snode++) {
        int li = wv * 4 + snode;    // local tile row
        int n = n0 + li;
        int base = ptr[n], end = ptr[n + 1];

        float ws0 = (g == 0) ? 1.0f : 0.0f;
        ushort4 sv = *reinterpret_cast<const ushort4*>(zbf + (size_t)n * 64 + cl * 4);
        float s0 = ws0 * bf2f(sv.x), s1 = ws0 * bf2f(sv.y);
        float s2 = ws0 * bf2f(sv.z), s3 = ws0 * bf2f(sv.w);

        for (int k = base; k < end; k += 8) {
            int e0 = k + g, e1 = k + 4 + g;
            int r0 = elist[min(e0, end - 1)];
            int r1 = elist[min(e1, end - 1)];
            ushort4 v0 = *reinterpret_cast<const ushort4*>(zbf + (size_t)r0 * 64 + cl * 4);
            ushort4 v1 = *reinterpret_cast<const ushort4*>(zbf + (size_t)r1 * 64 + cl * 4);
            float w0 = (e0 < end) ? 1.0f : 0.0f;
            float w1 = (e1 < end) ? 1.0f : 0.0f;
            s0 = fmaf(w0, bf2f(v0.x), s0); s1 = fmaf(w0, bf2f(v0.y), s1);
            s2 = fmaf(w0, bf2f(v0.z), s2); s3 = fmaf(w0, bf2f(v0.w), s3);
            s0 = fmaf(w1, bf2f(v1.x), s0); s1 = fmaf(w1, bf2f(v1.y), s1);
            s2 = fmaf(w1, bf2f(v1.z), s2); s3 = fmaf(w1, bf2f(v1.w), s3);
        }
        s0 += __shfl_xor(s0, 16, 64); s0 += __shfl_xor(s0, 32, 64);
        s1 += __shfl_xor(s1, 16, 64); s1 += __shfl_xor(s1, 32, 64);
        s2 += __shfl_xor(s2, 16, 64); s2 += __shfl_xor(s2, 32, 64);
        s3 += __shfl_xor(s3, 16, 64); s3 += __shfl_xor(s3, 32, 64);

        if (g == 0) {
            float dv = dinv[n];
            float h0 = fmaxf(fmaf(dv, s0, b4.x), 0.0f);
            float h1 = fmaxf(fmaf(dv, s1, b4.y), 0.0f);
            float h2 = fmaxf(fmaf(dv, s2, b4.z), 0.0f);
            float h3 = fmaxf(fmaf(dv, s3, b4.w), 0.0f);
            ushort4 hv;
            hv.x = f2bf(h0); hv.y = f2bf(h1); hv.z = f2bf(h2); hv.w = f2bf(h3);
            int bo = li * 128 + ((cl * 8) ^ ((li & 7) << 4));   // XOR-swizzle (G4)
            *reinterpret_cast<ushort4*>((char*)tile + bo) = hv;
        }
    }
    __syncthreads();

    // phase 2: wave wv computes output channels 16*wv..16*wv+15 for all 16 nodes
    int m = lane & 15, q = lane >> 4;
    bf16x8 bB0 = *reinterpret_cast<const bf16x8*>(fwc1 + (0 * 4 + wv) * 512 + lane * 8);
    bf16x8 bB1 = *reinterpret_cast<const bf16x8*>(fwc1 + (1 * 4 + wv) * 512 + lane * 8);

    f32x4 az = f32x4{0, 0, 0, 0};
    {
        int bo0 = m * 128 + ((0 * 64 + q * 16) ^ ((m & 7) << 4));
        bf16x8 a0 = *reinterpret_cast<const bf16x8*>((const char*)tile + bo0);
        az = __builtin_amdgcn_mfma_f32_16x16x32_bf16(a0, bB0, az, 0, 0, 0);
        int bo1 = m * 128 + ((1 * 64 + q * 16) ^ ((m & 7) << 4));
        bf16x8 a1 = *reinterpret_cast<const bf16x8*>((const char*)tile + bo1);
        az = __builtin_amdgcn_mfma_f32_16x16x32_bf16(a1, bB1, az, 0, 0, 0);
    }
    float dv4[4];
#pragma unroll
    for (int r = 0; r < 4; r++) dv4[r] = dinv[n0 + 4 * q + r];
#pragma unroll
    for (int r = 0; r < 4; r++) {
        int node = n0 + 4 * q + r;
        zout[(size_t)node * 64 + 16 * wv + m] = f2bf(az[r] * dv4[r]);
    }
}

// ---------------- gather-1 -> h_enc (fp32 out + fp8x16 table) ----------------
__global__ void __launch_bounds__(256) k_gather1(const unsigned short* __restrict__ zbf,
                                                 const int* __restrict__ ptr,
                                                 const int* __restrict__ elist,
                                                 const float* __restrict__ dinv,
                                                 const float* __restrict__ bias,
                                                 unsigned char* __restrict__ henc8,
                                                 float* __restrict__ ofp) {
    int lane = threadIdx.x & 63;
    int n = blockIdx.x * 4 + (threadIdx.x >> 6);
    int g = lane >> 4;
    int cl = lane & 15;
    int base = ptr[n], end = ptr[n + 1];

    float4 b4 = *reinterpret_cast<const float4*>(bias + 4 * cl);

    float ws0 = (g == 0) ? 1.0f : 0.0f;
    ushort4 sv = *reinterpret_cast<const ushort4*>(zbf + (size_t)n * 64 + cl * 4);
    float s0 = ws0 * bf2f(sv.x), s1 = ws0 * bf2f(sv.y);
    float s2 = ws0 * bf2f(sv.z), s3 = ws0 * bf2f(sv.w);

    for (int k = base; k < end; k += 8) {
        int e0 = k + g, e1 = k + 4 + g;
        int r0 = elist[min(e0, end - 1)];
        int r1 = elist[min(e1, end - 1)];
        ushort4 v0 = *reinterpret_cast<const ushort4*>(zbf + (size_t)r0 * 64 + cl * 4);
        ushort4 v1 = *reinterpret_cast<const ushort4*>(zbf + (size_t)r1 * 64 + cl * 4);
        float w0 = (e0 < end) ? 1.0f : 0.0f;
        float w1 = (e1 < end) ? 1.0f : 0.0f;
        s0 = fmaf(w0, bf2f(v0.x), s0); s1 = fmaf(w0, bf2f(v0.y), s1);
        s2 = fmaf(w0, bf2f(v0.z), s2); s3 = fmaf(w0, bf2f(v0.w), s3);
        s0 = fmaf(w1, bf2f(v1.x), s0); s1 = fmaf(w1, bf2f(v1.y), s1);
        s2 = fmaf(w1, bf2f(v1.z), s2); s3 = fmaf(w1, bf2f(v1.w), s3);
    }
    s0 += __shfl_xor(s0, 16, 64); s0 += __shfl_xor(s0, 32, 64);
    s1 += __shfl_xor(s1, 16, 64); s1 += __shfl_xor(s1, 32, 64);
    s2 += __shfl_xor(s2, 16, 64); s2 += __shfl_xor(s2, 32, 64);
    s3 += __shfl_xor(s3, 16, 64); s3 += __shfl_xor(s3, 32, 64);

    float dv = dinv[n];
    float o0 = fmaf(dv, s0, b4.x);
    float o1 = fmaf(dv, s1, b4.y);
    float o2 = fmaf(dv, s2, b4.z);
    float o3 = fmaf(dv, s3, b4.w);

    if (g == 0) {
        float4 ov; ov.x = o0; ov.y = o1; ov.z = o2; ov.w = o3;
        *reinterpret_cast<float4*>(ofp + (size_t)n * 64 + cl * 4) = ov;
    }
    // redistribute: lane converts channel `lane`
    int jc = lane >> 2;
    float a0 = __shfl(o0, jc, 64);
    float a1 = __shfl(o1, jc, 64);
    float a2 = __shfl(o2, jc, 64);
    float a3 = __shfl(o3, jc, 64);
    int sel = lane & 3;
    float mv = (sel == 0) ? a0 : (sel == 1) ? a1 : (sel == 2) ? a2 : a3;
    henc8[(size_t)n * 64 + lane] = f2fp8(16.0f * mv);
}

// ---------------- edge decoder (MFMA fp8, pipelined) ----------------
#define DEC_TPW 4
#define DEC_TILES (E_FULL / 16)

__global__ void __launch_bounds__(256) k_dec(const int* __restrict__ src,
                                             const int* __restrict__ dst,
                                             const unsigned char* __restrict__ h8,
                                             const float* __restrict__ ws,
                                             float* __restrict__ out) {
    int lane = threadIdx.x & 63;
    int wv = threadIdx.x >> 6;
    int m = lane & 15;
    int quad = lane >> 4;

    const unsigned char* fw = (const unsigned char*)(ws + OFF_FWD1);
    long bfr[4][4];
#pragma unroll
    for (int c = 0; c < 4; c++)
#pragma unroll
        for (int t = 0; t < 4; t++)
            bfr[c][t] = *reinterpret_cast<const long*>(fw + ((c * 4 + t) * 512 + lane * 8));

    float w2[4], b1v[4];
#pragma unroll
    for (int t = 0; t < 4; t++) {
        w2[t]  = ws[OFF_Wd2 + 16 * t + m];
        b1v[t] = ws[OFF_bd1 + 16 * t + m];
    }
    float b2 = ws[OFF_bd2];

    int tile0 = (blockIdx.x * 4 + wv) * DEC_TPW;
    int tc = min(tile0, DEC_TILES - 1);
    int s0 = src[tc * 16 + m], d0 = dst[tc * 16 + m];
    tc = min(tile0 + 1, DEC_TILES - 1);
    int s1 = src[tc * 16 + m], d1 = dst[tc * 16 + m];
    long A0[4];
#pragma unroll
    for (int c = 0; c < 4; c++) {
        int row = (c < 2) ? s0 : d0;
        A0[c] = *reinterpret_cast<const long*>(
            h8 + (size_t)row * 64 + (c & 1) * 32 + 8 * quad);
    }

    for (int i = 0; i < DEC_TPW; i++) {
        int tile = tile0 + i;
        int t2 = min(tile0 + i + 2, DEC_TILES - 1);
        int s2 = src[t2 * 16 + m], d2 = dst[t2 * 16 + m];
        long A1[4];
#pragma unroll
        for (int c = 0; c < 4; c++) {
            int row = (c < 2) ? s1 : d1;
            A1[c] = *reinterpret_cast<const long*>(
                h8 + (size_t)row * 64 + (c & 1) * 32 + 8 * quad);
        }
        f32x4 acc[4] = {f32x4{0,0,0,0}, f32x4{0,0,0,0}, f32x4{0,0,0,0}, f32x4{0,0,0,0}};
#pragma unroll
        for (int c = 0; c < 4; c++)
#pragma unroll
            for (int t = 0; t < 4; t++)
                acc[t] = __builtin_amdgcn_mfma_f32_16x16x32_fp8_fp8(A0[c], bfr[c][t], acc[t], 0, 0, 0);
        float sums[4];
#pragma unroll
        for (int r = 0; r < 4; r++) {
            float sv = 0.0f;
#pragma unroll
            for (int t = 0; t < 4; t++) {
                float v = fmaf(acc[t][r], 0.00390625f, b1v[t]);   // /256 un-scale
                float h = v * __builtin_amdgcn_rcpf(1.0f + __expf(-v));
                sv = fmaf(h, w2[t], sv);
            }
#pragma unroll
            for (int msk = 8; msk >= 1; msk >>= 1)
                sv += __shfl_xor(sv, msk, 64);
            sums[r] = sv;
        }
        if (m == 0 && tile < DEC_TILES) {
            float4 o;
            o.x = sums[0] + b2; o.y = sums[1] + b2;
            o.z = sums[2] + b2; o.w = sums[3] + b2;
            *reinterpret_cast<float4*>(out + tile * 16 + 4 * quad) = o;
        }
#pragma unroll
        for (int c = 0; c < 4; c++) A0[c] = A1[c];
        s1 = s2; d1 = d2;
    }
}

extern "C" void kernel_launch(void* const* d_in, const int* in_sizes, int n_in,
                              void* d_out, int out_size, void* d_ws, size_t ws_size,
                              hipStream_t stream) {
    if (n_in < 18) return;
    const void* x              = d_in[0];
    const int* edge_index      = (const int*)d_in[1];
    const int* full_edge_index = (const int*)d_in[2];
    const int* tsteps          = (const int*)d_in[3];
    float* ws = (float*)d_ws;
    float* out = (float*)d_out;

    int*   iws   = (int*)d_ws;
    int*   bsum  = iws + OFF_BSUM;
    int*   bcur  = iws + OFF_BCUR;
    int*   ptr   = iws + OFF_PTR;
    int*   elist = iws + OFF_ELIST;
    uint2* tmp   = (uint2*)(iws + OFF_TMP2);
    unsigned short* zbf  = (unsigned short*)(ws + OFF_ZBF);
    unsigned short* zbf2 = (unsigned short*)(ws + OFF_ZBF2);
    unsigned char*  h8   = (unsigned char*)(ws + OFF_HENC8);

    CvtArgs ca;
    for (int i = 0; i < 14; i++) ca.src[i] = d_in[4 + i];

    // CSR build: bucket totals -> prefix -> bucketed scatter -> per-bucket sort
    // (per-node counts/ptr/dinv all computed in LDS inside k_csort2)
    hipMemsetAsync(bsum, 0, (size_t)SCAN_NB * 4, stream);
    k_bcount<<<BC_NB, 256, 0, stream>>>(edge_index + E_MSG, bsum);
    k_scan2<<<1, 256, 0, stream>>>(bsum, bcur, ptr);
    k_bfill<<<SCAN_NB, 256, 0, stream>>>(edge_index, edge_index + E_MSG, bcur, tmp);
    k_csort2<<<SCAN_NB, 256, 0, stream>>>(tmp, bsum, ptr, ws + OFF_DINV, elist);

    // fused weight prep: cvt + frag tables (FWC1 over dead tmp) + t_emb
    k_wprep<<<WP_CVT_NB + WP_PREP_NB + WP_TEMB_NB, 256, 0, stream>>>(ca, ws);

    // embedder + fused lin0 (h_embed -> d_out fp32; z0 -> zbf)
    k_embed<<<(N_NODES / 16 + 3) / 4, 256, 0, stream>>>(
        x, (const unsigned short*)d_in[4], tsteps, ws, out + E_FULL, zbf);

    // gather0 + relu + fused lin1 (MFMA): zbf -> zbf2
    k_gather0<<<N_NODES / 16, 256, 0, stream>>>(zbf, ptr, elist, ws, zbf2);

    // gather1: zbf2 -> {out fp32, h8 fp8x16}
    k_gather1<<<N_NODES / 4, 256, 0, stream>>>(
        zbf2, ptr, elist, ws + OFF_DINV, ws + OFF_bc1, h8,
        out + E_FULL + (size_t)N_NODES * 64);

    // decoder (fp8 MFMA)
    int dec_blocks = (DEC_TILES + 4 * DEC_TPW - 1) / (4 * DEC_TPW);
    k_dec<<<dec_blocks, 256, 0, stream>>>(full_edge_index, full_edge_index + E_FULL,
                                          h8, ws, out);
}

// Round 5
// 262.720 us; speedup vs baseline: 2.1979x; 1.0020x over previous
//
#include <hip/hip_runtime.h>
#include <hip/hip_bf16.h>
#include <math.h>

#define N_NODES 50000
#define E_MSG   800000
#define E_FULL  1000000
#define IN_C    128
#define H_C     64
#define T_STEPS 128

// ---- workspace layout (in floats) ----
#define OFF_Win   0
#define OFF_bin   8192
#define OFF_Wt1   8256
#define OFF_bt1   24640
#define OFF_Wt2   24896
#define OFF_bt2   41280
#define OFF_Wc0   41344
#define OFF_bc0   45440
#define OFF_Wc1   45504
#define OFF_bc1   49600
#define OFF_Wd1   49664
#define OFF_bd1   57856
#define OFF_Wd2   57920
#define OFF_bd2   57984
#define W_TOTAL   57985
#define OFF_BSUM  58016                 // 256 ints (bucket TOTALS)
#define OFF_BCUR  58272                 // 256 ints (relative cursors, memset 0)
#define OFF_FWD1  58624                 // 8192 fp8 bytes (16*Wd1 frag table)
#define OFF_FWIN  60672                 // 8192 bf16 (W_in frag table)
#define OFF_FWC0  64768                 // 4096 bf16 (Wc0 frag table)
#define OFF_TEMB  66816                 // 128*64 floats
#define OFF_DINV  75008                 // 50000 floats
#define OFF_FWC1  125008                // 2048 floats (Wc1 frag table; ex-CNT)
#define OFF_PTR   175008                // 50001 ints
#define OFF_ELIST 225010                // 800000 ints
#define OFF_TMP2  1025012               // 1.6M ints (800000 uint2), 8B aligned
#define OFF_ZBF   2625012               // 3.2M bf16 (z0)
#define OFF_ZBF2  4225012               // 3.2M bf16 (z1)
#define OFF_HENC8 5825012               // 3.2M fp8 bytes
// total 6,625,012 floats = 26.5 MB

#define SCAN_NB   ((N_NODES + 255) / 256)   // 196 buckets
#define BF_CH     ((E_MSG + SCAN_NB - 1) / SCAN_NB)   // 4082 edges/block
#define BC_NB     392
#define BC_CH     ((E_MSG + BC_NB - 1) / BC_NB)       // 2041 edges/block

typedef __attribute__((ext_vector_type(8))) short bf16x8;
typedef __attribute__((ext_vector_type(4))) float f32x4;

static __device__ __forceinline__ float bf2f(unsigned short u) {
    return __uint_as_float(((unsigned)u) << 16);
}
static __device__ __forceinline__ unsigned short f2bf(float f) {
    unsigned u = __float_as_uint(f);
    unsigned r = (u + 0x7fffu + ((u >> 16) & 1u)) >> 16;
    return (unsigned short)r;
}
// fp32 -> fp8 e4m3fn, RNE, clamp to +-448
static __device__ __forceinline__ unsigned char f2fp8(float f) {
    unsigned u = __float_as_uint(f);
    unsigned s = (u >> 24) & 0x80;
    float a = fminf(__uint_as_float(u & 0x7FFFFFFF), 448.0f);
    if (a < 0.015625f) {
        int qi = (int)rintf(a * 512.0f);
        return (unsigned char)(s | qi);
    }
    unsigned ua = __float_as_uint(a);
    int e = (int)((ua >> 23) & 0xFF) - 127;
    unsigned man = (ua & 0x7FFFFF) | 0x800000;
    unsigned r = man >> 20;
    unsigned rem = man & 0xFFFFF;
    if (rem > 0x80000u || (rem == 0x80000u && (r & 1))) r++;
    if (r == 16) { r = 8; e++; }
    if (e > 8) return (unsigned char)(s | 0x7E);
    return (unsigned char)(s | ((unsigned)(e + 7) << 3) | (r & 7));
}
static __device__ __forceinline__ bool detect_f32(const unsigned short* w, int* scnt) {
    if (threadIdx.x == 0) *scnt = 0;
    __syncthreads();
    int big = 0;
    for (int i = threadIdx.x; i < 2048; i += blockDim.x)
        if (fabsf(bf2f(w[2 * i])) > 0.5f) big++;
    atomicAdd(scnt, big);
    __syncthreads();
    return *scnt > 64;
}
// raw-weight load with dtype dispatch
static __device__ __forceinline__ float ldw(const void* p, int idx, bool f32) {
    return f32 ? ((const float*)p)[idx] : bf2f(((const unsigned short*)p)[idx]);
}

// ---------------- CSR build ----------------
// bucketed scatter: per-block LDS histogram + in-LDS bucket prefix +
// one reservation atomic per (block, bucket) into relative cursors
__global__ void __launch_bounds__(256) k_bfill(const int* __restrict__ row,
                                               const int* __restrict__ col,
                                               const int* __restrict__ btot,
                                               int* __restrict__ bcur,
                                               uint2* __restrict__ tmp) {
    __shared__ int pref[256];
    __shared__ int hist[SCAN_NB];
    __shared__ int basew[SCAN_NB];
    int b = blockIdx.x, t = threadIdx.x;

    // in-LDS exclusive prefix of bucket totals
    int tv = (t < SCAN_NB) ? btot[t] : 0;
    pref[t] = tv;
    __syncthreads();
    for (int off = 1; off < 256; off <<= 1) {
        int u = (t >= off) ? pref[t - off] : 0;
        __syncthreads();
        pref[t] += u;
        __syncthreads();
    }
    int excl_t = pref[t] - tv;          // exclusive prefix for bucket t

    int lo = b * BF_CH;
    int hi = lo + BF_CH; if (hi > E_MSG) hi = E_MSG;
    for (int i = t; i < SCAN_NB; i += 256) hist[i] = 0;
    __syncthreads();
    for (int e = lo + t; e < hi; e += 256)
        atomicAdd(&hist[col[e] >> 8], 1);
    __syncthreads();
    if (t < SCAN_NB) {
        int c = hist[t];
        basew[t] = (c > 0) ? excl_t + atomicAdd(&bcur[t], c) : 0;
    }
    __syncthreads();
    for (int i = t; i < SCAN_NB; i += 256) hist[i] = 0;  // reuse as cursor
    __syncthreads();
    for (int e = lo + t; e < hi; e += 256) {
        int src = row[e], c = col[e];
        int bk = c >> 8;
        int off = atomicAdd(&hist[bk], 1);
        tmp[basew[bk] + off] = uint2{(unsigned)src, (unsigned)c};
    }
}

// per bucket: in-LDS bucket prefix -> [start,end); LDS degree count + prefix
// -> ptr/dinv; LDS-cursor scatter. No per-node global atomics.
__global__ void __launch_bounds__(256) k_csort2(const uint2* __restrict__ tmp,
                                                const int* __restrict__ btot,
                                                int* __restrict__ ptr,
                                                float* __restrict__ dinv,
                                                int* __restrict__ elist) {
    __shared__ int deg[256];
    __shared__ int pfx[256];
    int b = blockIdx.x, t = threadIdx.x;

    // bucket prefix (reuse pfx)
    int tv = (t < SCAN_NB) ? btot[t] : 0;
    pfx[t] = tv;
    __syncthreads();
    for (int off = 1; off < 256; off <<= 1) {
        int u = (t >= off) ? pfx[t - off] : 0;
        __syncthreads();
        pfx[t] += u;
        __syncthreads();
    }
    __shared__ int se[2];
    if (t == b) { se[0] = pfx[t] - tv; se[1] = pfx[t]; }
    __syncthreads();
    int start = se[0], end = se[1];

    deg[t] = 0;
    __syncthreads();
    for (int e = start + t; e < end; e += 256)
        atomicAdd(&deg[tmp[e].y & 255], 1);
    __syncthreads();

    int v = deg[t];
    pfx[t] = v;
    __syncthreads();
    for (int off = 1; off < 256; off <<= 1) {
        int u = (t >= off) ? pfx[t - off] : 0;
        __syncthreads();
        pfx[t] += u;
        __syncthreads();
    }
    int excl = pfx[t] - v;
    int n = (b << 8) + t;
    if (n < N_NODES) {
        ptr[n] = start + excl;
        dinv[n] = rsqrtf((float)v + 1.0f);
    }
    if (b == 0 && t == 0) ptr[N_NODES] = E_MSG;
    __syncthreads();
    deg[t] = excl;                       // reuse as local cursor
    __syncthreads();
    for (int e = start + t; e < end; e += 256) {
        uint2 p = tmp[e];
        int pos = atomicAdd(&deg[p.y & 255], 1);
        elist[start + pos] = (int)p.x;
    }
}

// ---------------- fused prep: bucket-count + cvt + frag tables + temb ----------
// blocks [0,392): edge bucket histogram (independent of weights)
// blocks [392,619): cvt -> ws fp32
// blocks [619,715): MFMA B-frag tables (read RAW weights, convert inline)
// blocks [715,843): t_emb, ONE timestep per block, 4-way k-split
#define WP_BC_NB   392
#define WP_CVT_NB  227
#define WP_PREP_NB 96
#define WP_TEMB_NB 128
#define WP_TOTAL_NB (WP_BC_NB + WP_CVT_NB + WP_PREP_NB + WP_TEMB_NB)

struct CvtArgs { const void* src[14]; };

__global__ void __launch_bounds__(256) k_wprep(CvtArgs a,
                                               const int* __restrict__ ecol,
                                               int* __restrict__ bsum,
                                               float* ws) {
    __shared__ int scnt;
    int bid = blockIdx.x;
    int tid = threadIdx.x;

    if (bid < WP_BC_NB) {
        // bucket totals: per-block LDS 196-bin histogram
        __shared__ int hist[SCAN_NB];
        for (int i = tid; i < SCAN_NB; i += 256) hist[i] = 0;
        __syncthreads();
        int lo = bid * BC_CH;
        int hi = lo + BC_CH; if (hi > E_MSG) hi = E_MSG;
        for (int e = lo + tid; e < hi; e += 256)
            atomicAdd(&hist[ecol[e] >> 8], 1);
        __syncthreads();
        for (int i = tid; i < SCAN_NB; i += 256) {
            int c = hist[i];
            if (c > 0) atomicAdd(&bsum[i], c);
        }
        return;
    }
    bid -= WP_BC_NB;

    bool f32 = detect_f32((const unsigned short*)a.src[0], &scnt);

    if (bid < WP_CVT_NB) {
        int t = bid * 256 + tid;
        if (t >= W_TOTAL) return;
        const int starts[14] = {OFF_Win, OFF_bin, OFF_Wt1, OFF_bt1, OFF_Wt2, OFF_bt2,
                                OFF_Wc0, OFF_bc0, OFF_Wc1, OFF_bc1, OFF_Wd1, OFF_bd1,
                                OFF_Wd2, OFF_bd2};
        int seg = 0;
#pragma unroll
        for (int i = 1; i < 14; i++)
            if (t >= starts[i]) seg = i;
        ws[t] = ldw(a.src[seg], t - starts[seg], f32);
    } else if (bid < WP_CVT_NB + WP_PREP_NB) {
        int idx = (bid - WP_CVT_NB) * 256 + tid;       // 0..24575
        int local, j, lane, ct, c, t, m, q;
        if (idx < 8192) {
            local = idx;
            j = local & 7; lane = (local >> 3) & 63; ct = local >> 9;
            c = ct >> 2; t = ct & 3; m = lane & 15; q = lane >> 4;
            ((unsigned char*)(ws + OFF_FWD1))[local] =
                f2fp8(16.0f * ldw(a.src[10], (32 * c + 8 * q + j) * 64 + 16 * t + m, f32));
        } else if (idx < 16384) {
            local = idx - 8192;
            j = local & 7; lane = (local >> 3) & 63; ct = local >> 9;
            c = ct >> 2; t = ct & 3; m = lane & 15; q = lane >> 4;
            ((unsigned short*)(ws + OFF_FWIN))[local] =
                f2bf(ldw(a.src[0], (32 * c + 8 * q + j) * 64 + 16 * t + m, f32));
        } else if (idx < 20480) {
            local = idx - 16384;
            j = local & 7; lane = (local >> 3) & 63; ct = local >> 9;
            c = ct >> 2; t = ct & 3; m = lane & 15; q = lane >> 4;
            ((unsigned short*)(ws + OFF_FWC0))[local] =
                f2bf(ldw(a.src[6], (32 * c + 8 * q + j) * 64 + 16 * t + m, f32));
        } else {
            local = idx - 20480;
            j = local & 7; lane = (local >> 3) & 63; ct = local >> 9;
            c = ct >> 2; t = ct & 3; m = lane & 15; q = lane >> 4;
            ((unsigned short*)(ws + OFF_FWC1))[local] =
                f2bf(ldw(a.src[8], (32 * c + 8 * q + j) * 64 + 16 * t + m, f32));
        }
    } else {
        // t_emb: one timestep per block; threads (j = tid&63, kg = tid>>6)
        __shared__ float pe[64];
        __shared__ float us4[4][256];
        __shared__ float us[256];
        __shared__ float pcs[4][64];
        int j = tid & 63;
        int kg = tid >> 6;
        int t = bid - WP_CVT_NB - WP_PREP_NB;

        if (tid < 64) {
            float xt = (float)t * (4000.0f / 128.0f);
            float sc = -logf(10000.0f) / 31.0f;
            float fr = __expf((float)(tid & 31) * sc);
            float ang = xt * fr;
            pe[tid] = (tid < 32) ? sinf(ang) : cosf(ang);
        }
        __syncthreads();

        float pu[4] = {0.f, 0.f, 0.f, 0.f};
#pragma unroll
        for (int kk = 0; kk < 16; kk++) {
            int k = 16 * kg + kk;
            float p = pe[k];
#pragma unroll
            for (int q = 0; q < 4; q++)
                pu[q] = fmaf(p, ldw(a.src[2], k * 256 + q * 64 + j, f32), pu[q]);
        }
#pragma unroll
        for (int q = 0; q < 4; q++) us4[kg][q * 64 + j] = pu[q];
        __syncthreads();

        {
            float uu = ldw(a.src[3], tid, f32) +
                       us4[0][tid] + us4[1][tid] + us4[2][tid] + us4[3][tid];
            us[tid] = uu * __builtin_amdgcn_rcpf(1.0f + __expf(-uu));
        }
        __syncthreads();

        float pc = 0.f;
#pragma unroll
        for (int kk = 0; kk < 64; kk++) {
            int k = 64 * kg + kk;
            pc = fmaf(us[k], ldw(a.src[4], k * 64 + j, f32), pc);
        }
        pcs[kg][j] = pc;
        __syncthreads();
        if (tid < 64) {
            float acc = ldw(a.src[5], j, f32) +
                        pcs[0][j] + pcs[1][j] + pcs[2][j] + pcs[3][j];
            (ws + OFF_TEMB)[t * 64 + j] = acc;
        }
    }
}

// ---------------- embedder + fused GCN-linear-0 (MFMA x2) ----------------
__global__ void __launch_bounds__(256) k_embed(const void* __restrict__ xraw,
                                               const unsigned short* __restrict__ wdet,
                                               const int* __restrict__ tsteps,
                                               float* __restrict__ ws,
                                               float* __restrict__ out_hembed,
                                               unsigned short* __restrict__ zbf) {
    __shared__ int scnt;
    __shared__ unsigned short tl[4][16 * 64];
    bool f32 = detect_f32(wdet, &scnt);

    int lane = threadIdx.x & 63;
    int wv = threadIdx.x >> 6;
    int m = lane & 15, quad = lane >> 4;
    int wid = blockIdx.x * 4 + wv;
    if (wid > N_NODES / 16 - 1) wid = N_NODES / 16 - 1;   // clamp (dup work benign)
    int n0 = wid * 16;

    const unsigned short* fwin = (const unsigned short*)(ws + OFF_FWIN);
    const unsigned short* fwc0 = (const unsigned short*)(ws + OFF_FWC0);

    bf16x8 bI[4][4];
#pragma unroll
    for (int c = 0; c < 4; c++)
#pragma unroll
        for (int t = 0; t < 4; t++)
            bI[c][t] = *reinterpret_cast<const bf16x8*>(fwin + (c * 4 + t) * 512 + lane * 8);

    f32x4 acc[4] = {f32x4{0,0,0,0}, f32x4{0,0,0,0}, f32x4{0,0,0,0}, f32x4{0,0,0,0}};
#pragma unroll
    for (int c = 0; c < 4; c++) {
        bf16x8 a;
        if (f32) {
            const float* xp = (const float*)xraw + (size_t)(n0 + m) * 128 + 32 * c + 8 * quad;
            float4 v0 = *reinterpret_cast<const float4*>(xp);
            float4 v1 = *reinterpret_cast<const float4*>(xp + 4);
            a[0] = (short)f2bf(v0.x); a[1] = (short)f2bf(v0.y);
            a[2] = (short)f2bf(v0.z); a[3] = (short)f2bf(v0.w);
            a[4] = (short)f2bf(v1.x); a[5] = (short)f2bf(v1.y);
            a[6] = (short)f2bf(v1.z); a[7] = (short)f2bf(v1.w);
        } else {
            a = *reinterpret_cast<const bf16x8*>(
                (const unsigned short*)xraw + (size_t)(n0 + m) * 128 + 32 * c + 8 * quad);
        }
#pragma unroll
        for (int t = 0; t < 4; t++)
            acc[t] = __builtin_amdgcn_mfma_f32_16x16x32_bf16(a, bI[c][t], acc[t], 0, 0, 0);
    }

    int tn[4];
#pragma unroll
    for (int r = 0; r < 4; r++) tn[r] = tsteps[n0 + 4 * quad + r];
    const float* temb = ws + OFF_TEMB;
#pragma unroll
    for (int t = 0; t < 4; t++) {
        int ch = 16 * t + m;
        float bj = ws[OFF_bin + ch];
#pragma unroll
        for (int r = 0; r < 4; r++) {
            int node = n0 + 4 * quad + r;
            float v = acc[t][r] + bj + temb[tn[r] * 64 + ch];
            out_hembed[(size_t)node * 64 + ch] = v;
            tl[wv][(4 * quad + r) * 64 + ch] = f2bf(v);
        }
    }
    __syncthreads();

    bf16x8 bC[2][4];
#pragma unroll
    for (int c = 0; c < 2; c++)
#pragma unroll
        for (int t = 0; t < 4; t++)
            bC[c][t] = *reinterpret_cast<const bf16x8*>(fwc0 + (c * 4 + t) * 512 + lane * 8);

    f32x4 az[4] = {f32x4{0,0,0,0}, f32x4{0,0,0,0}, f32x4{0,0,0,0}, f32x4{0,0,0,0}};
#pragma unroll
    for (int c = 0; c < 2; c++) {
        bf16x8 a2 = *reinterpret_cast<const bf16x8*>(&tl[wv][m * 64 + 32 * c + 8 * quad]);
#pragma unroll
        for (int t = 0; t < 4; t++)
            az[t] = __builtin_amdgcn_mfma_f32_16x16x32_bf16(a2, bC[c][t], az[t], 0, 0, 0);
    }
    const float* dinv = ws + OFF_DINV;
    float dv[4];
#pragma unroll
    for (int r = 0; r < 4; r++) dv[r] = dinv[n0 + 4 * quad + r];
#pragma unroll
    for (int t = 0; t < 4; t++) {
        int ch = 16 * t + m;
#pragma unroll
        for (int r = 0; r < 4; r++)
            zbf[(size_t)(n0 + 4 * quad + r) * 64 + ch] = f2bf(az[t][r] * dv[r]);
    }
}

// ---------------- gather-0 + relu + fused GCN-linear-1 (MFMA) ----------------
__global__ void __launch_bounds__(256) k_gather0(const unsigned short* __restrict__ zbf,
                                                 const int* __restrict__ ptr,
                                                 const int* __restrict__ elist,
                                                 const float* __restrict__ ws,
                                                 unsigned short* __restrict__ zout) {
    __shared__ unsigned short tile[16 * 64];     // 2KB, swizzled bf16 [16][64]
    const float* dinv = ws + OFF_DINV;
    const float* bias = ws + OFF_bc0;
    const unsigned short* fwc1 = (const unsigned short*)(ws + OFF_FWC1);

    int lane = threadIdx.x & 63;
    int wv = threadIdx.x >> 6;
    int g = lane >> 4;              // neighbor sub-group 0..3
    int cl = lane & 15;             // channel quad: channels 4cl..4cl+3
    int n0 = blockIdx.x * 16;

    float4 b4 = *reinterpret_cast<const float4*>(bias + 4 * cl);

#pragma unroll
    for (int snode = 0; snode < 4; snode++) {
        int li = wv * 4 + snode;    // local tile row
        int n = n0 + li;
        int base = ptr[n], end = ptr[n + 1];

        float ws0 = (g == 0) ? 1.0f : 0.0f;
        ushort4 sv = *reinterpret_cast<const ushort4*>(zbf + (size_t)n * 64 + cl * 4);
        float s0 = ws0 * bf2f(sv.x), s1 = ws0 * bf2f(sv.y);
        float s2 = ws0 * bf2f(sv.z), s3 = ws0 * bf2f(sv.w);

        for (int k = base; k < end; k += 8) {
            int e0 = k + g, e1 = k + 4 + g;
            int r0 = elist[min(e0, end - 1)];
            int r1 = elist[min(e1, end - 1)];
            ushort4 v0 = *reinterpret_cast<const ushort4*>(zbf + (size_t)r0 * 64 + cl * 4);
            ushort4 v1 = *reinterpret_cast<const ushort4*>(zbf + (size_t)r1 * 64 + cl * 4);
            float w0 = (e0 < end) ? 1.0f : 0.0f;
            float w1 = (e1 < end) ? 1.0f : 0.0f;
            s0 = fmaf(w0, bf2f(v0.x), s0); s1 = fmaf(w0, bf2f(v0.y), s1);
            s2 = fmaf(w0, bf2f(v0.z), s2); s3 = fmaf(w0, bf2f(v0.w), s3);
            s0 = fmaf(w1, bf2f(v1.x), s0); s1 = fmaf(w1, bf2f(v1.y), s1);
            s2 = fmaf(w1, bf2f(v1.z), s2); s3 = fmaf(w1, bf2f(v1.w), s3);
        }
        s0 += __shfl_xor(s0, 16, 64); s0 += __shfl_xor(s0, 32, 64);
        s1 += __shfl_xor(s1, 16, 64); s1 += __shfl_xor(s1, 32, 64);
        s2 += __shfl_xor(s2, 16, 64); s2 += __shfl_xor(s2, 32, 64);
        s3 += __shfl_xor(s3, 16, 64); s3 += __shfl_xor(s3, 32, 64);

        if (g == 0) {
            float dv = dinv[n];
            float h0 = fmaxf(fmaf(dv, s0, b4.x), 0.0f);
            float h1 = fmaxf(fmaf(dv, s1, b4.y), 0.0f);
            float h2 = fmaxf(fmaf(dv, s2, b4.z), 0.0f);
            float h3 = fmaxf(fmaf(dv, s3, b4.w), 0.0f);
            ushort4 hv;
            hv.x = f2bf(h0); hv.y = f2bf(h1); hv.z = f2bf(h2); hv.w = f2bf(h3);
            int bo = li * 128 + ((cl * 8) ^ ((li & 7) << 4));   // XOR-swizzle (G4)
            *reinterpret_cast<ushort4*>((char*)tile + bo) = hv;
        }
    }
    __syncthreads();

    // phase 2: wave wv computes output channels 16*wv..16*wv+15 for all 16 nodes
    int m = lane & 15, q = lane >> 4;
    bf16x8 bB0 = *reinterpret_cast<const bf16x8*>(fwc1 + (0 * 4 + wv) * 512 + lane * 8);
    bf16x8 bB1 = *reinterpret_cast<const bf16x8*>(fwc1 + (1 * 4 + wv) * 512 + lane * 8);

    f32x4 az = f32x4{0, 0, 0, 0};
    {
        int bo0 = m * 128 + ((0 * 64 + q * 16) ^ ((m & 7) << 4));
        bf16x8 a0 = *reinterpret_cast<const bf16x8*>((const char*)tile + bo0);
        az = __builtin_amdgcn_mfma_f32_16x16x32_bf16(a0, bB0, az, 0, 0, 0);
        int bo1 = m * 128 + ((1 * 64 + q * 16) ^ ((m & 7) << 4));
        bf16x8 a1 = *reinterpret_cast<const bf16x8*>((const char*)tile + bo1);
        az = __builtin_amdgcn_mfma_f32_16x16x32_bf16(a1, bB1, az, 0, 0, 0);
    }
    float dv4[4];
#pragma unroll
    for (int r = 0; r < 4; r++) dv4[r] = dinv[n0 + 4 * q + r];
#pragma unroll
    for (int r = 0; r < 4; r++) {
        int node = n0 + 4 * q + r;
        zout[(size_t)node * 64 + 16 * wv + m] = f2bf(az[r] * dv4[r]);
    }
}

// ---------------- gather-1 -> h_enc (fp32 out + fp8x16 table) ----------------
__global__ void __launch_bounds__(256) k_gather1(const unsigned short* __restrict__ zbf,
                                                 const int* __restrict__ ptr,
                                                 const int* __restrict__ elist,
                                                 const float* __restrict__ dinv,
                                                 const float* __restrict__ bias,
                                                 unsigned char* __restrict__ henc8,
                                                 float* __restrict__ ofp) {
    int lane = threadIdx.x & 63;
    int n = blockIdx.x * 4 + (threadIdx.x >> 6);
    int g = lane >> 4;
    int cl = lane & 15;
    int base = ptr[n], end = ptr[n + 1];

    float4 b4 = *reinterpret_cast<const float4*>(bias + 4 * cl);

    float ws0 = (g == 0) ? 1.0f : 0.0f;
    ushort4 sv = *reinterpret_cast<const ushort4*>(zbf + (size_t)n * 64 + cl * 4);
    float s0 = ws0 * bf2f(sv.x), s1 = ws0 * bf2f(sv.y);
    float s2 = ws0 * bf2f(sv.z), s3 = ws0 * bf2f(sv.w);

    for (int k = base; k < end; k += 8) {
        int e0 = k + g, e1 = k + 4 + g;
        int r0 = elist[min(e0, end - 1)];
        int r1 = elist[min(e1, end - 1)];
        ushort4 v0 = *reinterpret_cast<const ushort4*>(zbf + (size_t)r0 * 64 + cl * 4);
        ushort4 v1 = *reinterpret_cast<const ushort4*>(zbf + (size_t)r1 * 64 + cl * 4);
        float w0 = (e0 < end) ? 1.0f : 0.0f;
        float w1 = (e1 < end) ? 1.0f : 0.0f;
        s0 = fmaf(w0, bf2f(v0.x), s0); s1 = fmaf(w0, bf2f(v0.y), s1);
        s2 = fmaf(w0, bf2f(v0.z), s2); s3 = fmaf(w0, bf2f(v0.w), s3);
        s0 = fmaf(w1, bf2f(v1.x), s0); s1 = fmaf(w1, bf2f(v1.y), s1);
        s2 = fmaf(w1, bf2f(v1.z), s2); s3 = fmaf(w1, bf2f(v1.w), s3);
    }
    s0 += __shfl_xor(s0, 16, 64); s0 += __shfl_xor(s0, 32, 64);
    s1 += __shfl_xor(s1, 16, 64); s1 += __shfl_xor(s1, 32, 64);
    s2 += __shfl_xor(s2, 16, 64); s2 += __shfl_xor(s2, 32, 64);
    s3 += __shfl_xor(s3, 16, 64); s3 += __shfl_xor(s3, 32, 64);

    float dv = dinv[n];
    float o0 = fmaf(dv, s0, b4.x);
    float o1 = fmaf(dv, s1, b4.y);
    float o2 = fmaf(dv, s2, b4.z);
    float o3 = fmaf(dv, s3, b4.w);

    if (g == 0) {
        float4 ov; ov.x = o0; ov.y = o1; ov.z = o2; ov.w = o3;
        *reinterpret_cast<float4*>(ofp + (size_t)n * 64 + cl * 4) = ov;
    }
    // redistribute: lane converts channel `lane`
    int jc = lane >> 2;
    float a0 = __shfl(o0, jc, 64);
    float a1 = __shfl(o1, jc, 64);
    float a2 = __shfl(o2, jc, 64);
    float a3 = __shfl(o3, jc, 64);
    int sel = lane & 3;
    float mv = (sel == 0) ? a0 : (sel == 1) ? a1 : (sel == 2) ? a2 : a3;
    henc8[(size_t)n * 64 + lane] = f2fp8(16.0f * mv);
}

// ---------------- edge decoder (MFMA fp8, swapped operands) ----------------
// D[ch][edge] = Wd1^T . feat : A = FWD1 frag (A-layout == B-layout for 16x16),
// B = edge features (same per-lane loads as before). Each lane ends with 16
// channels of ONE edge (ch = 16*mt + 4*quad + r) -> Wd2 dot needs only a
// 2-step shfl reduce over quad, and the store is one coalesced 16-lane row.
#define DEC_TPW 4
#define DEC_TILES (E_FULL / 16)

__global__ void __launch_bounds__(256) k_dec(const int* __restrict__ src,
                                             const int* __restrict__ dst,
                                             const unsigned char* __restrict__ h8,
                                             const float* __restrict__ ws,
                                             float* __restrict__ out) {
    int lane = threadIdx.x & 63;
    int wv = threadIdx.x >> 6;
    int m = lane & 15;
    int quad = lane >> 4;

    const unsigned char* fw = (const unsigned char*)(ws + OFF_FWD1);
    long bfr[4][4];
#pragma unroll
    for (int c = 0; c < 4; c++)
#pragma unroll
        for (int t = 0; t < 4; t++)
            bfr[c][t] = *reinterpret_cast<const long*>(fw + ((c * 4 + t) * 512 + lane * 8));

    // per-lane channel constants: ch = 16*mt + 4*quad + r
    float4 w2v[4], b1v[4];
#pragma unroll
    for (int mt = 0; mt < 4; mt++) {
        w2v[mt] = *reinterpret_cast<const float4*>(ws + OFF_Wd2 + 16 * mt + 4 * quad);
        b1v[mt] = *reinterpret_cast<const float4*>(ws + OFF_bd1 + 16 * mt + 4 * quad);
    }
    float b2 = ws[OFF_bd2];

    int tile0 = (blockIdx.x * 4 + wv) * DEC_TPW;
    int tc = min(tile0, DEC_TILES - 1);
    int s0 = src[tc * 16 + m], d0 = dst[tc * 16 + m];
    tc = min(tile0 + 1, DEC_TILES - 1);
    int s1 = src[tc * 16 + m], d1 = dst[tc * 16 + m];
    long A0[4];
#pragma unroll
    for (int c = 0; c < 4; c++) {
        int row = (c < 2) ? s0 : d0;
        A0[c] = *reinterpret_cast<const long*>(
            h8 + (size_t)row * 64 + (c & 1) * 32 + 8 * quad);
    }

    for (int i = 0; i < DEC_TPW; i++) {
        int tile = tile0 + i;
        int t2 = min(tile0 + i + 2, DEC_TILES - 1);
        int s2 = src[t2 * 16 + m], d2 = dst[t2 * 16 + m];
        long A1[4];
#pragma unroll
        for (int c = 0; c < 4; c++) {
            int row = (c < 2) ? s1 : d1;
            A1[c] = *reinterpret_cast<const long*>(
                h8 + (size_t)row * 64 + (c & 1) * 32 + 8 * quad);
        }
        f32x4 acc[4] = {f32x4{0,0,0,0}, f32x4{0,0,0,0}, f32x4{0,0,0,0}, f32x4{0,0,0,0}};
#pragma unroll
        for (int c = 0; c < 4; c++)
#pragma unroll
            for (int mt = 0; mt < 4; mt++)
                acc[mt] = __builtin_amdgcn_mfma_f32_16x16x32_fp8_fp8(bfr[c][mt], A0[c], acc[mt], 0, 0, 0);

        // epilogue: 16 silu (independent) + Wd2 dot, all for edge (lane&15)
        float p[4];
#pragma unroll
        for (int mt = 0; mt < 4; mt++) {
            float pm = 0.0f;
#pragma unroll
            for (int r = 0; r < 4; r++) {
                float v = fmaf(acc[mt][r], 0.00390625f, b1v[mt][r]);   // /256 un-scale
                float h = v * __builtin_amdgcn_rcpf(1.0f + __expf(-v));
                pm = fmaf(h, w2v[mt][r], pm);
            }
            p[mt] = pm;
        }
        float sv = (p[0] + p[1]) + (p[2] + p[3]);
        sv += __shfl_xor(sv, 16, 64);
        sv += __shfl_xor(sv, 32, 64);
        if (lane < 16 && tile < DEC_TILES)
            out[tile * 16 + lane] = sv + b2;

#pragma unroll
        for (int c = 0; c < 4; c++) A0[c] = A1[c];
        s1 = s2; d1 = d2;
    }
}

extern "C" void kernel_launch(void* const* d_in, const int* in_sizes, int n_in,
                              void* d_out, int out_size, void* d_ws, size_t ws_size,
                              hipStream_t stream) {
    if (n_in < 18) return;
    const void* x              = d_in[0];
    const int* edge_index      = (const int*)d_in[1];
    const int* full_edge_index = (const int*)d_in[2];
    const int* tsteps          = (const int*)d_in[3];
    float* ws = (float*)d_ws;
    float* out = (float*)d_out;

    int*   iws   = (int*)d_ws;
    int*   bsum  = iws + OFF_BSUM;
    int*   bcur  = iws + OFF_BCUR;
    int*   ptr   = iws + OFF_PTR;
    int*   elist = iws + OFF_ELIST;
    uint2* tmp   = (uint2*)(iws + OFF_TMP2);
    unsigned short* zbf  = (unsigned short*)(ws + OFF_ZBF);
    unsigned short* zbf2 = (unsigned short*)(ws + OFF_ZBF2);
    unsigned char*  h8   = (unsigned char*)(ws + OFF_HENC8);

    CvtArgs ca;
    for (int i = 0; i < 14; i++) ca.src[i] = d_in[4 + i];

    // zero bucket totals + relative cursors (contiguous 512 ints)
    hipMemsetAsync(bsum, 0, (size_t)512 * 4, stream);

    // fused prep: edge bucket histogram + cvt + frag tables + t_emb
    k_wprep<<<WP_TOTAL_NB, 256, 0, stream>>>(ca, edge_index + E_MSG, bsum, ws);

    // CSR: bucketed scatter (in-LDS prefix) -> per-bucket sort (+ptr/dinv)
    k_bfill<<<SCAN_NB, 256, 0, stream>>>(edge_index, edge_index + E_MSG, bsum,
                                         bcur, tmp);
    k_csort2<<<SCAN_NB, 256, 0, stream>>>(tmp, bsum, ptr, ws + OFF_DINV, elist);

    // embedder + fused lin0 (h_embed -> d_out fp32; z0 -> zbf)
    k_embed<<<(N_NODES / 16 + 3) / 4, 256, 0, stream>>>(
        x, (const unsigned short*)d_in[4], tsteps, ws, out + E_FULL, zbf);

    // gather0 + relu + fused lin1 (MFMA): zbf -> zbf2
    k_gather0<<<N_NODES / 16, 256, 0, stream>>>(zbf, ptr, elist, ws, zbf2);

    // gather1: zbf2 -> {out fp32, h8 fp8x16}
    k_gather1<<<N_NODES / 4, 256, 0, stream>>>(
        zbf2, ptr, elist, ws + OFF_DINV, ws + OFF_bc1, h8,
        out + E_FULL + (size_t)N_NODES * 64);

    // decoder (fp8 MFMA, swapped operands)
    int dec_blocks = (DEC_TILES + 4 * DEC_TPW - 1) / (4 * DEC_TPW);
    k_dec<<<dec_blocks, 256, 0, stream>>>(full_edge_index, full_edge_index + E_FULL,
                                          h8, ws, out);
}

// Round 6
// 262.324 us; speedup vs baseline: 2.2012x; 1.0015x over previous
//
#include <hip/hip_runtime.h>
#include <hip/hip_bf16.h>
#include <math.h>

#define N_NODES 50000
#define E_MSG   800000
#define E_FULL  1000000
#define IN_C    128
#define H_C     64
#define T_STEPS 128

// ---- workspace layout (in floats) ----
#define OFF_Win   0
#define OFF_bin   8192
#define OFF_Wt1   8256
#define OFF_bt1   24640
#define OFF_Wt2   24896
#define OFF_bt2   41280
#define OFF_Wc0   41344
#define OFF_bc0   45440
#define OFF_Wc1   45504
#define OFF_bc1   49600
#define OFF_Wd1   49664
#define OFF_bd1   57856
#define OFF_Wd2   57920
#define OFF_bd2   57984
#define W_TOTAL   57985
#define OFF_BSUM  58016                 // 256 ints (bucket TOTALS)
#define OFF_BCUR  58272                 // 256 ints (relative cursors, memset 0)
#define OFF_FWD1  58624                 // 8192 fp8 bytes (16*Wd1 frag table)
#define OFF_FWIN  60672                 // 8192 bf16 (W_in frag table)
#define OFF_FWC0  64768                 // 4096 bf16 (Wc0 frag table)
#define OFF_TEMB  66816                 // 128*64 floats
#define OFF_DINV  75008                 // 50000 floats
#define OFF_FWC1  125008                // 2048 floats (Wc1 frag table; ex-CNT)
#define OFF_PTR   175008                // 50001 ints
#define OFF_ELIST 225010                // 800000 ints
#define OFF_TMP2  1025012               // 1.6M ints (800000 uint2), 8B aligned
#define OFF_ZBF   2625012               // 3.2M bf16 (z0)
#define OFF_ZBF2  4225012               // 3.2M bf16 (z1)
#define OFF_HENC8 5825012               // 3.2M fp8 bytes
// total 6,625,012 floats = 26.5 MB

#define SCAN_NB   ((N_NODES + 255) / 256)   // 196 buckets
#define BF_CH     ((E_MSG + SCAN_NB - 1) / SCAN_NB)   // 4082 edges/block
#define BC_NB     392
#define BC_CH     ((E_MSG + BC_NB - 1) / BC_NB)       // 2041 edges/block

typedef __attribute__((ext_vector_type(8))) short bf16x8;
typedef __attribute__((ext_vector_type(4))) float f32x4;

static __device__ __forceinline__ float bf2f(unsigned short u) {
    return __uint_as_float(((unsigned)u) << 16);
}
static __device__ __forceinline__ unsigned short f2bf(float f) {
    unsigned u = __float_as_uint(f);
    unsigned r = (u + 0x7fffu + ((u >> 16) & 1u)) >> 16;
    return (unsigned short)r;
}
// fp32 -> fp8 e4m3fn, RNE, clamp to +-448
static __device__ __forceinline__ unsigned char f2fp8(float f) {
    unsigned u = __float_as_uint(f);
    unsigned s = (u >> 24) & 0x80;
    float a = fminf(__uint_as_float(u & 0x7FFFFFFF), 448.0f);
    if (a < 0.015625f) {
        int qi = (int)rintf(a * 512.0f);
        return (unsigned char)(s | qi);
    }
    unsigned ua = __float_as_uint(a);
    int e = (int)((ua >> 23) & 0xFF) - 127;
    unsigned man = (ua & 0x7FFFFF) | 0x800000;
    unsigned r = man >> 20;
    unsigned rem = man & 0xFFFFF;
    if (rem > 0x80000u || (rem == 0x80000u && (r & 1))) r++;
    if (r == 16) { r = 8; e++; }
    if (e > 8) return (unsigned char)(s | 0x7E);
    return (unsigned char)(s | ((unsigned)(e + 7) << 3) | (r & 7));
}
static __device__ __forceinline__ bool detect_f32(const unsigned short* w, int* scnt) {
    if (threadIdx.x == 0) *scnt = 0;
    __syncthreads();
    int big = 0;
    for (int i = threadIdx.x; i < 2048; i += blockDim.x)
        if (fabsf(bf2f(w[2 * i])) > 0.5f) big++;
    atomicAdd(scnt, big);
    __syncthreads();
    return *scnt > 64;
}
// raw-weight load with dtype dispatch
static __device__ __forceinline__ float ldw(const void* p, int idx, bool f32) {
    return f32 ? ((const float*)p)[idx] : bf2f(((const unsigned short*)p)[idx]);
}

// ---------------- CSR build ----------------
// bucketed scatter: per-block LDS histogram + in-LDS bucket prefix +
// one reservation atomic per (block, bucket) into relative cursors
__global__ void __launch_bounds__(256) k_bfill(const int* __restrict__ row,
                                               const int* __restrict__ col,
                                               const int* __restrict__ btot,
                                               int* __restrict__ bcur,
                                               uint2* __restrict__ tmp) {
    __shared__ int pref[256];
    __shared__ int hist[SCAN_NB];
    __shared__ int basew[SCAN_NB];
    int b = blockIdx.x, t = threadIdx.x;

    // in-LDS exclusive prefix of bucket totals
    int tv = (t < SCAN_NB) ? btot[t] : 0;
    pref[t] = tv;
    __syncthreads();
    for (int off = 1; off < 256; off <<= 1) {
        int u = (t >= off) ? pref[t - off] : 0;
        __syncthreads();
        pref[t] += u;
        __syncthreads();
    }
    int excl_t = pref[t] - tv;          // exclusive prefix for bucket t

    int lo = b * BF_CH;
    int hi = lo + BF_CH; if (hi > E_MSG) hi = E_MSG;
    for (int i = t; i < SCAN_NB; i += 256) hist[i] = 0;
    __syncthreads();
    for (int e = lo + t; e < hi; e += 256)
        atomicAdd(&hist[col[e] >> 8], 1);
    __syncthreads();
    if (t < SCAN_NB) {
        int c = hist[t];
        basew[t] = (c > 0) ? excl_t + atomicAdd(&bcur[t], c) : 0;
    }
    __syncthreads();
    for (int i = t; i < SCAN_NB; i += 256) hist[i] = 0;  // reuse as cursor
    __syncthreads();
    for (int e = lo + t; e < hi; e += 256) {
        int src = row[e], c = col[e];
        int bk = c >> 8;
        int off = atomicAdd(&hist[bk], 1);
        tmp[basew[bk] + off] = uint2{(unsigned)src, (unsigned)c};
    }
}

// per bucket: in-LDS bucket prefix -> [start,end); LDS degree count + prefix
// -> ptr/dinv; LDS-cursor scatter. No per-node global atomics.
__global__ void __launch_bounds__(256) k_csort2(const uint2* __restrict__ tmp,
                                                const int* __restrict__ btot,
                                                int* __restrict__ ptr,
                                                float* __restrict__ dinv,
                                                int* __restrict__ elist) {
    __shared__ int deg[256];
    __shared__ int pfx[256];
    int b = blockIdx.x, t = threadIdx.x;

    // bucket prefix (reuse pfx)
    int tv = (t < SCAN_NB) ? btot[t] : 0;
    pfx[t] = tv;
    __syncthreads();
    for (int off = 1; off < 256; off <<= 1) {
        int u = (t >= off) ? pfx[t - off] : 0;
        __syncthreads();
        pfx[t] += u;
        __syncthreads();
    }
    __shared__ int se[2];
    if (t == b) { se[0] = pfx[t] - tv; se[1] = pfx[t]; }
    __syncthreads();
    int start = se[0], end = se[1];

    deg[t] = 0;
    __syncthreads();
    for (int e = start + t; e < end; e += 256)
        atomicAdd(&deg[tmp[e].y & 255], 1);
    __syncthreads();

    int v = deg[t];
    pfx[t] = v;
    __syncthreads();
    for (int off = 1; off < 256; off <<= 1) {
        int u = (t >= off) ? pfx[t - off] : 0;
        __syncthreads();
        pfx[t] += u;
        __syncthreads();
    }
    int excl = pfx[t] - v;
    int n = (b << 8) + t;
    if (n < N_NODES) {
        ptr[n] = start + excl;
        dinv[n] = rsqrtf((float)v + 1.0f);
    }
    if (b == 0 && t == 0) ptr[N_NODES] = E_MSG;
    __syncthreads();
    deg[t] = excl;                       // reuse as local cursor
    __syncthreads();
    for (int e = start + t; e < end; e += 256) {
        uint2 p = tmp[e];
        int pos = atomicAdd(&deg[p.y & 255], 1);
        elist[start + pos] = (int)p.x;
    }
}

// ---------------- fused prep: bucket-count + cvt + frag tables + temb ----------
// blocks [0,392): edge bucket histogram (independent of weights)
// blocks [392,619): cvt -> ws fp32
// blocks [619,715): MFMA B-frag tables (read RAW weights, convert inline)
// blocks [715,843): t_emb, ONE timestep per block, 4-way k-split
#define WP_BC_NB   392
#define WP_CVT_NB  227
#define WP_PREP_NB 96
#define WP_TEMB_NB 128
#define WP_TOTAL_NB (WP_BC_NB + WP_CVT_NB + WP_PREP_NB + WP_TEMB_NB)

struct CvtArgs { const void* src[14]; };

__global__ void __launch_bounds__(256) k_wprep(CvtArgs a,
                                               const int* __restrict__ ecol,
                                               int* __restrict__ bsum,
                                               float* ws) {
    __shared__ int scnt;
    int bid = blockIdx.x;
    int tid = threadIdx.x;

    if (bid < WP_BC_NB) {
        // bucket totals: per-block LDS 196-bin histogram
        __shared__ int hist[SCAN_NB];
        for (int i = tid; i < SCAN_NB; i += 256) hist[i] = 0;
        __syncthreads();
        int lo = bid * BC_CH;
        int hi = lo + BC_CH; if (hi > E_MSG) hi = E_MSG;
        for (int e = lo + tid; e < hi; e += 256)
            atomicAdd(&hist[ecol[e] >> 8], 1);
        __syncthreads();
        for (int i = tid; i < SCAN_NB; i += 256) {
            int c = hist[i];
            if (c > 0) atomicAdd(&bsum[i], c);
        }
        return;
    }
    bid -= WP_BC_NB;

    bool f32 = detect_f32((const unsigned short*)a.src[0], &scnt);

    if (bid < WP_CVT_NB) {
        int t = bid * 256 + tid;
        if (t >= W_TOTAL) return;
        const int starts[14] = {OFF_Win, OFF_bin, OFF_Wt1, OFF_bt1, OFF_Wt2, OFF_bt2,
                                OFF_Wc0, OFF_bc0, OFF_Wc1, OFF_bc1, OFF_Wd1, OFF_bd1,
                                OFF_Wd2, OFF_bd2};
        int seg = 0;
#pragma unroll
        for (int i = 1; i < 14; i++)
            if (t >= starts[i]) seg = i;
        ws[t] = ldw(a.src[seg], t - starts[seg], f32);
    } else if (bid < WP_CVT_NB + WP_PREP_NB) {
        int idx = (bid - WP_CVT_NB) * 256 + tid;       // 0..24575
        int local, j, lane, ct, c, t, m, q;
        if (idx < 8192) {
            local = idx;
            j = local & 7; lane = (local >> 3) & 63; ct = local >> 9;
            c = ct >> 2; t = ct & 3; m = lane & 15; q = lane >> 4;
            ((unsigned char*)(ws + OFF_FWD1))[local] =
                f2fp8(16.0f * ldw(a.src[10], (32 * c + 8 * q + j) * 64 + 16 * t + m, f32));
        } else if (idx < 16384) {
            local = idx - 8192;
            j = local & 7; lane = (local >> 3) & 63; ct = local >> 9;
            c = ct >> 2; t = ct & 3; m = lane & 15; q = lane >> 4;
            ((unsigned short*)(ws + OFF_FWIN))[local] =
                f2bf(ldw(a.src[0], (32 * c + 8 * q + j) * 64 + 16 * t + m, f32));
        } else if (idx < 20480) {
            local = idx - 16384;
            j = local & 7; lane = (local >> 3) & 63; ct = local >> 9;
            c = ct >> 2; t = ct & 3; m = lane & 15; q = lane >> 4;
            ((unsigned short*)(ws + OFF_FWC0))[local] =
                f2bf(ldw(a.src[6], (32 * c + 8 * q + j) * 64 + 16 * t + m, f32));
        } else {
            local = idx - 20480;
            j = local & 7; lane = (local >> 3) & 63; ct = local >> 9;
            c = ct >> 2; t = ct & 3; m = lane & 15; q = lane >> 4;
            ((unsigned short*)(ws + OFF_FWC1))[local] =
                f2bf(ldw(a.src[8], (32 * c + 8 * q + j) * 64 + 16 * t + m, f32));
        }
    } else {
        // t_emb: one timestep per block; threads (j = tid&63, kg = tid>>6)
        __shared__ float pe[64];
        __shared__ float us4[4][256];
        __shared__ float us[256];
        __shared__ float pcs[4][64];
        int j = tid & 63;
        int kg = tid >> 6;
        int t = bid - WP_CVT_NB - WP_PREP_NB;

        if (tid < 64) {
            float xt = (float)t * (4000.0f / 128.0f);
            float sc = -logf(10000.0f) / 31.0f;
            float fr = __expf((float)(tid & 31) * sc);
            float ang = xt * fr;
            pe[tid] = (tid < 32) ? sinf(ang) : cosf(ang);
        }
        __syncthreads();

        float pu[4] = {0.f, 0.f, 0.f, 0.f};
#pragma unroll
        for (int kk = 0; kk < 16; kk++) {
            int k = 16 * kg + kk;
            float p = pe[k];
#pragma unroll
            for (int q = 0; q < 4; q++)
                pu[q] = fmaf(p, ldw(a.src[2], k * 256 + q * 64 + j, f32), pu[q]);
        }
#pragma unroll
        for (int q = 0; q < 4; q++) us4[kg][q * 64 + j] = pu[q];
        __syncthreads();

        {
            float uu = ldw(a.src[3], tid, f32) +
                       us4[0][tid] + us4[1][tid] + us4[2][tid] + us4[3][tid];
            us[tid] = uu * __builtin_amdgcn_rcpf(1.0f + __expf(-uu));
        }
        __syncthreads();

        float pc = 0.f;
#pragma unroll
        for (int kk = 0; kk < 64; kk++) {
            int k = 64 * kg + kk;
            pc = fmaf(us[k], ldw(a.src[4], k * 64 + j, f32), pc);
        }
        pcs[kg][j] = pc;
        __syncthreads();
        if (tid < 64) {
            float acc = ldw(a.src[5], j, f32) +
                        pcs[0][j] + pcs[1][j] + pcs[2][j] + pcs[3][j];
            (ws + OFF_TEMB)[t * 64 + j] = acc;
        }
    }
}

// ---------------- embedder + fused GCN-linear-0 (MFMA x2) ----------------
__global__ void __launch_bounds__(256) k_embed(const void* __restrict__ xraw,
                                               const unsigned short* __restrict__ wdet,
                                               const int* __restrict__ tsteps,
                                               float* __restrict__ ws,
                                               float* __restrict__ out_hembed,
                                               unsigned short* __restrict__ zbf) {
    __shared__ int scnt;
    __shared__ unsigned short tl[4][16 * 64];
    bool f32 = detect_f32(wdet, &scnt);

    int lane = threadIdx.x & 63;
    int wv = threadIdx.x >> 6;
    int m = lane & 15, quad = lane >> 4;
    int wid = blockIdx.x * 4 + wv;
    if (wid > N_NODES / 16 - 1) wid = N_NODES / 16 - 1;   // clamp (dup work benign)
    int n0 = wid * 16;

    const unsigned short* fwin = (const unsigned short*)(ws + OFF_FWIN);
    const unsigned short* fwc0 = (const unsigned short*)(ws + OFF_FWC0);

    bf16x8 bI[4][4];
#pragma unroll
    for (int c = 0; c < 4; c++)
#pragma unroll
        for (int t = 0; t < 4; t++)
            bI[c][t] = *reinterpret_cast<const bf16x8*>(fwin + (c * 4 + t) * 512 + lane * 8);

    f32x4 acc[4] = {f32x4{0,0,0,0}, f32x4{0,0,0,0}, f32x4{0,0,0,0}, f32x4{0,0,0,0}};
#pragma unroll
    for (int c = 0; c < 4; c++) {
        bf16x8 a;
        if (f32) {
            const float* xp = (const float*)xraw + (size_t)(n0 + m) * 128 + 32 * c + 8 * quad;
            float4 v0 = *reinterpret_cast<const float4*>(xp);
            float4 v1 = *reinterpret_cast<const float4*>(xp + 4);
            a[0] = (short)f2bf(v0.x); a[1] = (short)f2bf(v0.y);
            a[2] = (short)f2bf(v0.z); a[3] = (short)f2bf(v0.w);
            a[4] = (short)f2bf(v1.x); a[5] = (short)f2bf(v1.y);
            a[6] = (short)f2bf(v1.z); a[7] = (short)f2bf(v1.w);
        } else {
            a = *reinterpret_cast<const bf16x8*>(
                (const unsigned short*)xraw + (size_t)(n0 + m) * 128 + 32 * c + 8 * quad);
        }
#pragma unroll
        for (int t = 0; t < 4; t++)
            acc[t] = __builtin_amdgcn_mfma_f32_16x16x32_bf16(a, bI[c][t], acc[t], 0, 0, 0);
    }

    int tn[4];
#pragma unroll
    for (int r = 0; r < 4; r++) tn[r] = tsteps[n0 + 4 * quad + r];
    const float* temb = ws + OFF_TEMB;
#pragma unroll
    for (int t = 0; t < 4; t++) {
        int ch = 16 * t + m;
        float bj = ws[OFF_bin + ch];
#pragma unroll
        for (int r = 0; r < 4; r++) {
            int node = n0 + 4 * quad + r;
            float v = acc[t][r] + bj + temb[tn[r] * 64 + ch];
            out_hembed[(size_t)node * 64 + ch] = v;
            tl[wv][(4 * quad + r) * 64 + ch] = f2bf(v);
        }
    }
    __syncthreads();

    bf16x8 bC[2][4];
#pragma unroll
    for (int c = 0; c < 2; c++)
#pragma unroll
        for (int t = 0; t < 4; t++)
            bC[c][t] = *reinterpret_cast<const bf16x8*>(fwc0 + (c * 4 + t) * 512 + lane * 8);

    f32x4 az[4] = {f32x4{0,0,0,0}, f32x4{0,0,0,0}, f32x4{0,0,0,0}, f32x4{0,0,0,0}};
#pragma unroll
    for (int c = 0; c < 2; c++) {
        bf16x8 a2 = *reinterpret_cast<const bf16x8*>(&tl[wv][m * 64 + 32 * c + 8 * quad]);
#pragma unroll
        for (int t = 0; t < 4; t++)
            az[t] = __builtin_amdgcn_mfma_f32_16x16x32_bf16(a2, bC[c][t], az[t], 0, 0, 0);
    }
    const float* dinv = ws + OFF_DINV;
    float dv[4];
#pragma unroll
    for (int r = 0; r < 4; r++) dv[r] = dinv[n0 + 4 * quad + r];
#pragma unroll
    for (int t = 0; t < 4; t++) {
        int ch = 16 * t + m;
#pragma unroll
        for (int r = 0; r < 4; r++)
            zbf[(size_t)(n0 + 4 * quad + r) * 64 + ch] = f2bf(az[t][r] * dv[r]);
    }
}

// ---------------- gather-0 + relu + fused GCN-linear-1 (MFMA) ----------------
__global__ void __launch_bounds__(256) k_gather0(const unsigned short* __restrict__ zbf,
                                                 const int* __restrict__ ptr,
                                                 const int* __restrict__ elist,
                                                 const float* __restrict__ ws,
                                                 unsigned short* __restrict__ zout) {
    __shared__ unsigned short tile[16 * 64];     // 2KB, swizzled bf16 [16][64]
    const float* dinv = ws + OFF_DINV;
    const float* bias = ws + OFF_bc0;
    const unsigned short* fwc1 = (const unsigned short*)(ws + OFF_FWC1);

    int lane = threadIdx.x & 63;
    int wv = threadIdx.x >> 6;
    int g = lane >> 4;              // neighbor sub-group 0..3
    int cl = lane & 15;             // channel quad: channels 4cl..4cl+3
    int n0 = blockIdx.x * 16;

    float4 b4 = *reinterpret_cast<const float4*>(bias + 4 * cl);

#pragma unroll
    for (int snode = 0; snode < 4; snode++) {
        int li = wv * 4 + snode;    // local tile row
        int n = n0 + li;
        int base = ptr[n], end = ptr[n + 1];

        float ws0 = (g == 0) ? 1.0f : 0.0f;
        ushort4 sv = *reinterpret_cast<const ushort4*>(zbf + (size_t)n * 64 + cl * 4);
        float s0 = ws0 * bf2f(sv.x), s1 = ws0 * bf2f(sv.y);
        float s2 = ws0 * bf2f(sv.z), s3 = ws0 * bf2f(sv.w);

        for (int k = base; k < end; k += 8) {
            int e0 = k + g, e1 = k + 4 + g;
            int r0 = elist[min(e0, end - 1)];
            int r1 = elist[min(e1, end - 1)];
            ushort4 v0 = *reinterpret_cast<const ushort4*>(zbf + (size_t)r0 * 64 + cl * 4);
            ushort4 v1 = *reinterpret_cast<const ushort4*>(zbf + (size_t)r1 * 64 + cl * 4);
            float w0 = (e0 < end) ? 1.0f : 0.0f;
            float w1 = (e1 < end) ? 1.0f : 0.0f;
            s0 = fmaf(w0, bf2f(v0.x), s0); s1 = fmaf(w0, bf2f(v0.y), s1);
            s2 = fmaf(w0, bf2f(v0.z), s2); s3 = fmaf(w0, bf2f(v0.w), s3);
            s0 = fmaf(w1, bf2f(v1.x), s0); s1 = fmaf(w1, bf2f(v1.y), s1);
            s2 = fmaf(w1, bf2f(v1.z), s2); s3 = fmaf(w1, bf2f(v1.w), s3);
        }
        s0 += __shfl_xor(s0, 16, 64); s0 += __shfl_xor(s0, 32, 64);
        s1 += __shfl_xor(s1, 16, 64); s1 += __shfl_xor(s1, 32, 64);
        s2 += __shfl_xor(s2, 16, 64); s2 += __shfl_xor(s2, 32, 64);
        s3 += __shfl_xor(s3, 16, 64); s3 += __shfl_xor(s3, 32, 64);

        if (g == 0) {
            float dv = dinv[n];
            float h0 = fmaxf(fmaf(dv, s0, b4.x), 0.0f);
            float h1 = fmaxf(fmaf(dv, s1, b4.y), 0.0f);
            float h2 = fmaxf(fmaf(dv, s2, b4.z), 0.0f);
            float h3 = fmaxf(fmaf(dv, s3, b4.w), 0.0f);
            ushort4 hv;
            hv.x = f2bf(h0); hv.y = f2bf(h1); hv.z = f2bf(h2); hv.w = f2bf(h3);
            int bo = li * 128 + ((cl * 8) ^ ((li & 7) << 4));   // XOR-swizzle (G4)
            *reinterpret_cast<ushort4*>((char*)tile + bo) = hv;
        }
    }
    __syncthreads();

    // phase 2: wave wv computes output channels 16*wv..16*wv+15 for all 16 nodes
    int m = lane & 15, q = lane >> 4;
    bf16x8 bB0 = *reinterpret_cast<const bf16x8*>(fwc1 + (0 * 4 + wv) * 512 + lane * 8);
    bf16x8 bB1 = *reinterpret_cast<const bf16x8*>(fwc1 + (1 * 4 + wv) * 512 + lane * 8);

    f32x4 az = f32x4{0, 0, 0, 0};
    {
        int bo0 = m * 128 + ((0 * 64 + q * 16) ^ ((m & 7) << 4));
        bf16x8 a0 = *reinterpret_cast<const bf16x8*>((const char*)tile + bo0);
        az = __builtin_amdgcn_mfma_f32_16x16x32_bf16(a0, bB0, az, 0, 0, 0);
        int bo1 = m * 128 + ((1 * 64 + q * 16) ^ ((m & 7) << 4));
        bf16x8 a1 = *reinterpret_cast<const bf16x8*>((const char*)tile + bo1);
        az = __builtin_amdgcn_mfma_f32_16x16x32_bf16(a1, bB1, az, 0, 0, 0);
    }
    float dv4[4];
#pragma unroll
    for (int r = 0; r < 4; r++) dv4[r] = dinv[n0 + 4 * q + r];
#pragma unroll
    for (int r = 0; r < 4; r++) {
        int node = n0 + 4 * q + r;
        zout[(size_t)node * 64 + 16 * wv + m] = f2bf(az[r] * dv4[r]);
    }
}

// ---------------- gather-1 -> h_enc (fp32 out + fp8x16 table) ----------------
__global__ void __launch_bounds__(256) k_gather1(const unsigned short* __restrict__ zbf,
                                                 const int* __restrict__ ptr,
                                                 const int* __restrict__ elist,
                                                 const float* __restrict__ dinv,
                                                 const float* __restrict__ bias,
                                                 unsigned char* __restrict__ henc8,
                                                 float* __restrict__ ofp) {
    int lane = threadIdx.x & 63;
    int n = blockIdx.x * 4 + (threadIdx.x >> 6);
    int g = lane >> 4;
    int cl = lane & 15;
    int base = ptr[n], end = ptr[n + 1];

    float4 b4 = *reinterpret_cast<const float4*>(bias + 4 * cl);

    float ws0 = (g == 0) ? 1.0f : 0.0f;
    ushort4 sv = *reinterpret_cast<const ushort4*>(zbf + (size_t)n * 64 + cl * 4);
    float s0 = ws0 * bf2f(sv.x), s1 = ws0 * bf2f(sv.y);
    float s2 = ws0 * bf2f(sv.z), s3 = ws0 * bf2f(sv.w);

    for (int k = base; k < end; k += 8) {
        int e0 = k + g, e1 = k + 4 + g;
        int r0 = elist[min(e0, end - 1)];
        int r1 = elist[min(e1, end - 1)];
        ushort4 v0 = *reinterpret_cast<const ushort4*>(zbf + (size_t)r0 * 64 + cl * 4);
        ushort4 v1 = *reinterpret_cast<const ushort4*>(zbf + (size_t)r1 * 64 + cl * 4);
        float w0 = (e0 < end) ? 1.0f : 0.0f;
        float w1 = (e1 < end) ? 1.0f : 0.0f;
        s0 = fmaf(w0, bf2f(v0.x), s0); s1 = fmaf(w0, bf2f(v0.y), s1);
        s2 = fmaf(w0, bf2f(v0.z), s2); s3 = fmaf(w0, bf2f(v0.w), s3);
        s0 = fmaf(w1, bf2f(v1.x), s0); s1 = fmaf(w1, bf2f(v1.y), s1);
        s2 = fmaf(w1, bf2f(v1.z), s2); s3 = fmaf(w1, bf2f(v1.w), s3);
    }
    s0 += __shfl_xor(s0, 16, 64); s0 += __shfl_xor(s0, 32, 64);
    s1 += __shfl_xor(s1, 16, 64); s1 += __shfl_xor(s1, 32, 64);
    s2 += __shfl_xor(s2, 16, 64); s2 += __shfl_xor(s2, 32, 64);
    s3 += __shfl_xor(s3, 16, 64); s3 += __shfl_xor(s3, 32, 64);

    float dv = dinv[n];
    float o0 = fmaf(dv, s0, b4.x);
    float o1 = fmaf(dv, s1, b4.y);
    float o2 = fmaf(dv, s2, b4.z);
    float o3 = fmaf(dv, s3, b4.w);

    if (g == 0) {
        float4 ov; ov.x = o0; ov.y = o1; ov.z = o2; ov.w = o3;
        *reinterpret_cast<float4*>(ofp + (size_t)n * 64 + cl * 4) = ov;
    }
    // redistribute: lane converts channel `lane`
    int jc = lane >> 2;
    float a0 = __shfl(o0, jc, 64);
    float a1 = __shfl(o1, jc, 64);
    float a2 = __shfl(o2, jc, 64);
    float a3 = __shfl(o3, jc, 64);
    int sel = lane & 3;
    float mv = (sel == 0) ? a0 : (sel == 1) ? a1 : (sel == 2) ? a2 : a3;
    henc8[(size_t)n * 64 + lane] = f2fp8(16.0f * mv);
}

// ---------------- edge decoder (MFMA fp8, batched deep-ILP) ----------------
// Each wave owns 4 tiles. ALL index loads (8) and ALL A-row gathers (16) are
// issued before any compute: 16 independent gathers in flight per wave covers
// the L2/HBM latency once per 4 tiles instead of once per tile (the round-5
// structure was only 1 tile deep -> ~90% stall at 2.5 waves/SIMD).
#define DEC_TPW 4
#define DEC_TILES (E_FULL / 16)

__global__ void __launch_bounds__(256) k_dec(const int* __restrict__ src,
                                             const int* __restrict__ dst,
                                             const unsigned char* __restrict__ h8,
                                             const float* __restrict__ ws,
                                             float* __restrict__ out) {
    int lane = threadIdx.x & 63;
    int wv = threadIdx.x >> 6;
    int m = lane & 15;
    int quad = lane >> 4;

    const unsigned char* fw = (const unsigned char*)(ws + OFF_FWD1);
    long bfr[4][4];
#pragma unroll
    for (int c = 0; c < 4; c++)
#pragma unroll
        for (int t = 0; t < 4; t++)
            bfr[c][t] = *reinterpret_cast<const long*>(fw + ((c * 4 + t) * 512 + lane * 8));

    // per-lane channel constants: ch = 16*mt + 4*quad + r
    float4 w2v[4], b1v[4];
#pragma unroll
    for (int mt = 0; mt < 4; mt++) {
        w2v[mt] = *reinterpret_cast<const float4*>(ws + OFF_Wd2 + 16 * mt + 4 * quad);
        b1v[mt] = *reinterpret_cast<const float4*>(ws + OFF_bd1 + 16 * mt + 4 * quad);
    }
    float b2 = ws[OFF_bd2];

    int tile0 = (blockIdx.x * 4 + wv) * DEC_TPW;

    // phase 1: all indices for the 4 tiles
    int sg[DEC_TPW], dg[DEC_TPW];
#pragma unroll
    for (int i = 0; i < DEC_TPW; i++) {
        int tc = min(tile0 + i, DEC_TILES - 1);
        sg[i] = src[tc * 16 + m];
        dg[i] = dst[tc * 16 + m];
    }

    // phase 2: all 16 A-row gathers in flight
    long A[DEC_TPW][4];
#pragma unroll
    for (int i = 0; i < DEC_TPW; i++)
#pragma unroll
        for (int c = 0; c < 4; c++) {
            int row = (c < 2) ? sg[i] : dg[i];
            A[i][c] = *reinterpret_cast<const long*>(
                h8 + (size_t)row * 64 + (c & 1) * 32 + 8 * quad);
        }

    // phase 3: compute tiles back-to-back (epilogue of tile i overlaps
    // MFMAs of tile i+1 on the separate pipes)
#pragma unroll
    for (int i = 0; i < DEC_TPW; i++) {
        int tile = tile0 + i;
        f32x4 acc[4] = {f32x4{0,0,0,0}, f32x4{0,0,0,0}, f32x4{0,0,0,0}, f32x4{0,0,0,0}};
#pragma unroll
        for (int c = 0; c < 4; c++)
#pragma unroll
            for (int mt = 0; mt < 4; mt++)
                acc[mt] = __builtin_amdgcn_mfma_f32_16x16x32_fp8_fp8(bfr[c][mt], A[i][c], acc[mt], 0, 0, 0);

        float p[4];
#pragma unroll
        for (int mt = 0; mt < 4; mt++) {
            float pm = 0.0f;
#pragma unroll
            for (int r = 0; r < 4; r++) {
                float v = fmaf(acc[mt][r], 0.00390625f, b1v[mt][r]);   // /256 un-scale
                float h = v * __builtin_amdgcn_rcpf(1.0f + __expf(-v));
                pm = fmaf(h, w2v[mt][r], pm);
            }
            p[mt] = pm;
        }
        float sv = (p[0] + p[1]) + (p[2] + p[3]);
        sv += __shfl_xor(sv, 16, 64);
        sv += __shfl_xor(sv, 32, 64);
        if (lane < 16 && tile < DEC_TILES)
            out[tile * 16 + lane] = sv + b2;
    }
}

extern "C" void kernel_launch(void* const* d_in, const int* in_sizes, int n_in,
                              void* d_out, int out_size, void* d_ws, size_t ws_size,
                              hipStream_t stream) {
    if (n_in < 18) return;
    const void* x              = d_in[0];
    const int* edge_index      = (const int*)d_in[1];
    const int* full_edge_index = (const int*)d_in[2];
    const int* tsteps          = (const int*)d_in[3];
    float* ws = (float*)d_ws;
    float* out = (float*)d_out;

    int*   iws   = (int*)d_ws;
    int*   bsum  = iws + OFF_BSUM;
    int*   bcur  = iws + OFF_BCUR;
    int*   ptr   = iws + OFF_PTR;
    int*   elist = iws + OFF_ELIST;
    uint2* tmp   = (uint2*)(iws + OFF_TMP2);
    unsigned short* zbf  = (unsigned short*)(ws + OFF_ZBF);
    unsigned short* zbf2 = (unsigned short*)(ws + OFF_ZBF2);
    unsigned char*  h8   = (unsigned char*)(ws + OFF_HENC8);

    CvtArgs ca;
    for (int i = 0; i < 14; i++) ca.src[i] = d_in[4 + i];

    // zero bucket totals + relative cursors (contiguous 512 ints)
    hipMemsetAsync(bsum, 0, (size_t)512 * 4, stream);

    // fused prep: edge bucket histogram + cvt + frag tables + t_emb
    k_wprep<<<WP_TOTAL_NB, 256, 0, stream>>>(ca, edge_index + E_MSG, bsum, ws);

    // CSR: bucketed scatter (in-LDS prefix) -> per-bucket sort (+ptr/dinv)
    k_bfill<<<SCAN_NB, 256, 0, stream>>>(edge_index, edge_index + E_MSG, bsum,
                                         bcur, tmp);
    k_csort2<<<SCAN_NB, 256, 0, stream>>>(tmp, bsum, ptr, ws + OFF_DINV, elist);

    // embedder + fused lin0 (h_embed -> d_out fp32; z0 -> zbf)
    k_embed<<<(N_NODES / 16 + 3) / 4, 256, 0, stream>>>(
        x, (const unsigned short*)d_in[4], tsteps, ws, out + E_FULL, zbf);

    // gather0 + relu + fused lin1 (MFMA): zbf -> zbf2
    k_gather0<<<N_NODES / 16, 256, 0, stream>>>(zbf, ptr, elist, ws, zbf2);

    // gather1: zbf2 -> {out fp32, h8 fp8x16}
    k_gather1<<<N_NODES / 4, 256, 0, stream>>>(
        zbf2, ptr, elist, ws + OFF_DINV, ws + OFF_bc1, h8,
        out + E_FULL + (size_t)N_NODES * 64);

    // decoder (fp8 MFMA, batched deep-ILP)
    int dec_blocks = (DEC_TILES + 4 * DEC_TPW - 1) / (4 * DEC_TPW);
    k_dec<<<dec_blocks, 256, 0, stream>>>(full_edge_index, full_edge_index + E_FULL,
                                          h8, ws, out);
}

// Round 8
// 253.658 us; speedup vs baseline: 2.2764x; 1.0342x over previous
//
#include <hip/hip_runtime.h>
#include <hip/hip_bf16.h>
#include <math.h>

#define N_NODES 50000
#define E_MSG   800000
#define E_FULL  1000000
#define IN_C    128
#define H_C     64
#define T_STEPS 128

// ---- workspace layout (in floats) ----
#define OFF_Win   0
#define OFF_bin   8192
#define OFF_Wt1   8256
#define OFF_bt1   24640
#define OFF_Wt2   24896
#define OFF_bt2   41280
#define OFF_Wc0   41344
#define OFF_bc0   45440
#define OFF_Wc1   45504
#define OFF_bc1   49600
#define OFF_Wd1   49664
#define OFF_bd1   57856
#define OFF_Wd2   57920
#define OFF_bd2   57984
#define W_TOTAL   57985
#define OFF_BSUM  58016                 // 256 ints (bucket TOTALS)
#define OFF_BCUR  58272                 // 256 ints (relative cursors, memset 0)
#define OFF_FWD1  58624                 // 8192 fp8 bytes (16*Wd1 frag table)
#define OFF_FWIN  60672                 // 8192 bf16 (W_in frag table)
#define OFF_FWC0  64768                 // 4096 bf16 (Wc0 frag table)
#define OFF_TEMB  66816                 // 128*64 floats
#define OFF_DINV  75008                 // 50000 floats
#define OFF_FWC1  125008                // 2048 floats (Wc1 frag table; ex-CNT)
#define OFF_PTR   175008                // 50001 ints
#define OFF_ELIST 225010                // 800000 ints
#define OFF_TMP2  1025012               // 1.6M ints (800000 uint2), 8B aligned
#define OFF_ZBF   2625012               // 3.2M bf16 (z0)
#define OFF_ZBF2  4225012               // 3.2M bf16 (z1)
#define OFF_HENC8 5825012               // 3.2M fp8 bytes
// total 6,625,012 floats = 26.5 MB

#define SCAN_NB   ((N_NODES + 255) / 256)   // 196 buckets
#define BF_CH     ((E_MSG + SCAN_NB - 1) / SCAN_NB)   // 4082 edges/block
#define BC_NB     392
#define BC_CH     ((E_MSG + BC_NB - 1) / BC_NB)       // 2041 edges/block

typedef __attribute__((ext_vector_type(8))) short bf16x8;
typedef __attribute__((ext_vector_type(4))) float f32x4;

static __device__ __forceinline__ float bf2f(unsigned short u) {
    return __uint_as_float(((unsigned)u) << 16);
}
static __device__ __forceinline__ unsigned short f2bf(float f) {
    unsigned u = __float_as_uint(f);
    unsigned r = (u + 0x7fffu + ((u >> 16) & 1u)) >> 16;
    return (unsigned short)r;
}
// fp32 -> fp8 e4m3fn, RNE, clamp to +-448
static __device__ __forceinline__ unsigned char f2fp8(float f) {
    unsigned u = __float_as_uint(f);
    unsigned s = (u >> 24) & 0x80;
    float a = fminf(__uint_as_float(u & 0x7FFFFFFF), 448.0f);
    if (a < 0.015625f) {
        int qi = (int)rintf(a * 512.0f);
        return (unsigned char)(s | qi);
    }
    unsigned ua = __float_as_uint(a);
    int e = (int)((ua >> 23) & 0xFF) - 127;
    unsigned man = (ua & 0x7FFFFF) | 0x800000;
    unsigned r = man >> 20;
    unsigned rem = man & 0xFFFFF;
    if (rem > 0x80000u || (rem == 0x80000u && (r & 1))) r++;
    if (r == 16) { r = 8; e++; }
    if (e > 8) return (unsigned char)(s | 0x7E);
    return (unsigned char)(s | ((unsigned)(e + 7) << 3) | (r & 7));
}
static __device__ __forceinline__ bool detect_f32(const unsigned short* w, int* scnt) {
    if (threadIdx.x == 0) *scnt = 0;
    __syncthreads();
    int big = 0;
    for (int i = threadIdx.x; i < 2048; i += blockDim.x)
        if (fabsf(bf2f(w[2 * i])) > 0.5f) big++;
    atomicAdd(scnt, big);
    __syncthreads();
    return *scnt > 64;
}
// raw-weight load with dtype dispatch
static __device__ __forceinline__ float ldw(const void* p, int idx, bool f32) {
    return f32 ? ((const float*)p)[idx] : bf2f(((const unsigned short*)p)[idx]);
}

// ---------------- CSR build ----------------
// bucketed scatter: per-block LDS histogram + in-LDS bucket prefix +
// one reservation atomic per (block, bucket) into relative cursors
__global__ void __launch_bounds__(256) k_bfill(const int* __restrict__ row,
                                               const int* __restrict__ col,
                                               const int* __restrict__ btot,
                                               int* __restrict__ bcur,
                                               uint2* __restrict__ tmp) {
    __shared__ int pref[256];
    __shared__ int hist[SCAN_NB];
    __shared__ int basew[SCAN_NB];
    int b = blockIdx.x, t = threadIdx.x;

    // in-LDS exclusive prefix of bucket totals
    int tv = (t < SCAN_NB) ? btot[t] : 0;
    pref[t] = tv;
    __syncthreads();
    for (int off = 1; off < 256; off <<= 1) {
        int u = (t >= off) ? pref[t - off] : 0;
        __syncthreads();
        pref[t] += u;
        __syncthreads();
    }
    int excl_t = pref[t] - tv;          // exclusive prefix for bucket t

    int lo = b * BF_CH;
    int hi = lo + BF_CH; if (hi > E_MSG) hi = E_MSG;
    for (int i = t; i < SCAN_NB; i += 256) hist[i] = 0;
    __syncthreads();
    for (int e = lo + t; e < hi; e += 256)
        atomicAdd(&hist[col[e] >> 8], 1);
    __syncthreads();
    if (t < SCAN_NB) {
        int c = hist[t];
        basew[t] = (c > 0) ? excl_t + atomicAdd(&bcur[t], c) : 0;
    }
    __syncthreads();
    for (int i = t; i < SCAN_NB; i += 256) hist[i] = 0;  // reuse as cursor
    __syncthreads();
    for (int e = lo + t; e < hi; e += 256) {
        int src = row[e], c = col[e];
        int bk = c >> 8;
        int off = atomicAdd(&hist[bk], 1);
        tmp[basew[bk] + off] = uint2{(unsigned)src, (unsigned)c};
    }
}

// per bucket: in-LDS bucket prefix -> [start,end); LDS degree count + prefix
// -> ptr/dinv; LDS-cursor scatter. No per-node global atomics.
__global__ void __launch_bounds__(256) k_csort2(const uint2* __restrict__ tmp,
                                                const int* __restrict__ btot,
                                                int* __restrict__ ptr,
                                                float* __restrict__ dinv,
                                                int* __restrict__ elist) {
    __shared__ int deg[256];
    __shared__ int pfx[256];
    int b = blockIdx.x, t = threadIdx.x;

    // bucket prefix (reuse pfx)
    int tv = (t < SCAN_NB) ? btot[t] : 0;
    pfx[t] = tv;
    __syncthreads();
    for (int off = 1; off < 256; off <<= 1) {
        int u = (t >= off) ? pfx[t - off] : 0;
        __syncthreads();
        pfx[t] += u;
        __syncthreads();
    }
    __shared__ int se[2];
    if (t == b) { se[0] = pfx[t] - tv; se[1] = pfx[t]; }
    __syncthreads();
    int start = se[0], end = se[1];

    deg[t] = 0;
    __syncthreads();
    for (int e = start + t; e < end; e += 256)
        atomicAdd(&deg[tmp[e].y & 255], 1);
    __syncthreads();

    int v = deg[t];
    pfx[t] = v;
    __syncthreads();
    for (int off = 1; off < 256; off <<= 1) {
        int u = (t >= off) ? pfx[t - off] : 0;
        __syncthreads();
        pfx[t] += u;
        __syncthreads();
    }
    int excl = pfx[t] - v;
    int n = (b << 8) + t;
    if (n < N_NODES) {
        ptr[n] = start + excl;
        dinv[n] = rsqrtf((float)v + 1.0f);
    }
    if (b == 0 && t == 0) ptr[N_NODES] = E_MSG;
    __syncthreads();
    deg[t] = excl;                       // reuse as local cursor
    __syncthreads();
    for (int e = start + t; e < end; e += 256) {
        uint2 p = tmp[e];
        int pos = atomicAdd(&deg[p.y & 255], 1);
        elist[start + pos] = (int)p.x;
    }
}

// ---------------- fused prep: bucket-count + cvt + frag tables + temb ----------
// blocks [0,392): edge bucket histogram (independent of weights)
// blocks [392,619): cvt -> ws fp32
// blocks [619,715): MFMA B-frag tables (read RAW weights, convert inline)
// blocks [715,843): t_emb, ONE timestep per block, 4-way k-split
#define WP_BC_NB   392
#define WP_CVT_NB  227
#define WP_PREP_NB 96
#define WP_TEMB_NB 128
#define WP_TOTAL_NB (WP_BC_NB + WP_CVT_NB + WP_PREP_NB + WP_TEMB_NB)

struct CvtArgs { const void* src[14]; };

__global__ void __launch_bounds__(256) k_wprep(CvtArgs a,
                                               const int* __restrict__ ecol,
                                               int* __restrict__ bsum,
                                               float* ws) {
    __shared__ int scnt;
    int bid = blockIdx.x;
    int tid = threadIdx.x;

    if (bid < WP_BC_NB) {
        // bucket totals: per-block LDS 196-bin histogram
        __shared__ int hist[SCAN_NB];
        for (int i = tid; i < SCAN_NB; i += 256) hist[i] = 0;
        __syncthreads();
        int lo = bid * BC_CH;
        int hi = lo + BC_CH; if (hi > E_MSG) hi = E_MSG;
        for (int e = lo + tid; e < hi; e += 256)
            atomicAdd(&hist[ecol[e] >> 8], 1);
        __syncthreads();
        for (int i = tid; i < SCAN_NB; i += 256) {
            int c = hist[i];
            if (c > 0) atomicAdd(&bsum[i], c);
        }
        return;
    }
    bid -= WP_BC_NB;

    bool f32 = detect_f32((const unsigned short*)a.src[0], &scnt);

    if (bid < WP_CVT_NB) {
        int t = bid * 256 + tid;
        if (t >= W_TOTAL) return;
        const int starts[14] = {OFF_Win, OFF_bin, OFF_Wt1, OFF_bt1, OFF_Wt2, OFF_bt2,
                                OFF_Wc0, OFF_bc0, OFF_Wc1, OFF_bc1, OFF_Wd1, OFF_bd1,
                                OFF_Wd2, OFF_bd2};
        int seg = 0;
#pragma unroll
        for (int i = 1; i < 14; i++)
            if (t >= starts[i]) seg = i;
        ws[t] = ldw(a.src[seg], t - starts[seg], f32);
    } else if (bid < WP_CVT_NB + WP_PREP_NB) {
        int idx = (bid - WP_CVT_NB) * 256 + tid;       // 0..24575
        int local, j, lane, ct, c, t, m, q;
        if (idx < 8192) {
            local = idx;
            j = local & 7; lane = (local >> 3) & 63; ct = local >> 9;
            c = ct >> 2; t = ct & 3; m = lane & 15; q = lane >> 4;
            ((unsigned char*)(ws + OFF_FWD1))[local] =
                f2fp8(16.0f * ldw(a.src[10], (32 * c + 8 * q + j) * 64 + 16 * t + m, f32));
        } else if (idx < 16384) {
            local = idx - 8192;
            j = local & 7; lane = (local >> 3) & 63; ct = local >> 9;
            c = ct >> 2; t = ct & 3; m = lane & 15; q = lane >> 4;
            ((unsigned short*)(ws + OFF_FWIN))[local] =
                f2bf(ldw(a.src[0], (32 * c + 8 * q + j) * 64 + 16 * t + m, f32));
        } else if (idx < 20480) {
            local = idx - 16384;
            j = local & 7; lane = (local >> 3) & 63; ct = local >> 9;
            c = ct >> 2; t = ct & 3; m = lane & 15; q = lane >> 4;
            ((unsigned short*)(ws + OFF_FWC0))[local] =
                f2bf(ldw(a.src[6], (32 * c + 8 * q + j) * 64 + 16 * t + m, f32));
        } else {
            local = idx - 20480;
            j = local & 7; lane = (local >> 3) & 63; ct = local >> 9;
            c = ct >> 2; t = ct & 3; m = lane & 15; q = lane >> 4;
            ((unsigned short*)(ws + OFF_FWC1))[local] =
                f2bf(ldw(a.src[8], (32 * c + 8 * q + j) * 64 + 16 * t + m, f32));
        }
    } else {
        // t_emb: one timestep per block; threads (j = tid&63, kg = tid>>6)
        __shared__ float pe[64];
        __shared__ float us4[4][256];
        __shared__ float us[256];
        __shared__ float pcs[4][64];
        int j = tid & 63;
        int kg = tid >> 6;
        int t = bid - WP_CVT_NB - WP_PREP_NB;

        if (tid < 64) {
            float xt = (float)t * (4000.0f / 128.0f);
            float sc = -logf(10000.0f) / 31.0f;
            float fr = __expf((float)(tid & 31) * sc);
            float ang = xt * fr;
            pe[tid] = (tid < 32) ? sinf(ang) : cosf(ang);
        }
        __syncthreads();

        float pu[4] = {0.f, 0.f, 0.f, 0.f};
#pragma unroll
        for (int kk = 0; kk < 16; kk++) {
            int k = 16 * kg + kk;
            float p = pe[k];
#pragma unroll
            for (int q = 0; q < 4; q++)
                pu[q] = fmaf(p, ldw(a.src[2], k * 256 + q * 64 + j, f32), pu[q]);
        }
#pragma unroll
        for (int q = 0; q < 4; q++) us4[kg][q * 64 + j] = pu[q];
        __syncthreads();

        {
            float uu = ldw(a.src[3], tid, f32) +
                       us4[0][tid] + us4[1][tid] + us4[2][tid] + us4[3][tid];
            us[tid] = uu * __builtin_amdgcn_rcpf(1.0f + __expf(-uu));
        }
        __syncthreads();

        float pc = 0.f;
#pragma unroll
        for (int kk = 0; kk < 64; kk++) {
            int k = 64 * kg + kk;
            pc = fmaf(us[k], ldw(a.src[4], k * 64 + j, f32), pc);
        }
        pcs[kg][j] = pc;
        __syncthreads();
        if (tid < 64) {
            float acc = ldw(a.src[5], j, f32) +
                        pcs[0][j] + pcs[1][j] + pcs[2][j] + pcs[3][j];
            (ws + OFF_TEMB)[t * 64 + j] = acc;
        }
    }
}

// ---------------- embedder + fused GCN-linear-0 (MFMA x2) ----------------
__global__ void __launch_bounds__(256) k_embed(const void* __restrict__ xraw,
                                               const unsigned short* __restrict__ wdet,
                                               const int* __restrict__ tsteps,
                                               float* __restrict__ ws,
                                               float* __restrict__ out_hembed,
                                               unsigned short* __restrict__ zbf) {
    __shared__ int scnt;
    __shared__ unsigned short tl[4][16 * 64];
    bool f32 = detect_f32(wdet, &scnt);

    int lane = threadIdx.x & 63;
    int wv = threadIdx.x >> 6;
    int m = lane & 15, quad = lane >> 4;
    int wid = blockIdx.x * 4 + wv;
    if (wid > N_NODES / 16 - 1) wid = N_NODES / 16 - 1;   // clamp (dup work benign)
    int n0 = wid * 16;

    const unsigned short* fwin = (const unsigned short*)(ws + OFF_FWIN);
    const unsigned short* fwc0 = (const unsigned short*)(ws + OFF_FWC0);

    bf16x8 bI[4][4];
#pragma unroll
    for (int c = 0; c < 4; c++)
#pragma unroll
        for (int t = 0; t < 4; t++)
            bI[c][t] = *reinterpret_cast<const bf16x8*>(fwin + (c * 4 + t) * 512 + lane * 8);

    f32x4 acc[4] = {f32x4{0,0,0,0}, f32x4{0,0,0,0}, f32x4{0,0,0,0}, f32x4{0,0,0,0}};
#pragma unroll
    for (int c = 0; c < 4; c++) {
        bf16x8 a;
        if (f32) {
            const float* xp = (const float*)xraw + (size_t)(n0 + m) * 128 + 32 * c + 8 * quad;
            float4 v0 = *reinterpret_cast<const float4*>(xp);
            float4 v1 = *reinterpret_cast<const float4*>(xp + 4);
            a[0] = (short)f2bf(v0.x); a[1] = (short)f2bf(v0.y);
            a[2] = (short)f2bf(v0.z); a[3] = (short)f2bf(v0.w);
            a[4] = (short)f2bf(v1.x); a[5] = (short)f2bf(v1.y);
            a[6] = (short)f2bf(v1.z); a[7] = (short)f2bf(v1.w);
        } else {
            a = *reinterpret_cast<const bf16x8*>(
                (const unsigned short*)xraw + (size_t)(n0 + m) * 128 + 32 * c + 8 * quad);
        }
#pragma unroll
        for (int t = 0; t < 4; t++)
            acc[t] = __builtin_amdgcn_mfma_f32_16x16x32_bf16(a, bI[c][t], acc[t], 0, 0, 0);
    }

    int tn[4];
#pragma unroll
    for (int r = 0; r < 4; r++) tn[r] = tsteps[n0 + 4 * quad + r];
    const float* temb = ws + OFF_TEMB;
#pragma unroll
    for (int t = 0; t < 4; t++) {
        int ch = 16 * t + m;
        float bj = ws[OFF_bin + ch];
#pragma unroll
        for (int r = 0; r < 4; r++) {
            int node = n0 + 4 * quad + r;
            float v = acc[t][r] + bj + temb[tn[r] * 64 + ch];
            out_hembed[(size_t)node * 64 + ch] = v;
            tl[wv][(4 * quad + r) * 64 + ch] = f2bf(v);
        }
    }
    __syncthreads();

    bf16x8 bC[2][4];
#pragma unroll
    for (int c = 0; c < 2; c++)
#pragma unroll
        for (int t = 0; t < 4; t++)
            bC[c][t] = *reinterpret_cast<const bf16x8*>(fwc0 + (c * 4 + t) * 512 + lane * 8);

    f32x4 az[4] = {f32x4{0,0,0,0}, f32x4{0,0,0,0}, f32x4{0,0,0,0}, f32x4{0,0,0,0}};
#pragma unroll
    for (int c = 0; c < 2; c++) {
        bf16x8 a2 = *reinterpret_cast<const bf16x8*>(&tl[wv][m * 64 + 32 * c + 8 * quad]);
#pragma unroll
        for (int t = 0; t < 4; t++)
            az[t] = __builtin_amdgcn_mfma_f32_16x16x32_bf16(a2, bC[c][t], az[t], 0, 0, 0);
    }
    const float* dinv = ws + OFF_DINV;
    float dv[4];
#pragma unroll
    for (int r = 0; r < 4; r++) dv[r] = dinv[n0 + 4 * quad + r];
#pragma unroll
    for (int t = 0; t < 4; t++) {
        int ch = 16 * t + m;
#pragma unroll
        for (int r = 0; r < 4; r++)
            zbf[(size_t)(n0 + 4 * quad + r) * 64 + ch] = f2bf(az[t][r] * dv[r]);
    }
}

// ---------------- gather-0 + relu + fused GCN-linear-1 (MFMA) ----------------
__global__ void __launch_bounds__(256) k_gather0(const unsigned short* __restrict__ zbf,
                                                 const int* __restrict__ ptr,
                                                 const int* __restrict__ elist,
                                                 const float* __restrict__ ws,
                                                 unsigned short* __restrict__ zout) {
    __shared__ unsigned short tile[16 * 64];     // 2KB, swizzled bf16 [16][64]
    const float* dinv = ws + OFF_DINV;
    const float* bias = ws + OFF_bc0;
    const unsigned short* fwc1 = (const unsigned short*)(ws + OFF_FWC1);

    int lane = threadIdx.x & 63;
    int wv = threadIdx.x >> 6;
    int g = lane >> 4;              // neighbor sub-group 0..3
    int cl = lane & 15;             // channel quad: channels 4cl..4cl+3
    int n0 = blockIdx.x * 16;

    float4 b4 = *reinterpret_cast<const float4*>(bias + 4 * cl);

#pragma unroll
    for (int snode = 0; snode < 4; snode++) {
        int li = wv * 4 + snode;    // local tile row
        int n = n0 + li;
        int base = ptr[n], end = ptr[n + 1];

        float ws0 = (g == 0) ? 1.0f : 0.0f;
        ushort4 sv = *reinterpret_cast<const ushort4*>(zbf + (size_t)n * 64 + cl * 4);
        float s0 = ws0 * bf2f(sv.x), s1 = ws0 * bf2f(sv.y);
        float s2 = ws0 * bf2f(sv.z), s3 = ws0 * bf2f(sv.w);

        for (int k = base; k < end; k += 8) {
            int e0 = k + g, e1 = k + 4 + g;
            int r0 = elist[min(e0, end - 1)];
            int r1 = elist[min(e1, end - 1)];
            ushort4 v0 = *reinterpret_cast<const ushort4*>(zbf + (size_t)r0 * 64 + cl * 4);
            ushort4 v1 = *reinterpret_cast<const ushort4*>(zbf + (size_t)r1 * 64 + cl * 4);
            float w0 = (e0 < end) ? 1.0f : 0.0f;
            float w1 = (e1 < end) ? 1.0f : 0.0f;
            s0 = fmaf(w0, bf2f(v0.x), s0); s1 = fmaf(w0, bf2f(v0.y), s1);
            s2 = fmaf(w0, bf2f(v0.z), s2); s3 = fmaf(w0, bf2f(v0.w), s3);
            s0 = fmaf(w1, bf2f(v1.x), s0); s1 = fmaf(w1, bf2f(v1.y), s1);
            s2 = fmaf(w1, bf2f(v1.z), s2); s3 = fmaf(w1, bf2f(v1.w), s3);
        }
        s0 += __shfl_xor(s0, 16, 64); s0 += __shfl_xor(s0, 32, 64);
        s1 += __shfl_xor(s1, 16, 64); s1 += __shfl_xor(s1, 32, 64);
        s2 += __shfl_xor(s2, 16, 64); s2 += __shfl_xor(s2, 32, 64);
        s3 += __shfl_xor(s3, 16, 64); s3 += __shfl_xor(s3, 32, 64);

        if (g == 0) {
            float dv = dinv[n];
            float h0 = fmaxf(fmaf(dv, s0, b4.x), 0.0f);
            float h1 = fmaxf(fmaf(dv, s1, b4.y), 0.0f);
            float h2 = fmaxf(fmaf(dv, s2, b4.z), 0.0f);
            float h3 = fmaxf(fmaf(dv, s3, b4.w), 0.0f);
            ushort4 hv;
            hv.x = f2bf(h0); hv.y = f2bf(h1); hv.z = f2bf(h2); hv.w = f2bf(h3);
            int bo = li * 128 + ((cl * 8) ^ ((li & 7) << 4));   // XOR-swizzle (G4)
            *reinterpret_cast<ushort4*>((char*)tile + bo) = hv;
        }
    }
    __syncthreads();

    // phase 2: wave wv computes output channels 16*wv..16*wv+15 for all 16 nodes
    int m = lane & 15, q = lane >> 4;
    bf16x8 bB0 = *reinterpret_cast<const bf16x8*>(fwc1 + (0 * 4 + wv) * 512 + lane * 8);
    bf16x8 bB1 = *reinterpret_cast<const bf16x8*>(fwc1 + (1 * 4 + wv) * 512 + lane * 8);

    f32x4 az = f32x4{0, 0, 0, 0};
    {
        int bo0 = m * 128 + ((0 * 64 + q * 16) ^ ((m & 7) << 4));
        bf16x8 a0 = *reinterpret_cast<const bf16x8*>((const char*)tile + bo0);
        az = __builtin_amdgcn_mfma_f32_16x16x32_bf16(a0, bB0, az, 0, 0, 0);
        int bo1 = m * 128 + ((1 * 64 + q * 16) ^ ((m & 7) << 4));
        bf16x8 a1 = *reinterpret_cast<const bf16x8*>((const char*)tile + bo1);
        az = __builtin_amdgcn_mfma_f32_16x16x32_bf16(a1, bB1, az, 0, 0, 0);
    }
    float dv4[4];
#pragma unroll
    for (int r = 0; r < 4; r++) dv4[r] = dinv[n0 + 4 * q + r];
#pragma unroll
    for (int r = 0; r < 4; r++) {
        int node = n0 + 4 * q + r;
        zout[(size_t)node * 64 + 16 * wv + m] = f2bf(az[r] * dv4[r]);
    }
}

// ---------------- gather-1 -> h_enc (fp32 out + fp8x16 table) ----------------
__global__ void __launch_bounds__(256) k_gather1(const unsigned short* __restrict__ zbf,
                                                 const int* __restrict__ ptr,
                                                 const int* __restrict__ elist,
                                                 const float* __restrict__ dinv,
                                                 const float* __restrict__ bias,
                                                 unsigned char* __restrict__ henc8,
                                                 float* __restrict__ ofp) {
    int lane = threadIdx.x & 63;
    int n = blockIdx.x * 4 + (threadIdx.x >> 6);
    int g = lane >> 4;
    int cl = lane & 15;
    int base = ptr[n], end = ptr[n + 1];

    float4 b4 = *reinterpret_cast<const float4*>(bias + 4 * cl);

    float ws0 = (g == 0) ? 1.0f : 0.0f;
    ushort4 sv = *reinterpret_cast<const ushort4*>(zbf + (size_t)n * 64 + cl * 4);
    float s0 = ws0 * bf2f(sv.x), s1 = ws0 * bf2f(sv.y);
    float s2 = ws0 * bf2f(sv.z), s3 = ws0 * bf2f(sv.w);

    for (int k = base; k < end; k += 8) {
        int e0 = k + g, e1 = k + 4 + g;
        int r0 = elist[min(e0, end - 1)];
        int r1 = elist[min(e1, end - 1)];
        ushort4 v0 = *reinterpret_cast<const ushort4*>(zbf + (size_t)r0 * 64 + cl * 4);
        ushort4 v1 = *reinterpret_cast<const ushort4*>(zbf + (size_t)r1 * 64 + cl * 4);
        float w0 = (e0 < end) ? 1.0f : 0.0f;
        float w1 = (e1 < end) ? 1.0f : 0.0f;
        s0 = fmaf(w0, bf2f(v0.x), s0); s1 = fmaf(w0, bf2f(v0.y), s1);
        s2 = fmaf(w0, bf2f(v0.z), s2); s3 = fmaf(w0, bf2f(v0.w), s3);
        s0 = fmaf(w1, bf2f(v1.x), s0); s1 = fmaf(w1, bf2f(v1.y), s1);
        s2 = fmaf(w1, bf2f(v1.z), s2); s3 = fmaf(w1, bf2f(v1.w), s3);
    }
    s0 += __shfl_xor(s0, 16, 64); s0 += __shfl_xor(s0, 32, 64);
    s1 += __shfl_xor(s1, 16, 64); s1 += __shfl_xor(s1, 32, 64);
    s2 += __shfl_xor(s2, 16, 64); s2 += __shfl_xor(s2, 32, 64);
    s3 += __shfl_xor(s3, 16, 64); s3 += __shfl_xor(s3, 32, 64);

    float dv = dinv[n];
    float o0 = fmaf(dv, s0, b4.x);
    float o1 = fmaf(dv, s1, b4.y);
    float o2 = fmaf(dv, s2, b4.z);
    float o3 = fmaf(dv, s3, b4.w);

    if (g == 0) {
        float4 ov; ov.x = o0; ov.y = o1; ov.z = o2; ov.w = o3;
        *reinterpret_cast<float4*>(ofp + (size_t)n * 64 + cl * 4) = ov;
    }
    // redistribute: lane converts channel `lane`
    int jc = lane >> 2;
    float a0 = __shfl(o0, jc, 64);
    float a1 = __shfl(o1, jc, 64);
    float a2 = __shfl(o2, jc, 64);
    float a3 = __shfl(o3, jc, 64);
    int sel = lane & 3;
    float mv = (sel == 0) ? a0 : (sel == 1) ? a1 : (sel == 2) ? a2 : a3;
    henc8[(size_t)n * 64 + lane] = f2fp8(16.0f * mv);
}

// ---------------- edge decoder (MFMA fp8, LDS weights / low-VGPR) ----------------
// The block-uniform weight fragments (bfr: 32 VGPR) and channel constants
// (w2/b1: 32 VGPR) move to LDS; per-tile ds_read_b64 (lane-stride, conflict-
// free) and quad-uniform ds_read_b128 (broadcast) replace them. Arch VGPR
// drops ~68 -> ~48, which per the occupancy-vs-VGPR relation measured across
// rounds 4-6 should roughly double resident waves and let TLP hide the h8
// gather latency + trans-pipe epilogue.
#define DEC_TPW 4
#define DEC_TILES (E_FULL / 16)

__global__ void __launch_bounds__(256) k_dec(const int* __restrict__ src,
                                             const int* __restrict__ dst,
                                             const unsigned char* __restrict__ h8,
                                             const float* __restrict__ ws,
                                             float* __restrict__ out) {
    __shared__ long s_bfr[16 * 64];      // 8KB: FWD1 frag table [ct][lane]
    __shared__ float s_w2[64];
    __shared__ float s_b1[64];

    int tid = threadIdx.x;
    float b2 = ws[OFF_bd2];
    {
        const long* fw8 = (const long*)(ws + OFF_FWD1);   // 1024 longs
        for (int idx = tid; idx < 1024; idx += 256)
            s_bfr[idx] = fw8[idx];
        if (tid < 64) {
            s_w2[tid] = ws[OFF_Wd2 + tid];
            s_b1[tid] = ws[OFF_bd1 + tid];
        }
    }
    __syncthreads();

    int lane = tid & 63;
    int wv = tid >> 6;
    int m = lane & 15;
    int quad = lane >> 4;

    int tile0 = (blockIdx.x * 4 + wv) * DEC_TPW;

    // all indices up front (independent loads)
    int sg[DEC_TPW], dg[DEC_TPW];
#pragma unroll
    for (int i = 0; i < DEC_TPW; i++) {
        int tc = min(tile0 + i, DEC_TILES - 1);
        sg[i] = src[tc * 16 + m];
        dg[i] = dst[tc * 16 + m];
    }

#pragma unroll
    for (int i = 0; i < DEC_TPW; i++) {
        int tile = tile0 + i;
        long A[4];
#pragma unroll
        for (int c = 0; c < 4; c++) {
            int row = (c < 2) ? sg[i] : dg[i];
            A[c] = *reinterpret_cast<const long*>(
                h8 + (size_t)row * 64 + (c & 1) * 32 + 8 * quad);
        }
        f32x4 acc[4] = {f32x4{0,0,0,0}, f32x4{0,0,0,0}, f32x4{0,0,0,0}, f32x4{0,0,0,0}};
#pragma unroll
        for (int c = 0; c < 4; c++)
#pragma unroll
            for (int mt = 0; mt < 4; mt++) {
                long bk = s_bfr[(c * 4 + mt) * 64 + lane];
                acc[mt] = __builtin_amdgcn_mfma_f32_16x16x32_fp8_fp8(bk, A[c], acc[mt], 0, 0, 0);
            }

        // epilogue: 16 silu + Wd2 dot, all for edge (lane&15)
        float p[4];
#pragma unroll
        for (int mt = 0; mt < 4; mt++) {
            float4 w2v = *reinterpret_cast<const float4*>(&s_w2[16 * mt + 4 * quad]);
            float4 b1v = *reinterpret_cast<const float4*>(&s_b1[16 * mt + 4 * quad]);
            float pm = 0.0f;
#pragma unroll
            for (int r = 0; r < 4; r++) {
                float v = fmaf(acc[mt][r], 0.00390625f, b1v[r]);   // /256 un-scale
                float h = v * __builtin_amdgcn_rcpf(1.0f + __expf(-v));
                pm = fmaf(h, w2v[r], pm);
            }
            p[mt] = pm;
        }
        float sv = (p[0] + p[1]) + (p[2] + p[3]);
        sv += __shfl_xor(sv, 16, 64);
        sv += __shfl_xor(sv, 32, 64);
        if (lane < 16 && tile < DEC_TILES)
            out[tile * 16 + lane] = sv + b2;
    }
}

extern "C" void kernel_launch(void* const* d_in, const int* in_sizes, int n_in,
                              void* d_out, int out_size, void* d_ws, size_t ws_size,
                              hipStream_t stream) {
    if (n_in < 18) return;
    const void* x              = d_in[0];
    const int* edge_index      = (const int*)d_in[1];
    const int* full_edge_index = (const int*)d_in[2];
    const int* tsteps          = (const int*)d_in[3];
    float* ws = (float*)d_ws;
    float* out = (float*)d_out;

    int*   iws   = (int*)d_ws;
    int*   bsum  = iws + OFF_BSUM;
    int*   bcur  = iws + OFF_BCUR;
    int*   ptr   = iws + OFF_PTR;
    int*   elist = iws + OFF_ELIST;
    uint2* tmp   = (uint2*)(iws + OFF_TMP2);
    unsigned short* zbf  = (unsigned short*)(ws + OFF_ZBF);
    unsigned short* zbf2 = (unsigned short*)(ws + OFF_ZBF2);
    unsigned char*  h8   = (unsigned char*)(ws + OFF_HENC8);

    CvtArgs ca;
    for (int i = 0; i < 14; i++) ca.src[i] = d_in[4 + i];

    // zero bucket totals + relative cursors (contiguous 512 ints)
    hipMemsetAsync(bsum, 0, (size_t)512 * 4, stream);

    // fused prep: edge bucket histogram + cvt + frag tables + t_emb
    k_wprep<<<WP_TOTAL_NB, 256, 0, stream>>>(ca, edge_index + E_MSG, bsum, ws);

    // CSR: bucketed scatter (in-LDS prefix) -> per-bucket sort (+ptr/dinv)
    k_bfill<<<SCAN_NB, 256, 0, stream>>>(edge_index, edge_index + E_MSG, bsum,
                                         bcur, tmp);
    k_csort2<<<SCAN_NB, 256, 0, stream>>>(tmp, bsum, ptr, ws + OFF_DINV, elist);

    // embedder + fused lin0 (h_embed -> d_out fp32; z0 -> zbf)
    k_embed<<<(N_NODES / 16 + 3) / 4, 256, 0, stream>>>(
        x, (const unsigned short*)d_in[4], tsteps, ws, out + E_FULL, zbf);

    // gather0 + relu + fused lin1 (MFMA): zbf -> zbf2
    k_gather0<<<N_NODES / 16, 256, 0, stream>>>(zbf, ptr, elist, ws, zbf2);

    // gather1: zbf2 -> {out fp32, h8 fp8x16}
    k_gather1<<<N_NODES / 4, 256, 0, stream>>>(
        zbf2, ptr, elist, ws + OFF_DINV, ws + OFF_bc1, h8,
        out + E_FULL + (size_t)N_NODES * 64);

    // decoder (fp8 MFMA, LDS weights / low-VGPR)
    int dec_blocks = (DEC_TILES + 4 * DEC_TPW - 1) / (4 * DEC_TPW);
    k_dec<<<dec_blocks, 256, 0, stream>>>(full_edge_index, full_edge_index + E_FULL,
                                          h8, ws, out);
}